// Round 1
// baseline (1423.650 us; speedup 1.0000x reference)
//
#include <hip/hip_runtime.h>
#include <hip/hip_bf16.h>
#include <cstddef>

#define B_ 2
#define SL_ 2048
#define RATIO_ 16
#define SG_ 128
#define S_ 2176
#define D_ 512
#define H_ 8
#define HD_ 64
#define FF_ 1024
#define KCLIP_ 4
#define RAD_ 4
#define NC_ 2
#define NEG_ (-1.0e9f)
#define MROWS_ (B_ * S_)   // 4352

// ---------------------------------------------------------------- build x + pad
__global__ void build_x_kernel(const int* __restrict__ ids,
                               const float* __restrict__ embed,
                               const float* __restrict__ gtok,
                               float* __restrict__ x,
                               int* __restrict__ pad_all) {
    int row = blockIdx.x;            // 0..MROWS_-1
    int b = row / S_, s = row % S_;
    const float* src;
    if (s < SL_) {
        int tok = ids[b * SL_ + s];
        src = embed + (size_t)tok * D_;
        if (threadIdx.x == 0) pad_all[row] = (tok == 0) ? 1 : 0;
    } else {
        src = gtok;
        if (threadIdx.x == 0) {
            int g = s - SL_;
            int allz = 1;
            for (int r = 0; r < RATIO_; ++r)
                allz &= (ids[b * SL_ + g * RATIO_ + r] == 0) ? 1 : 0;
            pad_all[row] = allz;
        }
    }
    // 128 threads x float4 = 512 floats
    float4 v = ((const float4*)src)[threadIdx.x];
    ((float4*)(x + (size_t)row * D_))[threadIdx.x] = v;
}

// ---------------------------------------------------------------- f32 tiled GEMM
// C[M,N] = A[M,K] @ W[K,N] + bias (opt relu). BM=BN=64, BK=16, 256 thr, 4x4/thread.
__global__ __launch_bounds__(256) void gemm_kernel(const float* __restrict__ A,
                                                   const float* __restrict__ W,
                                                   const float* __restrict__ bias,
                                                   float* __restrict__ C,
                                                   int M, int K, int N, int relu) {
    __shared__ __align__(16) float As[16][68];
    __shared__ __align__(16) float Bs[16][68];
    int tid = threadIdx.x;
    int m0 = blockIdx.y * 64;
    int n0 = blockIdx.x * 64;
    int tx = tid & 15, ty = tid >> 4;
    float acc[4][4] = {};
    int a_m = tid >> 2;            // 0..63
    int a_k = (tid & 3) * 4;       // 0,4,8,12
    int b_k = tid >> 4;            // 0..15
    int b_n = (tid & 15) * 4;      // 0..60

    for (int k0 = 0; k0 < K; k0 += 16) {
        float4 av = *(const float4*)(A + (size_t)(m0 + a_m) * K + k0 + a_k);
        float4 bv = *(const float4*)(W + (size_t)(k0 + b_k) * N + n0 + b_n);
        __syncthreads();
        As[a_k + 0][a_m] = av.x;
        As[a_k + 1][a_m] = av.y;
        As[a_k + 2][a_m] = av.z;
        As[a_k + 3][a_m] = av.w;
        *(float4*)&Bs[b_k][b_n] = bv;
        __syncthreads();
#pragma unroll
        for (int kk = 0; kk < 16; ++kk) {
            const float4 a4 = *(const float4*)&As[kk][ty * 4];
            const float4 b4 = *(const float4*)&Bs[kk][tx * 4];
            float ar[4] = {a4.x, a4.y, a4.z, a4.w};
            float br[4] = {b4.x, b4.y, b4.z, b4.w};
#pragma unroll
            for (int ii = 0; ii < 4; ++ii)
#pragma unroll
                for (int jj = 0; jj < 4; ++jj)
                    acc[ii][jj] = fmaf(ar[ii], br[jj], acc[ii][jj]);
        }
    }
#pragma unroll
    for (int ii = 0; ii < 4; ++ii) {
        int m = m0 + ty * 4 + ii;
#pragma unroll
        for (int jj = 0; jj < 4; ++jj) {
            int n = n0 + tx * 4 + jj;
            float v = acc[ii][jj] + bias[n];
            if (relu) v = fmaxf(v, 0.0f);
            C[(size_t)m * N + n] = v;
        }
    }
}

// ---------------------------------------------------------------- attention
// One wave (64 lanes) per (b,h,query). lane = head-dim. Online softmax.
__global__ __launch_bounds__(256) void attn_kernel(const float* __restrict__ Q,
                                                   const float* __restrict__ Kb,
                                                   const float* __restrict__ Vb,
                                                   const float* __restrict__ rel_bias,
                                                   const int* __restrict__ pad_all,
                                                   float* __restrict__ O) {
    int wave = (int)((blockIdx.x * (size_t)blockDim.x + threadIdx.x) >> 6);
    int lane = threadIdx.x & 63;
    int i  = wave % S_;
    int bh = wave / S_;
    int h  = bh % H_;
    int b  = bh / H_;

    size_t qoff = ((size_t)(b * S_ + i)) * D_ + h * HD_ + lane;
    float qv = Q[qoff] * 0.125f;   // 1/sqrt(64)

    float m = -1.0e30f, l = 0.0f, acc = 0.0f;
    const int* pad = pad_all + b * S_;

    auto step = [&](int j, float biasv) {
        size_t koff = ((size_t)(b * S_ + j)) * D_ + h * HD_ + lane;
        float s = qv * Kb[koff];
        s += __shfl_xor(s, 1);
        s += __shfl_xor(s, 2);
        s += __shfl_xor(s, 4);
        s += __shfl_xor(s, 8);
        s += __shfl_xor(s, 16);
        s += __shfl_xor(s, 32);
        s += biasv;
        if (pad[j]) s = NEG_;
        float nm = fmaxf(m, s);
        float fac = __expf(m - nm);
        float p = __expf(s - nm);
        acc = acc * fac + p * Vb[koff];
        l = l * fac + p;
        m = nm;
    };

    if (i < SL_) {
        int j0 = i - RAD_; if (j0 < 0) j0 = 0;
        int j1 = i + RAD_; if (j1 > SL_ - 1) j1 = SL_ - 1;
        for (int j = j0; j <= j1; ++j)
            step(j, rel_bias[h * (2 * KCLIP_ + 1) + (j - i + KCLIP_)]);
        for (int j = SL_; j < S_; ++j)
            step(j, 0.0f);
    } else {
        for (int j = 0; j < S_; ++j)
            step(j, 0.0f);
    }
    O[qoff] = acc / l;
}

// ---------------------------------------------------------------- residual + LN
__global__ __launch_bounds__(256) void ln_kernel(const float* __restrict__ A,
                                                 const float* __restrict__ Bres,
                                                 const float* __restrict__ g,
                                                 const float* __restrict__ be,
                                                 float* __restrict__ out) {
    int row = blockIdx.x;
    int tid = threadIdx.x;
    size_t base = (size_t)row * D_;
    float x0 = A[base + tid]       + Bres[base + tid];
    float x1 = A[base + tid + 256] + Bres[base + tid + 256];
    float s1 = x0 + x1;
    float s2 = x0 * x0 + x1 * x1;
    for (int off = 1; off < 64; off <<= 1) {
        s1 += __shfl_xor(s1, off);
        s2 += __shfl_xor(s2, off);
    }
    __shared__ float ws1[4], ws2[4];
    int wid = tid >> 6;
    if ((tid & 63) == 0) { ws1[wid] = s1; ws2[wid] = s2; }
    __syncthreads();
    s1 = ws1[0] + ws1[1] + ws1[2] + ws1[3];
    s2 = ws2[0] + ws2[1] + ws2[2] + ws2[3];
    float mean = s1 * (1.0f / D_);
    float var  = s2 * (1.0f / D_) - mean * mean;
    float rstd = rsqrtf(var + 1e-5f);
    out[base + tid]       = (x0 - mean) * rstd * g[tid]       + be[tid];
    out[base + tid + 256] = (x1 - mean) * rstd * g[tid + 256] + be[tid + 256];
}

// ---------------------------------------------------------------- pool + classifier
__global__ __launch_bounds__(256) void pool_cls_kernel(const float* __restrict__ x2,
                                                       const int* __restrict__ pad_all,
                                                       const float* __restrict__ w1,
                                                       const float* __restrict__ w2,
                                                       float* __restrict__ out) {
    int b = blockIdx.x;
    int tid = threadIdx.x;
    __shared__ float zg[D_];
    __shared__ int cnt_s;
    if (tid == 0) {
        int c = 0;
        for (int g = 0; g < SG_; ++g) c += pad_all[b * S_ + SL_ + g] ? 0 : 1;
        cnt_s = c;
    }
    float acc0 = 0.0f, acc1 = 0.0f;
    for (int g = 0; g < SG_; ++g) {
        if (!pad_all[b * S_ + SL_ + g]) {
            size_t base = ((size_t)(b * S_ + SL_ + g)) * D_;
            acc0 += x2[base + tid];
            acc1 += x2[base + tid + 256];
        }
    }
    __syncthreads();
    float inv = 1.0f / (float)cnt_s;
    zg[tid]       = acc0 * inv;
    zg[tid + 256] = acc1 * inv;
    __syncthreads();
    // hidden[tid] = relu(zg . w1[:,tid]), w1 is (512,256)
    float hsum = 0.0f;
    for (int d = 0; d < D_; ++d)
        hsum = fmaf(zg[d], w1[(size_t)d * 256 + tid], hsum);
    hsum = fmaxf(hsum, 0.0f);
    // out[n] = sum_t hidden[t] * w2[t,n], w2 is (256,2)
    float o0 = hsum * w2[(size_t)tid * NC_ + 0];
    float o1 = hsum * w2[(size_t)tid * NC_ + 1];
    for (int off = 1; off < 64; off <<= 1) {
        o0 += __shfl_xor(o0, off);
        o1 += __shfl_xor(o1, off);
    }
    __shared__ float r0[4], r1[4];
    if ((tid & 63) == 0) { r0[tid >> 6] = o0; r1[tid >> 6] = o1; }
    __syncthreads();
    if (tid == 0) {
        out[b * NC_ + 0] = r0[0] + r0[1] + r0[2] + r0[3];
        out[b * NC_ + 1] = r1[0] + r1[1] + r1[2] + r1[3];
    }
}

// ---------------------------------------------------------------- launch
extern "C" void kernel_launch(void* const* d_in, const int* in_sizes, int n_in,
                              void* d_out, int out_size, void* d_ws, size_t ws_size,
                              hipStream_t stream) {
    const int*   ids    = (const int*)d_in[0];
    const float* embed  = (const float*)d_in[1];
    const float* gtok   = (const float*)d_in[2];
    const float* relb   = (const float*)d_in[3];
    const float* q_w    = (const float*)d_in[4];
    const float* q_b    = (const float*)d_in[5];
    const float* k_w    = (const float*)d_in[6];
    const float* k_b    = (const float*)d_in[7];
    const float* v_w    = (const float*)d_in[8];
    const float* v_b    = (const float*)d_in[9];
    const float* o_w    = (const float*)d_in[10];
    const float* o_b    = (const float*)d_in[11];
    const float* ln1_g  = (const float*)d_in[12];
    const float* ln1_b  = (const float*)d_in[13];
    const float* ln2_g  = (const float*)d_in[14];
    const float* ln2_b  = (const float*)d_in[15];
    const float* ff1_w  = (const float*)d_in[16];
    const float* ff1_b  = (const float*)d_in[17];
    const float* ff2_w  = (const float*)d_in[18];
    const float* ff2_b  = (const float*)d_in[19];
    const float* cls_w1 = (const float*)d_in[20];
    const float* cls_w2 = (const float*)d_in[21];

    char* ws = (char*)d_ws;
    const size_t SLOT = (size_t)MROWS_ * D_ * sizeof(float);   // 8,912,896 B
    float* x    = (float*)(ws + 0 * SLOT);
    float* q    = (float*)(ws + 1 * SLOT);
    float* k    = (float*)(ws + 2 * SLOT);
    float* v    = (float*)(ws + 3 * SLOT);
    float* o    = (float*)(ws + 4 * SLOT);
    float* tmp  = q;        // q dead after attention
    float* x1   = k;        // k dead after attention
    float* ffh  = v;        // v+o dead after o-proj: 2 contiguous slots (3,4)
    float* tmp2 = x;        // x dead after LN1
    float* x2   = q;        // tmp dead after LN1
    int* pad_all = (int*)(ws + 5 * SLOT);

    build_x_kernel<<<MROWS_, 128, 0, stream>>>(ids, embed, gtok, x, pad_all);

    gemm_kernel<<<dim3(D_ / 64, MROWS_ / 64), 256, 0, stream>>>(x, q_w, q_b, q, MROWS_, D_, D_, 0);
    gemm_kernel<<<dim3(D_ / 64, MROWS_ / 64), 256, 0, stream>>>(x, k_w, k_b, k, MROWS_, D_, D_, 0);
    gemm_kernel<<<dim3(D_ / 64, MROWS_ / 64), 256, 0, stream>>>(x, v_w, v_b, v, MROWS_, D_, D_, 0);

    attn_kernel<<<(B_ * H_ * S_) / 4, 256, 0, stream>>>(q, k, v, relb, pad_all, o);

    gemm_kernel<<<dim3(D_ / 64, MROWS_ / 64), 256, 0, stream>>>(o, o_w, o_b, tmp, MROWS_, D_, D_, 0);
    ln_kernel<<<MROWS_, 256, 0, stream>>>(x, tmp, ln1_g, ln1_b, x1);

    gemm_kernel<<<dim3(FF_ / 64, MROWS_ / 64), 256, 0, stream>>>(x1, ff1_w, ff1_b, ffh, MROWS_, D_, FF_, 1);
    gemm_kernel<<<dim3(D_ / 64, MROWS_ / 64), 256, 0, stream>>>(ffh, ff2_w, ff2_b, tmp2, MROWS_, FF_, D_, 0);
    ln_kernel<<<MROWS_, 256, 0, stream>>>(x1, tmp2, ln2_g, ln2_b, x2);

    pool_cls_kernel<<<B_, 256, 0, stream>>>(x2, pad_all, cls_w1, cls_w2, (float*)d_out);
}

// Round 2
// 731.544 us; speedup vs baseline: 1.9461x; 1.9461x over previous
//
#include <hip/hip_runtime.h>
#include <hip/hip_bf16.h>
#include <cstddef>

#define B_ 2
#define SL_ 2048
#define RATIO_ 16
#define SG_ 128
#define S_ 2176
#define D_ 512
#define H_ 8
#define HD_ 64
#define FF_ 1024
#define KCLIP_ 4
#define RAD_ 4
#define NC_ 2
#define NEG_ (-1.0e9f)
#define MINF_ (-1.0e30f)
#define MROWS_ (B_ * S_)   // 4352
#define KC_ 4              // split-K chunks for global-query attention

// ---------------------------------------------------------------- build x + pad
__global__ void build_x_kernel(const int* __restrict__ ids,
                               const float* __restrict__ embed,
                               const float* __restrict__ gtok,
                               float* __restrict__ x,
                               int* __restrict__ pad_all) {
    int row = blockIdx.x;            // 0..MROWS_-1
    int b = row / S_, s = row % S_;
    const float* src;
    if (s < SL_) {
        int tok = ids[b * SL_ + s];
        src = embed + (size_t)tok * D_;
        if (threadIdx.x == 0) pad_all[row] = (tok == 0) ? 1 : 0;
    } else {
        src = gtok;
        if (threadIdx.x == 0) {
            int g = s - SL_;
            int allz = 1;
            for (int r = 0; r < RATIO_; ++r)
                allz &= (ids[b * SL_ + g * RATIO_ + r] == 0) ? 1 : 0;
            pad_all[row] = allz;
        }
    }
    float4 v = ((const float4*)src)[threadIdx.x];
    ((float4*)(x + (size_t)row * D_))[threadIdx.x] = v;
}

// ---------------------------------------------------------------- f32 tiled GEMM
__global__ __launch_bounds__(256) void gemm_kernel(const float* __restrict__ A,
                                                   const float* __restrict__ W,
                                                   const float* __restrict__ bias,
                                                   float* __restrict__ C,
                                                   int M, int K, int N, int relu) {
    __shared__ __align__(16) float As[16][68];
    __shared__ __align__(16) float Bs[16][68];
    int tid = threadIdx.x;
    int m0 = blockIdx.y * 64;
    int n0 = blockIdx.x * 64;
    int tx = tid & 15, ty = tid >> 4;
    float acc[4][4] = {};
    int a_m = tid >> 2;
    int a_k = (tid & 3) * 4;
    int b_k = tid >> 4;
    int b_n = (tid & 15) * 4;

    for (int k0 = 0; k0 < K; k0 += 16) {
        float4 av = *(const float4*)(A + (size_t)(m0 + a_m) * K + k0 + a_k);
        float4 bv = *(const float4*)(W + (size_t)(k0 + b_k) * N + n0 + b_n);
        __syncthreads();
        As[a_k + 0][a_m] = av.x;
        As[a_k + 1][a_m] = av.y;
        As[a_k + 2][a_m] = av.z;
        As[a_k + 3][a_m] = av.w;
        *(float4*)&Bs[b_k][b_n] = bv;
        __syncthreads();
#pragma unroll
        for (int kk = 0; kk < 16; ++kk) {
            const float4 a4 = *(const float4*)&As[kk][ty * 4];
            const float4 b4 = *(const float4*)&Bs[kk][tx * 4];
            float ar[4] = {a4.x, a4.y, a4.z, a4.w};
            float br[4] = {b4.x, b4.y, b4.z, b4.w};
#pragma unroll
            for (int ii = 0; ii < 4; ++ii)
#pragma unroll
                for (int jj = 0; jj < 4; ++jj)
                    acc[ii][jj] = fmaf(ar[ii], br[jj], acc[ii][jj]);
        }
    }
#pragma unroll
    for (int ii = 0; ii < 4; ++ii) {
        int m = m0 + ty * 4 + ii;
#pragma unroll
        for (int jj = 0; jj < 4; ++jj) {
            int n = n0 + tx * 4 + jj;
            float v = acc[ii][jj] + bias[n];
            if (relu) v = fmaxf(v, 0.0f);
            C[(size_t)m * N + n] = v;
        }
    }
}

// ================================================================ attention
// Shared tile structure: 32 queries/block (4 waves x 8q), 64-key rounds in LDS.
// Phase 1: lane = key slot, K-column reads (pad 65, conflict-free), Q broadcast.
// Phase 2: lane = dim, V-row reads (conflict-free), P broadcast float4.

#define PADK_ 65

__device__ __forceinline__ float wave_max(float v) {
#pragma unroll
    for (int off = 1; off < 64; off <<= 1) v = fmaxf(v, __shfl_xor(v, off));
    return v;
}
__device__ __forceinline__ float wave_sum(float v) {
#pragma unroll
    for (int off = 1; off < 64; off <<= 1) v += __shfl_xor(v, off);
    return v;
}

// ------------------------------------------- long queries (i < SL)
// grid: 64 qtiles * 8 h * 2 b = 1024 blocks. 3 rounds: local band, global x2.
__global__ __launch_bounds__(256) void attn_long_kernel(const float* __restrict__ Q,
                                                        const float* __restrict__ Kb,
                                                        const float* __restrict__ Vb,
                                                        const float* __restrict__ relb,
                                                        const int* __restrict__ pad_all,
                                                        float* __restrict__ O) {
    __shared__ float Ks[64][PADK_];
    __shared__ float Vs[64][PADK_];
    __shared__ __align__(16) float Qs[32][64];
    __shared__ __align__(16) float Ps[4][8][64];

    int bid = blockIdx.x;
    int qt = bid & 63;            // 64 tiles of 32 queries
    int h  = (bid >> 6) & 7;
    int b  = bid >> 9;
    int i0 = qt * 32;
    int tid = threadIdx.x;
    int w = tid >> 6, lane = tid & 63;
    const int* pad = pad_all + b * S_;

    // stage Q (scaled)
#pragma unroll
    for (int p = 0; p < 2; ++p) {
        int r = p * 16 + (tid >> 4);
        int f = tid & 15;
        float4 qv = *(const float4*)(Q + ((size_t)(b * S_ + i0 + r)) * D_ + h * HD_ + f * 4);
        qv.x *= 0.125f; qv.y *= 0.125f; qv.z *= 0.125f; qv.w *= 0.125f;
        *(float4*)&Qs[r][f * 4] = qv;
    }

    float m[8], l[8], acc[8], facs[8];
#pragma unroll
    for (int q = 0; q < 8; ++q) { m[q] = MINF_; l[q] = 0.0f; acc[q] = 0.0f; }

    for (int r = 0; r < 3; ++r) {
        __syncthreads();
        // stage K/V: 64 rows x 64 cols
#pragma unroll
        for (int p = 0; p < 4; ++p) {
            int row = p * 16 + (tid >> 4);
            int f = tid & 15;
            int j = (r == 0) ? (i0 - 4 + row) : (SL_ + (r - 1) * 64 + row);
            int jc = j < 0 ? 0 : (j > SL_ - 1 && r == 0 ? SL_ - 1 : j);
            size_t off = ((size_t)(b * S_ + jc)) * D_ + h * HD_ + f * 4;
            float4 kv = *(const float4*)(Kb + off);
            float4 vv = *(const float4*)(Vb + off);
            Ks[row][f * 4 + 0] = kv.x; Ks[row][f * 4 + 1] = kv.y;
            Ks[row][f * 4 + 2] = kv.z; Ks[row][f * 4 + 3] = kv.w;
            Vs[row][f * 4 + 0] = vv.x; Vs[row][f * 4 + 1] = vv.y;
            Vs[row][f * 4 + 2] = vv.z; Vs[row][f * 4 + 3] = vv.w;
        }
        __syncthreads();

        // ---- phase 1: lane = key slot
        int j = (r == 0) ? (i0 - 4 + lane) : (SL_ + (r - 1) * 64 + lane);
        float s[8] = {};
#pragma unroll
        for (int d4 = 0; d4 < 16; ++d4) {
            float k0 = Ks[lane][d4 * 4 + 0];
            float k1 = Ks[lane][d4 * 4 + 1];
            float k2 = Ks[lane][d4 * 4 + 2];
            float k3 = Ks[lane][d4 * 4 + 3];
#pragma unroll
            for (int q = 0; q < 8; ++q) {
                float4 qv = *(const float4*)&Qs[w * 8 + q][d4 * 4];
                s[q] = fmaf(qv.x, k0, fmaf(qv.y, k1, fmaf(qv.z, k2, fmaf(qv.w, k3, s[q]))));
            }
        }
        int jok = (r == 0) ? (j >= 0 && j < SL_) : 1;
        int padj = jok ? pad[j] : 1;
#pragma unroll
        for (int q = 0; q < 8; ++q) {
            int qi = w * 8 + q;
            float sv;
            if (r == 0) {
                int rel = lane - qi;                     // dist + 4
                if (rel >= 0 && rel <= 8 && jok)
                    sv = padj ? NEG_ : s[q] + relb[h * (2 * KCLIP_ + 1) + rel];
                else
                    sv = MINF_;
            } else {
                sv = padj ? NEG_ : s[q];
            }
            float rmax = wave_max(sv);
            float mnew = fmaxf(m[q], rmax);
            float fac = __expf(m[q] - mnew);
            float pv = __expf(sv - mnew);
            float psum = wave_sum(pv);
            l[q] = l[q] * fac + psum;
            m[q] = mnew;
            facs[q] = fac;
            Ps[w][q][lane] = pv;
        }
        __syncthreads();

        // ---- phase 2: lane = dim
        int d = lane;
#pragma unroll
        for (int q = 0; q < 8; ++q) acc[q] *= facs[q];
#pragma unroll
        for (int j4 = 0; j4 < 16; ++j4) {
            float v0 = Vs[j4 * 4 + 0][d];
            float v1 = Vs[j4 * 4 + 1][d];
            float v2 = Vs[j4 * 4 + 2][d];
            float v3 = Vs[j4 * 4 + 3][d];
#pragma unroll
            for (int q = 0; q < 8; ++q) {
                float4 p4 = *(const float4*)&Ps[w][q][j4 * 4];
                acc[q] = fmaf(p4.x, v0, fmaf(p4.y, v1, fmaf(p4.z, v2, fmaf(p4.w, v3, acc[q]))));
            }
        }
    }
#pragma unroll
    for (int q = 0; q < 8; ++q) {
        int i = i0 + w * 8 + q;
        O[((size_t)(b * S_ + i)) * D_ + h * HD_ + lane] = acc[q] / l[q];
    }
}

// ------------------------------------------- global queries (i >= SL), split-K
// grid: KC_ chunks * 4 qtiles * 8 h * 2 b = 256 blocks.
__global__ __launch_bounds__(256) void attn_global_kernel(const float* __restrict__ Q,
                                                          const float* __restrict__ Kb,
                                                          const float* __restrict__ Vb,
                                                          const int* __restrict__ pad_all,
                                                          float* __restrict__ pacc,
                                                          float* __restrict__ pm,
                                                          float* __restrict__ pl) {
    __shared__ float Ks[64][PADK_];
    __shared__ float Vs[64][PADK_];
    __shared__ __align__(16) float Qs[32][64];
    __shared__ __align__(16) float Ps[4][8][64];

    const int TS[KC_ + 1] = {0, 8, 17, 25, 34};

    int bid = blockIdx.x;
    int c  = bid & 3;             // key chunk
    int qt = (bid >> 2) & 3;      // 4 tiles of 32 global queries
    int h  = (bid >> 4) & 7;
    int b  = bid >> 7;
    int i0 = SL_ + qt * 32;
    int tid = threadIdx.x;
    int w = tid >> 6, lane = tid & 63;
    const int* pad = pad_all + b * S_;

#pragma unroll
    for (int p = 0; p < 2; ++p) {
        int r = p * 16 + (tid >> 4);
        int f = tid & 15;
        float4 qv = *(const float4*)(Q + ((size_t)(b * S_ + i0 + r)) * D_ + h * HD_ + f * 4);
        qv.x *= 0.125f; qv.y *= 0.125f; qv.z *= 0.125f; qv.w *= 0.125f;
        *(float4*)&Qs[r][f * 4] = qv;
    }

    float m[8], l[8], acc[8], facs[8];
#pragma unroll
    for (int q = 0; q < 8; ++q) { m[q] = MINF_; l[q] = 0.0f; acc[q] = 0.0f; }

    for (int t = TS[c]; t < TS[c + 1]; ++t) {
        int j0 = t * 64;
        __syncthreads();
#pragma unroll
        for (int p = 0; p < 4; ++p) {
            int row = p * 16 + (tid >> 4);
            int f = tid & 15;
            size_t off = ((size_t)(b * S_ + j0 + row)) * D_ + h * HD_ + f * 4;
            float4 kv = *(const float4*)(Kb + off);
            float4 vv = *(const float4*)(Vb + off);
            Ks[row][f * 4 + 0] = kv.x; Ks[row][f * 4 + 1] = kv.y;
            Ks[row][f * 4 + 2] = kv.z; Ks[row][f * 4 + 3] = kv.w;
            Vs[row][f * 4 + 0] = vv.x; Vs[row][f * 4 + 1] = vv.y;
            Vs[row][f * 4 + 2] = vv.z; Vs[row][f * 4 + 3] = vv.w;
        }
        __syncthreads();

        float s[8] = {};
#pragma unroll
        for (int d4 = 0; d4 < 16; ++d4) {
            float k0 = Ks[lane][d4 * 4 + 0];
            float k1 = Ks[lane][d4 * 4 + 1];
            float k2 = Ks[lane][d4 * 4 + 2];
            float k3 = Ks[lane][d4 * 4 + 3];
#pragma unroll
            for (int q = 0; q < 8; ++q) {
                float4 qv = *(const float4*)&Qs[w * 8 + q][d4 * 4];
                s[q] = fmaf(qv.x, k0, fmaf(qv.y, k1, fmaf(qv.z, k2, fmaf(qv.w, k3, s[q]))));
            }
        }
        int padj = pad[j0 + lane];
#pragma unroll
        for (int q = 0; q < 8; ++q) {
            float sv = padj ? NEG_ : s[q];
            float rmax = wave_max(sv);
            float mnew = fmaxf(m[q], rmax);
            float fac = __expf(m[q] - mnew);
            float pv = __expf(sv - mnew);
            float psum = wave_sum(pv);
            l[q] = l[q] * fac + psum;
            m[q] = mnew;
            facs[q] = fac;
            Ps[w][q][lane] = pv;
        }
        __syncthreads();

        int d = lane;
#pragma unroll
        for (int q = 0; q < 8; ++q) acc[q] *= facs[q];
#pragma unroll
        for (int j4 = 0; j4 < 16; ++j4) {
            float v0 = Vs[j4 * 4 + 0][d];
            float v1 = Vs[j4 * 4 + 1][d];
            float v2 = Vs[j4 * 4 + 2][d];
            float v3 = Vs[j4 * 4 + 3][d];
#pragma unroll
            for (int q = 0; q < 8; ++q) {
                float4 p4 = *(const float4*)&Ps[w][q][j4 * 4];
                acc[q] = fmaf(p4.x, v0, fmaf(p4.y, v1, fmaf(p4.z, v2, fmaf(p4.w, v3, acc[q]))));
            }
        }
    }
#pragma unroll
    for (int q = 0; q < 8; ++q) {
        int gq = qt * 32 + w * 8 + q;
        int pidx = ((c * B_ + b) * H_ + h) * SG_ + gq;
        pacc[(size_t)pidx * HD_ + lane] = acc[q];
        if (lane == 0) { pm[pidx] = m[q]; pl[pidx] = l[q]; }
    }
}

// ------------------------------------------- merge split-K partials
__global__ __launch_bounds__(256) void attn_combine_kernel(const float* __restrict__ pacc,
                                                           const float* __restrict__ pm,
                                                           const float* __restrict__ pl,
                                                           float* __restrict__ O) {
    int wave = (int)((blockIdx.x * (size_t)blockDim.x + threadIdx.x) >> 6);
    int lane = threadIdx.x & 63;
    // wave -> (b,h,gq)
    int gq = wave & (SG_ - 1);
    int h  = (wave >> 7) & 7;
    int b  = wave >> 10;

    float M = MINF_;
#pragma unroll
    for (int c = 0; c < KC_; ++c) {
        int pidx = ((c * B_ + b) * H_ + h) * SG_ + gq;
        M = fmaxf(M, pm[pidx]);
    }
    float L = 0.0f, Ov = 0.0f;
#pragma unroll
    for (int c = 0; c < KC_; ++c) {
        int pidx = ((c * B_ + b) * H_ + h) * SG_ + gq;
        float e = __expf(pm[pidx] - M);
        L += pl[pidx] * e;
        Ov += pacc[(size_t)pidx * HD_ + lane] * e;
    }
    O[((size_t)(b * S_ + SL_ + gq)) * D_ + h * HD_ + lane] = Ov / L;
}

// ---------------------------------------------------------------- residual + LN
__global__ __launch_bounds__(256) void ln_kernel(const float* __restrict__ A,
                                                 const float* __restrict__ Bres,
                                                 const float* __restrict__ g,
                                                 const float* __restrict__ be,
                                                 float* __restrict__ out) {
    int row = blockIdx.x;
    int tid = threadIdx.x;
    size_t base = (size_t)row * D_;
    float x0 = A[base + tid]       + Bres[base + tid];
    float x1 = A[base + tid + 256] + Bres[base + tid + 256];
    float s1 = x0 + x1;
    float s2 = x0 * x0 + x1 * x1;
    for (int off = 1; off < 64; off <<= 1) {
        s1 += __shfl_xor(s1, off);
        s2 += __shfl_xor(s2, off);
    }
    __shared__ float ws1[4], ws2[4];
    int wid = tid >> 6;
    if ((tid & 63) == 0) { ws1[wid] = s1; ws2[wid] = s2; }
    __syncthreads();
    s1 = ws1[0] + ws1[1] + ws1[2] + ws1[3];
    s2 = ws2[0] + ws2[1] + ws2[2] + ws2[3];
    float mean = s1 * (1.0f / D_);
    float var  = s2 * (1.0f / D_) - mean * mean;
    float rstd = rsqrtf(var + 1e-5f);
    out[base + tid]       = (x0 - mean) * rstd * g[tid]       + be[tid];
    out[base + tid + 256] = (x1 - mean) * rstd * g[tid + 256] + be[tid + 256];
}

// ---------------------------------------------------------------- pool + classifier
__global__ __launch_bounds__(256) void pool_cls_kernel(const float* __restrict__ x2,
                                                       const int* __restrict__ pad_all,
                                                       const float* __restrict__ w1,
                                                       const float* __restrict__ w2,
                                                       float* __restrict__ out) {
    int b = blockIdx.x;
    int tid = threadIdx.x;
    __shared__ float zg[D_];
    __shared__ int cnt_s;
    if (tid == 0) {
        int c = 0;
        for (int g = 0; g < SG_; ++g) c += pad_all[b * S_ + SL_ + g] ? 0 : 1;
        cnt_s = c;
    }
    float acc0 = 0.0f, acc1 = 0.0f;
    for (int g = 0; g < SG_; ++g) {
        if (!pad_all[b * S_ + SL_ + g]) {
            size_t base = ((size_t)(b * S_ + SL_ + g)) * D_;
            acc0 += x2[base + tid];
            acc1 += x2[base + tid + 256];
        }
    }
    __syncthreads();
    float inv = 1.0f / (float)cnt_s;
    zg[tid]       = acc0 * inv;
    zg[tid + 256] = acc1 * inv;
    __syncthreads();
    float hsum = 0.0f;
    for (int d = 0; d < D_; ++d)
        hsum = fmaf(zg[d], w1[(size_t)d * 256 + tid], hsum);
    hsum = fmaxf(hsum, 0.0f);
    float o0 = hsum * w2[(size_t)tid * NC_ + 0];
    float o1 = hsum * w2[(size_t)tid * NC_ + 1];
    for (int off = 1; off < 64; off <<= 1) {
        o0 += __shfl_xor(o0, off);
        o1 += __shfl_xor(o1, off);
    }
    __shared__ float r0[4], r1[4];
    if ((tid & 63) == 0) { r0[tid >> 6] = o0; r1[tid >> 6] = o1; }
    __syncthreads();
    if (tid == 0) {
        out[b * NC_ + 0] = r0[0] + r0[1] + r0[2] + r0[3];
        out[b * NC_ + 1] = r1[0] + r1[1] + r1[2] + r1[3];
    }
}

// ---------------------------------------------------------------- launch
extern "C" void kernel_launch(void* const* d_in, const int* in_sizes, int n_in,
                              void* d_out, int out_size, void* d_ws, size_t ws_size,
                              hipStream_t stream) {
    const int*   ids    = (const int*)d_in[0];
    const float* embed  = (const float*)d_in[1];
    const float* gtok   = (const float*)d_in[2];
    const float* relb   = (const float*)d_in[3];
    const float* q_w    = (const float*)d_in[4];
    const float* q_b    = (const float*)d_in[5];
    const float* k_w    = (const float*)d_in[6];
    const float* k_b    = (const float*)d_in[7];
    const float* v_w    = (const float*)d_in[8];
    const float* v_b    = (const float*)d_in[9];
    const float* o_w    = (const float*)d_in[10];
    const float* o_b    = (const float*)d_in[11];
    const float* ln1_g  = (const float*)d_in[12];
    const float* ln1_b  = (const float*)d_in[13];
    const float* ln2_g  = (const float*)d_in[14];
    const float* ln2_b  = (const float*)d_in[15];
    const float* ff1_w  = (const float*)d_in[16];
    const float* ff1_b  = (const float*)d_in[17];
    const float* ff2_w  = (const float*)d_in[18];
    const float* ff2_b  = (const float*)d_in[19];
    const float* cls_w1 = (const float*)d_in[20];
    const float* cls_w2 = (const float*)d_in[21];

    char* ws = (char*)d_ws;
    const size_t SLOT = (size_t)MROWS_ * D_ * sizeof(float);   // 8,912,896 B
    float* x    = (float*)(ws + 0 * SLOT);
    float* q    = (float*)(ws + 1 * SLOT);
    float* k    = (float*)(ws + 2 * SLOT);
    float* v    = (float*)(ws + 3 * SLOT);
    float* o    = (float*)(ws + 4 * SLOT);
    float* tmp  = q;
    float* x1   = k;
    float* ffh  = v;        // slots 3+4 contiguous for FF hidden
    float* tmp2 = x;
    float* x2   = q;
    int* pad_all = (int*)(ws + 5 * SLOT);
    char* extra  = ws + 5 * SLOT + 65536;
    float* pacc = (float*)extra;                                   // [KC_*B_*H_*SG_][64]
    float* pm   = (float*)(extra + (size_t)KC_ * B_ * H_ * SG_ * HD_ * 4);
    float* pl   = pm + KC_ * B_ * H_ * SG_;

    build_x_kernel<<<MROWS_, 128, 0, stream>>>(ids, embed, gtok, x, pad_all);

    gemm_kernel<<<dim3(D_ / 64, MROWS_ / 64), 256, 0, stream>>>(x, q_w, q_b, q, MROWS_, D_, D_, 0);
    gemm_kernel<<<dim3(D_ / 64, MROWS_ / 64), 256, 0, stream>>>(x, k_w, k_b, k, MROWS_, D_, D_, 0);
    gemm_kernel<<<dim3(D_ / 64, MROWS_ / 64), 256, 0, stream>>>(x, v_w, v_b, v, MROWS_, D_, D_, 0);

    attn_long_kernel<<<B_ * H_ * 64, 256, 0, stream>>>(q, k, v, relb, pad_all, o);
    attn_global_kernel<<<B_ * H_ * 4 * KC_, 256, 0, stream>>>(q, k, v, pad_all, pacc, pm, pl);
    attn_combine_kernel<<<(B_ * H_ * SG_) / 4, 256, 0, stream>>>(pacc, pm, pl, o);

    gemm_kernel<<<dim3(D_ / 64, MROWS_ / 64), 256, 0, stream>>>(o, o_w, o_b, tmp, MROWS_, D_, D_, 0);
    ln_kernel<<<MROWS_, 256, 0, stream>>>(x, tmp, ln1_g, ln1_b, x1);

    gemm_kernel<<<dim3(FF_ / 64, MROWS_ / 64), 256, 0, stream>>>(x1, ff1_w, ff1_b, ffh, MROWS_, D_, FF_, 1);
    gemm_kernel<<<dim3(D_ / 64, MROWS_ / 64), 256, 0, stream>>>(ffh, ff2_w, ff2_b, tmp2, MROWS_, FF_, D_, 0);
    ln_kernel<<<MROWS_, 256, 0, stream>>>(x1, tmp2, ln2_g, ln2_b, x2);

    pool_cls_kernel<<<B_, 256, 0, stream>>>(x2, pad_all, cls_w1, cls_w2, (float*)d_out);
}

// Round 3
// 445.515 us; speedup vs baseline: 3.1955x; 1.6420x over previous
//
#include <hip/hip_runtime.h>
#include <hip/hip_bf16.h>
#include <cstddef>

#define B_ 2
#define SL_ 2048
#define RATIO_ 16
#define SG_ 128
#define S_ 2176
#define D_ 512
#define H_ 8
#define HD_ 64
#define FF_ 1024
#define KCLIP_ 4
#define RAD_ 4
#define NC_ 2
#define NEG_ (-1.0e9f)
#define MINF_ (-1.0e30f)
#define MROWS_ (B_ * S_)   // 4352
#define KC_ 4              // split-K chunks for global-query attention
#define QKVLD_ 1536        // fused QKV row stride
#define PADK_ 65

typedef __attribute__((ext_vector_type(8))) short short8;
typedef __attribute__((ext_vector_type(4))) float f32x4;

__device__ __forceinline__ void gll16(const void* g, void* l) {
    __builtin_amdgcn_global_load_lds((const __attribute__((address_space(1))) void*)g,
                                     (__attribute__((address_space(3))) void*)l, 16, 0, 0);
}

// ---------------------------------------------------------------- build x (f32 + bf16) + pad
__global__ void build_x_kernel(const int* __restrict__ ids,
                               const float* __restrict__ embed,
                               const float* __restrict__ gtok,
                               float* __restrict__ x,
                               __hip_bfloat16* __restrict__ xb,
                               int* __restrict__ pad_all) {
    int row = blockIdx.x;
    int b = row / S_, s = row % S_;
    const float* src;
    if (s < SL_) {
        int tok = ids[b * SL_ + s];
        src = embed + (size_t)tok * D_;
        if (threadIdx.x == 0) pad_all[row] = (tok == 0) ? 1 : 0;
    } else {
        src = gtok;
        if (threadIdx.x == 0) {
            int g = s - SL_;
            int allz = 1;
            for (int r = 0; r < RATIO_; ++r)
                allz &= (ids[b * SL_ + g * RATIO_ + r] == 0) ? 1 : 0;
            pad_all[row] = allz;
        }
    }
    float4 v = ((const float4*)src)[threadIdx.x];
    ((float4*)(x + (size_t)row * D_))[threadIdx.x] = v;
    __hip_bfloat16 hb[4] = {__float2bfloat16(v.x), __float2bfloat16(v.y),
                            __float2bfloat16(v.z), __float2bfloat16(v.w)};
    *(uint2*)(xb + (size_t)row * D_ + threadIdx.x * 4) = *(const uint2*)hb;
}

// ---------------------------------------------------------------- weight transpose+convert
// in: W f32 [K][N] row-major; out: Wt bf16 [N][K] (caller pre-offsets out rows)
__global__ __launch_bounds__(256) void wt_kernel(const float* __restrict__ W,
                                                 __hip_bfloat16* __restrict__ Wt,
                                                 int K, int N) {
    __shared__ float tile[64][65];
    int n0 = blockIdx.x * 64, k0 = blockIdx.y * 64;
    int t = threadIdx.x, c = t & 63, r4 = t >> 6;
#pragma unroll
    for (int i = 0; i < 16; ++i) {
        int r = i * 4 + r4;
        tile[r][c] = W[(size_t)(k0 + r) * N + n0 + c];
    }
    __syncthreads();
#pragma unroll
    for (int i = 0; i < 16; ++i) {
        int n = i * 4 + r4;
        Wt[(size_t)(n0 + n) * K + k0 + c] = __float2bfloat16(tile[c][n]);
    }
}

__global__ void bias_concat_kernel(const float* __restrict__ qb,
                                   const float* __restrict__ kb,
                                   const float* __restrict__ vb,
                                   float* __restrict__ out) {
    int i = blockIdx.x * 256 + threadIdx.x;   // 0..1535
    float v = (i < 512) ? qb[i] : (i < 1024 ? kb[i - 512] : vb[i - 1024]);
    out[i] = v;
}

// ---------------------------------------------------------------- bf16 MFMA GEMM (B^T form)
// C[M,N] = A[M,K](bf16) @ Bt[N,K](bf16)^T + bias. 128x128 tile, BK=32, 4 waves.
// flags: 1 = relu, 2 = bf16 output
__global__ __launch_bounds__(256) void gemm_bt_kernel(const __hip_bfloat16* __restrict__ A,
                                                      const __hip_bfloat16* __restrict__ Bt,
                                                      const float* __restrict__ bias,
                                                      void* __restrict__ Cout,
                                                      int N, int K, int flags) {
    __shared__ short As[128 * 32];
    __shared__ short Bs[128 * 32];
    int tid = threadIdx.x;
    int m0 = blockIdx.y * 128, n0 = blockIdx.x * 128;
    int w = tid >> 6, lane = tid & 63;
    int wr = w >> 1, wc = w & 1;

    f32x4 acc[4][4];
#pragma unroll
    for (int m = 0; m < 4; ++m)
#pragma unroll
        for (int n = 0; n < 4; ++n)
            acc[m][n] = (f32x4){0.f, 0.f, 0.f, 0.f};

    int p0 = tid * 16;          // byte offset of this thread's first 16B chunk
    int rs = p0 >> 6;           // staging row (64B per row of 32 bf16)
    int cs = p0 & 63;           // byte col within row
    const char* Ab = (const char*)A;
    const char* Bb = (const char*)Bt;

    for (int k0 = 0; k0 < K; k0 += 32) {
        __syncthreads();
        gll16(Ab + ((size_t)(m0 + rs) * K + k0) * 2 + cs, (char*)As + p0);
        gll16(Ab + ((size_t)(m0 + rs + 64) * K + k0) * 2 + cs, (char*)As + p0 + 4096);
        gll16(Bb + ((size_t)(n0 + rs) * K + k0) * 2 + cs, (char*)Bs + p0);
        gll16(Bb + ((size_t)(n0 + rs + 64) * K + k0) * 2 + cs, (char*)Bs + p0 + 4096);
        __syncthreads();
        short8 af[4], bfr[4];
#pragma unroll
        for (int m = 0; m < 4; ++m)
            af[m] = *(const short8*)&As[(wr * 64 + m * 16 + (lane & 15)) * 32 + (lane >> 4) * 8];
#pragma unroll
        for (int n = 0; n < 4; ++n)
            bfr[n] = *(const short8*)&Bs[(wc * 64 + n * 16 + (lane & 15)) * 32 + (lane >> 4) * 8];
#pragma unroll
        for (int m = 0; m < 4; ++m)
#pragma unroll
            for (int n = 0; n < 4; ++n)
                acc[m][n] = __builtin_amdgcn_mfma_f32_16x16x32_bf16(af[m], bfr[n], acc[m][n], 0, 0, 0);
    }

    int rbase = m0 + wr * 64 + (lane >> 4) * 4;
    int cbase = n0 + wc * 64 + (lane & 15);
#pragma unroll
    for (int m = 0; m < 4; ++m)
#pragma unroll
        for (int n = 0; n < 4; ++n) {
            int col = cbase + n * 16;
            float bv = bias[col];
#pragma unroll
            for (int j = 0; j < 4; ++j) {
                int row = rbase + m * 16 + j;
                float v = acc[m][n][j] + bv;
                if (flags & 1) v = fmaxf(v, 0.0f);
                if (flags & 2)
                    ((__hip_bfloat16*)Cout)[(size_t)row * N + col] = __float2bfloat16(v);
                else
                    ((float*)Cout)[(size_t)row * N + col] = v;
            }
        }
}

// ================================================================ attention (f32, QKV fused layout)
__device__ __forceinline__ float wave_max(float v) {
#pragma unroll
    for (int off = 1; off < 64; off <<= 1) v = fmaxf(v, __shfl_xor(v, off));
    return v;
}
__device__ __forceinline__ float wave_sum(float v) {
#pragma unroll
    for (int off = 1; off < 64; off <<= 1) v += __shfl_xor(v, off);
    return v;
}

// ------------------------------------------- long queries
__global__ __launch_bounds__(256) void attn_long_kernel(const float* __restrict__ QKV,
                                                        const float* __restrict__ relb,
                                                        const int* __restrict__ pad_all,
                                                        __hip_bfloat16* __restrict__ Ob) {
    __shared__ float Ks[64][PADK_];
    __shared__ float Vs[64][PADK_];
    __shared__ __align__(16) float Qs[32][64];
    __shared__ __align__(16) float Ps[4][8][64];

    int bid = blockIdx.x;
    int qt = bid & 63, h = (bid >> 6) & 7, b = bid >> 9;
    int i0 = qt * 32;
    int tid = threadIdx.x, w = tid >> 6, lane = tid & 63;
    const int* pad = pad_all + b * S_;

#pragma unroll
    for (int p = 0; p < 2; ++p) {
        int r = p * 16 + (tid >> 4);
        int f = tid & 15;
        float4 qv = *(const float4*)(QKV + (size_t)(b * S_ + i0 + r) * QKVLD_ + h * HD_ + f * 4);
        qv.x *= 0.125f; qv.y *= 0.125f; qv.z *= 0.125f; qv.w *= 0.125f;
        *(float4*)&Qs[r][f * 4] = qv;
    }

    float m[8], l[8], acc[8];
#pragma unroll
    for (int q = 0; q < 8; ++q) { m[q] = MINF_; l[q] = 0.0f; acc[q] = 0.0f; }

    for (int r = 0; r < 3; ++r) {
        __syncthreads();
        {
            int f = tid & 15;
#pragma unroll
            for (int p = 0; p < 4; ++p) {
                int row = p * 16 + (tid >> 4);
                int j = (r == 0) ? (i0 - 4 + row) : (SL_ + (r - 1) * 64 + row);
                int jc = j < 0 ? 0 : (j > SL_ - 1 && r == 0 ? SL_ - 1 : j);
                size_t base = (size_t)(b * S_ + jc) * QKVLD_ + h * HD_;
                float4 kv = *(const float4*)(QKV + base + 512 + f * 4);
                float4 vv = *(const float4*)(QKV + base + 1024 + f * 4);
                Ks[row][f * 4 + 0] = kv.x; Ks[row][f * 4 + 1] = kv.y;
                Ks[row][f * 4 + 2] = kv.z; Ks[row][f * 4 + 3] = kv.w;
                Vs[row][f * 4 + 0] = vv.x; Vs[row][f * 4 + 1] = vv.y;
                Vs[row][f * 4 + 2] = vv.z; Vs[row][f * 4 + 3] = vv.w;
            }
        }
        __syncthreads();

        // phase 1: lane = key slot; K row in registers, Q via uniform broadcast
        float kreg[64];
#pragma unroll
        for (int c = 0; c < 64; ++c) kreg[c] = Ks[lane][c];
        float sv[8];
#pragma unroll
        for (int q = 0; q < 8; ++q) {
            float s = 0.0f;
#pragma unroll
            for (int d4 = 0; d4 < 16; ++d4) {
                float4 qv = *(const float4*)&Qs[w * 8 + q][d4 * 4];
                s = fmaf(qv.x, kreg[d4 * 4 + 0],
                    fmaf(qv.y, kreg[d4 * 4 + 1],
                    fmaf(qv.z, kreg[d4 * 4 + 2],
                    fmaf(qv.w, kreg[d4 * 4 + 3], s))));
            }
            sv[q] = s;
        }
        int j = (r == 0) ? (i0 - 4 + lane) : (SL_ + (r - 1) * 64 + lane);
        int jok = (r == 0) ? (j >= 0 && j < SL_) : 1;
        int padj = jok ? pad[j] : 1;
        float facs[8];
#pragma unroll
        for (int q = 0; q < 8; ++q) {
            int qi = w * 8 + q;
            float s;
            if (r == 0) {
                int rel = lane - qi;
                if (rel >= 0 && rel <= 8 && jok)
                    s = padj ? NEG_ : sv[q] + relb[h * (2 * KCLIP_ + 1) + rel];
                else
                    s = MINF_;
            } else {
                s = padj ? NEG_ : sv[q];
            }
            float rmax = wave_max(s);
            float mnew = fmaxf(m[q], rmax);
            float fac = __expf(m[q] - mnew);
            float pv = __expf(s - mnew);
            float psum = wave_sum(pv);
            l[q] = l[q] * fac + psum;
            m[q] = mnew;
            facs[q] = fac;
            Ps[w][q][lane] = pv;
        }

        // phase 2: lane = dim; V column in registers, P via uniform broadcast
        float vreg[64];
#pragma unroll
        for (int c = 0; c < 64; ++c) vreg[c] = Vs[c][lane];
#pragma unroll
        for (int q = 0; q < 8; ++q) {
            float a = acc[q] * facs[q];
#pragma unroll
            for (int j4 = 0; j4 < 16; ++j4) {
                float4 p4 = *(const float4*)&Ps[w][q][j4 * 4];
                a = fmaf(p4.x, vreg[j4 * 4 + 0],
                    fmaf(p4.y, vreg[j4 * 4 + 1],
                    fmaf(p4.z, vreg[j4 * 4 + 2],
                    fmaf(p4.w, vreg[j4 * 4 + 3], a))));
            }
            acc[q] = a;
        }
    }
#pragma unroll
    for (int q = 0; q < 8; ++q) {
        int i = i0 + w * 8 + q;
        Ob[(size_t)(b * S_ + i) * D_ + h * HD_ + lane] = __float2bfloat16(acc[q] / l[q]);
    }
}

// ------------------------------------------- global queries, split-K
__global__ __launch_bounds__(256) void attn_global_kernel(const float* __restrict__ QKV,
                                                          const int* __restrict__ pad_all,
                                                          float* __restrict__ pacc,
                                                          float* __restrict__ pm,
                                                          float* __restrict__ pl) {
    __shared__ float Ks[64][PADK_];
    __shared__ float Vs[64][PADK_];
    __shared__ __align__(16) float Qs[32][64];
    __shared__ __align__(16) float Ps[4][8][64];

    int bid = blockIdx.x;
    int c  = bid & 3;
    int qt = (bid >> 2) & 3;
    int h  = (bid >> 4) & 7;
    int b  = bid >> 7;
    int i0 = SL_ + qt * 32;
    int tid = threadIdx.x, w = tid >> 6, lane = tid & 63;
    const int* pad = pad_all + b * S_;

#pragma unroll
    for (int p = 0; p < 2; ++p) {
        int r = p * 16 + (tid >> 4);
        int f = tid & 15;
        float4 qv = *(const float4*)(QKV + (size_t)(b * S_ + i0 + r) * QKVLD_ + h * HD_ + f * 4);
        qv.x *= 0.125f; qv.y *= 0.125f; qv.z *= 0.125f; qv.w *= 0.125f;
        *(float4*)&Qs[r][f * 4] = qv;
    }

    float m[8], l[8], acc[8];
#pragma unroll
    for (int q = 0; q < 8; ++q) { m[q] = MINF_; l[q] = 0.0f; acc[q] = 0.0f; }

    int t0 = (c * 34) >> 2, t1 = ((c + 1) * 34) >> 2;
    for (int t = t0; t < t1; ++t) {
        int j0 = t * 64;
        __syncthreads();
        {
            int f = tid & 15;
#pragma unroll
            for (int p = 0; p < 4; ++p) {
                int row = p * 16 + (tid >> 4);
                size_t base = (size_t)(b * S_ + j0 + row) * QKVLD_ + h * HD_;
                float4 kv = *(const float4*)(QKV + base + 512 + f * 4);
                float4 vv = *(const float4*)(QKV + base + 1024 + f * 4);
                Ks[row][f * 4 + 0] = kv.x; Ks[row][f * 4 + 1] = kv.y;
                Ks[row][f * 4 + 2] = kv.z; Ks[row][f * 4 + 3] = kv.w;
                Vs[row][f * 4 + 0] = vv.x; Vs[row][f * 4 + 1] = vv.y;
                Vs[row][f * 4 + 2] = vv.z; Vs[row][f * 4 + 3] = vv.w;
            }
        }
        __syncthreads();

        float kreg[64];
#pragma unroll
        for (int cc = 0; cc < 64; ++cc) kreg[cc] = Ks[lane][cc];
        float sv[8];
#pragma unroll
        for (int q = 0; q < 8; ++q) {
            float s = 0.0f;
#pragma unroll
            for (int d4 = 0; d4 < 16; ++d4) {
                float4 qv = *(const float4*)&Qs[w * 8 + q][d4 * 4];
                s = fmaf(qv.x, kreg[d4 * 4 + 0],
                    fmaf(qv.y, kreg[d4 * 4 + 1],
                    fmaf(qv.z, kreg[d4 * 4 + 2],
                    fmaf(qv.w, kreg[d4 * 4 + 3], s))));
            }
            sv[q] = s;
        }
        int padj = pad[j0 + lane];
        float facs[8];
#pragma unroll
        for (int q = 0; q < 8; ++q) {
            float s = padj ? NEG_ : sv[q];
            float rmax = wave_max(s);
            float mnew = fmaxf(m[q], rmax);
            float fac = __expf(m[q] - mnew);
            float pv = __expf(s - mnew);
            float psum = wave_sum(pv);
            l[q] = l[q] * fac + psum;
            m[q] = mnew;
            facs[q] = fac;
            Ps[w][q][lane] = pv;
        }

        float vreg[64];
#pragma unroll
        for (int cc = 0; cc < 64; ++cc) vreg[cc] = Vs[cc][lane];
#pragma unroll
        for (int q = 0; q < 8; ++q) {
            float a = acc[q] * facs[q];
#pragma unroll
            for (int j4 = 0; j4 < 16; ++j4) {
                float4 p4 = *(const float4*)&Ps[w][q][j4 * 4];
                a = fmaf(p4.x, vreg[j4 * 4 + 0],
                    fmaf(p4.y, vreg[j4 * 4 + 1],
                    fmaf(p4.z, vreg[j4 * 4 + 2],
                    fmaf(p4.w, vreg[j4 * 4 + 3], a))));
            }
            acc[q] = a;
        }
    }
#pragma unroll
    for (int q = 0; q < 8; ++q) {
        int gq = qt * 32 + w * 8 + q;
        int pidx = ((c * B_ + b) * H_ + h) * SG_ + gq;
        pacc[(size_t)pidx * HD_ + lane] = acc[q];
        if (lane == 0) { pm[pidx] = m[q]; pl[pidx] = l[q]; }
    }
}

__global__ __launch_bounds__(256) void attn_combine_kernel(const float* __restrict__ pacc,
                                                           const float* __restrict__ pm,
                                                           const float* __restrict__ pl,
                                                           __hip_bfloat16* __restrict__ Ob) {
    int wave = (int)((blockIdx.x * (size_t)blockDim.x + threadIdx.x) >> 6);
    int lane = threadIdx.x & 63;
    int gq = wave & (SG_ - 1);
    int h  = (wave >> 7) & 7;
    int b  = wave >> 10;

    float M = MINF_;
#pragma unroll
    for (int c = 0; c < KC_; ++c) {
        int pidx = ((c * B_ + b) * H_ + h) * SG_ + gq;
        M = fmaxf(M, pm[pidx]);
    }
    float L = 0.0f, Ov = 0.0f;
#pragma unroll
    for (int c = 0; c < KC_; ++c) {
        int pidx = ((c * B_ + b) * H_ + h) * SG_ + gq;
        float e = __expf(pm[pidx] - M);
        L += pl[pidx] * e;
        Ov += pacc[(size_t)pidx * HD_ + lane] * e;
    }
    Ob[(size_t)(b * S_ + SL_ + gq) * D_ + h * HD_ + lane] = __float2bfloat16(Ov / L);
}

// ---------------------------------------------------------------- residual + LN (f32 out, optional bf16 out)
__global__ __launch_bounds__(256) void ln_kernel(const float* __restrict__ A,
                                                 const float* __restrict__ Bres,
                                                 const float* __restrict__ g,
                                                 const float* __restrict__ be,
                                                 float* __restrict__ out,
                                                 __hip_bfloat16* __restrict__ outb,
                                                 int wb) {
    int row = blockIdx.x;
    int tid = threadIdx.x;
    size_t base = (size_t)row * D_;
    float x0 = A[base + tid]       + Bres[base + tid];
    float x1 = A[base + tid + 256] + Bres[base + tid + 256];
    float s1 = x0 + x1;
    float s2 = x0 * x0 + x1 * x1;
    for (int off = 1; off < 64; off <<= 1) {
        s1 += __shfl_xor(s1, off);
        s2 += __shfl_xor(s2, off);
    }
    __shared__ float ws1[4], ws2[4];
    int wid = tid >> 6;
    if ((tid & 63) == 0) { ws1[wid] = s1; ws2[wid] = s2; }
    __syncthreads();
    s1 = ws1[0] + ws1[1] + ws1[2] + ws1[3];
    s2 = ws2[0] + ws2[1] + ws2[2] + ws2[3];
    float mean = s1 * (1.0f / D_);
    float var  = s2 * (1.0f / D_) - mean * mean;
    float rstd = rsqrtf(var + 1e-5f);
    float o0 = (x0 - mean) * rstd * g[tid]       + be[tid];
    float o1 = (x1 - mean) * rstd * g[tid + 256] + be[tid + 256];
    out[base + tid]       = o0;
    out[base + tid + 256] = o1;
    if (wb) {
        outb[base + tid]       = __float2bfloat16(o0);
        outb[base + tid + 256] = __float2bfloat16(o1);
    }
}

// ---------------------------------------------------------------- pool + classifier
__global__ __launch_bounds__(256) void pool_cls_kernel(const float* __restrict__ x2,
                                                       const int* __restrict__ pad_all,
                                                       const float* __restrict__ w1,
                                                       const float* __restrict__ w2,
                                                       float* __restrict__ out) {
    int b = blockIdx.x;
    int tid = threadIdx.x;
    __shared__ float zg[D_];
    __shared__ int cnt_s;
    if (tid == 0) {
        int c = 0;
        for (int g = 0; g < SG_; ++g) c += pad_all[b * S_ + SL_ + g] ? 0 : 1;
        cnt_s = c;
    }
    float acc0 = 0.0f, acc1 = 0.0f;
    for (int g = 0; g < SG_; ++g) {
        if (!pad_all[b * S_ + SL_ + g]) {
            size_t base = (size_t)(b * S_ + SL_ + g) * D_;
            acc0 += x2[base + tid];
            acc1 += x2[base + tid + 256];
        }
    }
    __syncthreads();
    float inv = 1.0f / (float)cnt_s;
    zg[tid]       = acc0 * inv;
    zg[tid + 256] = acc1 * inv;
    __syncthreads();
    float hsum = 0.0f;
    for (int d = 0; d < D_; ++d)
        hsum = fmaf(zg[d], w1[(size_t)d * 256 + tid], hsum);
    hsum = fmaxf(hsum, 0.0f);
    float o0 = hsum * w2[(size_t)tid * NC_ + 0];
    float o1 = hsum * w2[(size_t)tid * NC_ + 1];
    for (int off = 1; off < 64; off <<= 1) {
        o0 += __shfl_xor(o0, off);
        o1 += __shfl_xor(o1, off);
    }
    __shared__ float r0[4], r1[4];
    if ((tid & 63) == 0) { r0[tid >> 6] = o0; r1[tid >> 6] = o1; }
    __syncthreads();
    if (tid == 0) {
        out[b * NC_ + 0] = r0[0] + r0[1] + r0[2] + r0[3];
        out[b * NC_ + 1] = r1[0] + r1[1] + r1[2] + r1[3];
    }
}

// ---------------------------------------------------------------- launch
extern "C" void kernel_launch(void* const* d_in, const int* in_sizes, int n_in,
                              void* d_out, int out_size, void* d_ws, size_t ws_size,
                              hipStream_t stream) {
    const int*   ids    = (const int*)d_in[0];
    const float* embed  = (const float*)d_in[1];
    const float* gtok   = (const float*)d_in[2];
    const float* relb   = (const float*)d_in[3];
    const float* q_w    = (const float*)d_in[4];
    const float* q_b    = (const float*)d_in[5];
    const float* k_w    = (const float*)d_in[6];
    const float* k_b    = (const float*)d_in[7];
    const float* v_w    = (const float*)d_in[8];
    const float* v_b    = (const float*)d_in[9];
    const float* o_w    = (const float*)d_in[10];
    const float* o_b    = (const float*)d_in[11];
    const float* ln1_g  = (const float*)d_in[12];
    const float* ln1_b  = (const float*)d_in[13];
    const float* ln2_g  = (const float*)d_in[14];
    const float* ln2_b  = (const float*)d_in[15];
    const float* ff1_w  = (const float*)d_in[16];
    const float* ff1_b  = (const float*)d_in[17];
    const float* ff2_w  = (const float*)d_in[18];
    const float* ff2_b  = (const float*)d_in[19];
    const float* cls_w1 = (const float*)d_in[20];
    const float* cls_w2 = (const float*)d_in[21];

    char* ws = (char*)d_ws;
    const size_t SLOT = (size_t)MROWS_ * D_ * sizeof(float);   // 8,912,896
    float*          x_f32 = (float*)(ws);
    __hip_bfloat16* x_b   = (__hip_bfloat16*)(ws + SLOT);
    float*          QKV   = (float*)(ws + SLOT + SLOT / 2);
    __hip_bfloat16* o_bf  = (__hip_bfloat16*)(ws + SLOT + SLOT / 2 + 3 * SLOT);
    char*           extra = ws + SLOT + SLOT / 2 + 3 * SLOT + SLOT / 2;

    __hip_bfloat16* WqkvT = (__hip_bfloat16*)extra;                      // 1,572,864 B
    __hip_bfloat16* WoT   = (__hip_bfloat16*)(extra + 1572864);          //   524,288
    __hip_bfloat16* Wff1T = (__hip_bfloat16*)(extra + 2097152);          // 1,048,576
    __hip_bfloat16* Wff2T = (__hip_bfloat16*)(extra + 3145728);          // 1,048,576
    float* qkvb   = (float*)(extra + 4194304);                           //     6,144
    int*   pad_all = (int*)(extra + 4202496);                            //    17,408
    float* pacc   = (float*)(extra + 4227072);                           // 2,097,152
    float* pm     = (float*)(extra + 6324224);                           //    32,768
    float* pl     = (float*)(extra + 6356992);                           //    32,768

    // aliases (lifetime-checked)
    float*          tmp  = QKV;                                  // QKV slot0, after attn
    float*          x1   = QKV + (size_t)MROWS_ * D_;            // QKV slot1
    __hip_bfloat16* x1b  = o_bf;                                 // o dead after O-proj
    __hip_bfloat16* ffh  = (__hip_bfloat16*)(QKV + 2 * (size_t)MROWS_ * D_);  // QKV slot2
    float*          tmp2 = QKV;                                  // tmp dead after LN1
    float*          x2   = x_f32;                                // x dead after LN1

    build_x_kernel<<<MROWS_, 128, 0, stream>>>(ids, embed, gtok, x_f32, x_b, pad_all);
    bias_concat_kernel<<<6, 256, 0, stream>>>(q_b, k_b, v_b, qkvb);
    wt_kernel<<<dim3(8, 8), 256, 0, stream>>>(q_w, WqkvT, 512, 512);
    wt_kernel<<<dim3(8, 8), 256, 0, stream>>>(k_w, WqkvT + (size_t)512 * 512, 512, 512);
    wt_kernel<<<dim3(8, 8), 256, 0, stream>>>(v_w, WqkvT + (size_t)1024 * 512, 512, 512);
    wt_kernel<<<dim3(8, 8), 256, 0, stream>>>(o_w, WoT, 512, 512);
    wt_kernel<<<dim3(16, 8), 256, 0, stream>>>(ff1_w, Wff1T, 512, 1024);
    wt_kernel<<<dim3(8, 16), 256, 0, stream>>>(ff2_w, Wff2T, 1024, 512);

    gemm_bt_kernel<<<dim3(12, 34), 256, 0, stream>>>(x_b, WqkvT, qkvb, QKV, QKVLD_, 512, 0);

    attn_long_kernel<<<B_ * H_ * 64, 256, 0, stream>>>(QKV, relb, pad_all, o_bf);
    attn_global_kernel<<<B_ * H_ * 4 * KC_, 256, 0, stream>>>(QKV, pad_all, pacc, pm, pl);
    attn_combine_kernel<<<(B_ * H_ * SG_) / 4, 256, 0, stream>>>(pacc, pm, pl, o_bf);

    gemm_bt_kernel<<<dim3(4, 34), 256, 0, stream>>>(o_bf, WoT, o_b, tmp, 512, 512, 0);
    ln_kernel<<<MROWS_, 256, 0, stream>>>(x_f32, tmp, ln1_g, ln1_b, x1, x1b, 1);

    gemm_bt_kernel<<<dim3(8, 34), 256, 0, stream>>>(x1b, Wff1T, ff1_b, ffh, 1024, 512, 3);
    gemm_bt_kernel<<<dim3(4, 34), 256, 0, stream>>>(ffh, Wff2T, ff2_b, tmp2, 512, 1024, 0);
    ln_kernel<<<MROWS_, 256, 0, stream>>>(x1, tmp2, ln2_g, ln2_b, x2, nullptr, 0);

    pool_cls_kernel<<<B_, 256, 0, stream>>>(x2, pad_all, cls_w1, cls_w2, (float*)d_out);
}

// Round 4
// 303.995 us; speedup vs baseline: 4.6831x; 1.4655x over previous
//
#include <hip/hip_runtime.h>
#include <hip/hip_bf16.h>
#include <cstddef>

#define B_ 2
#define SL_ 2048
#define RATIO_ 16
#define SG_ 128
#define S_ 2176
#define D_ 512
#define H_ 8
#define HD_ 64
#define FF_ 1024
#define KCLIP_ 4
#define RAD_ 4
#define NC_ 2
#define NEG_ (-1.0e9f)
#define MINF_ (-1.0e30f)
#define MROWS_ (B_ * S_)   // 4352
#define KC_ 4              // split-K chunks for global-query attention
#define QKVLD_ 1536        // fused QKV row stride
#define PADK_ 65

typedef __attribute__((ext_vector_type(8))) short short8;
typedef __attribute__((ext_vector_type(4))) float f32x4;

__device__ __forceinline__ void gll16(const void* g, void* l) {
    __builtin_amdgcn_global_load_lds((const __attribute__((address_space(1))) void*)g,
                                     (__attribute__((address_space(3))) void*)l, 16, 0, 0);
}

// ---------------------------------------------------------------- build x (f32 + bf16) + pad
__global__ void build_x_kernel(const int* __restrict__ ids,
                               const float* __restrict__ embed,
                               const float* __restrict__ gtok,
                               float* __restrict__ x,
                               __hip_bfloat16* __restrict__ xb,
                               int* __restrict__ pad_all) {
    int row = blockIdx.x;
    int b = row / S_, s = row % S_;
    const float* src;
    if (s < SL_) {
        int tok = ids[b * SL_ + s];
        src = embed + (size_t)tok * D_;
        if (threadIdx.x == 0) pad_all[row] = (tok == 0) ? 1 : 0;
    } else {
        src = gtok;
        if (threadIdx.x == 0) {
            int g = s - SL_;
            int allz = 1;
            for (int r = 0; r < RATIO_; ++r)
                allz &= (ids[b * SL_ + g * RATIO_ + r] == 0) ? 1 : 0;
            pad_all[row] = allz;
        }
    }
    float4 v = ((const float4*)src)[threadIdx.x];
    ((float4*)(x + (size_t)row * D_))[threadIdx.x] = v;
    __hip_bfloat16 hb[4] = {__float2bfloat16(v.x), __float2bfloat16(v.y),
                            __float2bfloat16(v.z), __float2bfloat16(v.w)};
    *(uint2*)(xb + (size_t)row * D_ + threadIdx.x * 4) = *(const uint2*)hb;
}

// ---------------------------------------------------------------- weight transpose+convert
__global__ __launch_bounds__(256) void wt_kernel(const float* __restrict__ W,
                                                 __hip_bfloat16* __restrict__ Wt,
                                                 int K, int N) {
    __shared__ float tile[64][65];
    int n0 = blockIdx.x * 64, k0 = blockIdx.y * 64;
    int t = threadIdx.x, c = t & 63, r4 = t >> 6;
#pragma unroll
    for (int i = 0; i < 16; ++i) {
        int r = i * 4 + r4;
        tile[r][c] = W[(size_t)(k0 + r) * N + n0 + c];
    }
    __syncthreads();
#pragma unroll
    for (int i = 0; i < 16; ++i) {
        int n = i * 4 + r4;
        Wt[(size_t)(n0 + n) * K + k0 + c] = __float2bfloat16(tile[c][n]);
    }
}

__global__ void bias_concat_kernel(const float* __restrict__ qb,
                                   const float* __restrict__ kb,
                                   const float* __restrict__ vb,
                                   float* __restrict__ out) {
    int i = blockIdx.x * 256 + threadIdx.x;   // 0..1535
    float v = (i < 512) ? qb[i] : (i < 1024 ? kb[i - 512] : vb[i - 1024]);
    out[i] = v;
}

// ---------------------------------------------------------------- bf16 MFMA GEMM (B^T form)
// C[M,N] = A[M,K](bf16) @ Bt[N,K](bf16)^T + bias. 128x128 tile, BK=32, 4 waves.
// flags: 1 = relu, 2 = bf16 output
__global__ __launch_bounds__(256) void gemm_bt_kernel(const __hip_bfloat16* __restrict__ A,
                                                      const __hip_bfloat16* __restrict__ Bt,
                                                      const float* __restrict__ bias,
                                                      void* __restrict__ Cout,
                                                      int N, int K, int flags) {
    __shared__ short As[128 * 32];
    __shared__ short Bs[128 * 32];
    int tid = threadIdx.x;
    int m0 = blockIdx.y * 128, n0 = blockIdx.x * 128;
    int w = tid >> 6, lane = tid & 63;
    int wr = w >> 1, wc = w & 1;

    f32x4 acc[4][4];
#pragma unroll
    for (int m = 0; m < 4; ++m)
#pragma unroll
        for (int n = 0; n < 4; ++n)
            acc[m][n] = (f32x4){0.f, 0.f, 0.f, 0.f};

    int p0 = tid * 16;
    int rs = p0 >> 6;
    int cs = p0 & 63;
    const char* Ab = (const char*)A;
    const char* Bb = (const char*)Bt;

    for (int k0 = 0; k0 < K; k0 += 32) {
        __syncthreads();
        gll16(Ab + ((size_t)(m0 + rs) * K + k0) * 2 + cs, (char*)As + p0);
        gll16(Ab + ((size_t)(m0 + rs + 64) * K + k0) * 2 + cs, (char*)As + p0 + 4096);
        gll16(Bb + ((size_t)(n0 + rs) * K + k0) * 2 + cs, (char*)Bs + p0);
        gll16(Bb + ((size_t)(n0 + rs + 64) * K + k0) * 2 + cs, (char*)Bs + p0 + 4096);
        __syncthreads();
        short8 af[4], bfr[4];
#pragma unroll
        for (int m = 0; m < 4; ++m)
            af[m] = *(const short8*)&As[(wr * 64 + m * 16 + (lane & 15)) * 32 + (lane >> 4) * 8];
#pragma unroll
        for (int n = 0; n < 4; ++n)
            bfr[n] = *(const short8*)&Bs[(wc * 64 + n * 16 + (lane & 15)) * 32 + (lane >> 4) * 8];
#pragma unroll
        for (int m = 0; m < 4; ++m)
#pragma unroll
            for (int n = 0; n < 4; ++n)
                acc[m][n] = __builtin_amdgcn_mfma_f32_16x16x32_bf16(af[m], bfr[n], acc[m][n], 0, 0, 0);
    }

    int rbase = m0 + wr * 64 + (lane >> 4) * 4;
    int cbase = n0 + wc * 64 + (lane & 15);
#pragma unroll
    for (int m = 0; m < 4; ++m)
#pragma unroll
        for (int n = 0; n < 4; ++n) {
            int col = cbase + n * 16;
            float bv = bias[col];
#pragma unroll
            for (int j = 0; j < 4; ++j) {
                int row = rbase + m * 16 + j;
                float v = acc[m][n][j] + bv;
                if (flags & 1) v = fmaxf(v, 0.0f);
                if (flags & 2)
                    ((__hip_bfloat16*)Cout)[(size_t)row * N + col] = __float2bfloat16(v);
                else
                    ((float*)Cout)[(size_t)row * N + col] = v;
            }
        }
}

// ================================================================ attention
__device__ __forceinline__ float wave_max(float v) {
#pragma unroll
    for (int off = 1; off < 64; off <<= 1) v = fmaxf(v, __shfl_xor(v, off));
    return v;
}
__device__ __forceinline__ float wave_sum(float v) {
#pragma unroll
    for (int off = 1; off < 64; off <<= 1) v += __shfl_xor(v, off);
    return v;
}

// ------------------------------------------- long queries
// __launch_bounds__(256,3): hard VGPR budget ~168 so the scheduler cannot
// hoist LDS loads into a spill (r2/r3: 256 VGPR + 320 MB scratch writes).
// LDS 48.5KB binds at 3 blocks/CU regardless, so no occupancy lost.
__global__ __launch_bounds__(256, 3) void attn_long_kernel(const float* __restrict__ QKV,
                                                           const float* __restrict__ relb,
                                                           const int* __restrict__ pad_all,
                                                           __hip_bfloat16* __restrict__ Ob) {
    __shared__ float Ks[64][PADK_];
    __shared__ float Vs[64][PADK_];
    __shared__ __align__(16) float Qs[32][64];
    __shared__ __align__(16) float Ps[4][8][64];

    int bid = blockIdx.x;
    int qt = bid & 63, h = (bid >> 6) & 7, b = bid >> 9;
    int i0 = qt * 32;
    int tid = threadIdx.x, w = tid >> 6, lane = tid & 63;
    const int* pad = pad_all + b * S_;

#pragma unroll
    for (int p = 0; p < 2; ++p) {
        int r = p * 16 + (tid >> 4);
        int f = tid & 15;
        float4 qv = *(const float4*)(QKV + (size_t)(b * S_ + i0 + r) * QKVLD_ + h * HD_ + f * 4);
        qv.x *= 0.125f; qv.y *= 0.125f; qv.z *= 0.125f; qv.w *= 0.125f;
        *(float4*)&Qs[r][f * 4] = qv;
    }

    float m[8], l[8], acc[8];
#pragma unroll
    for (int q = 0; q < 8; ++q) { m[q] = MINF_; l[q] = 0.0f; acc[q] = 0.0f; }

    for (int r = 0; r < 3; ++r) {
        __syncthreads();
        {
            int f = tid & 15;
#pragma unroll
            for (int p = 0; p < 4; ++p) {
                int row = p * 16 + (tid >> 4);
                int j = (r == 0) ? (i0 - 4 + row) : (SL_ + (r - 1) * 64 + row);
                int jc = j < 0 ? 0 : (j > SL_ - 1 && r == 0 ? SL_ - 1 : j);
                size_t base = (size_t)(b * S_ + jc) * QKVLD_ + h * HD_;
                float4 kv = *(const float4*)(QKV + base + 512 + f * 4);
                float4 vv = *(const float4*)(QKV + base + 1024 + f * 4);
                Ks[row][f * 4 + 0] = kv.x; Ks[row][f * 4 + 1] = kv.y;
                Ks[row][f * 4 + 2] = kv.z; Ks[row][f * 4 + 3] = kv.w;
                Vs[row][f * 4 + 0] = vv.x; Vs[row][f * 4 + 1] = vv.y;
                Vs[row][f * 4 + 2] = vv.z; Vs[row][f * 4 + 3] = vv.w;
            }
        }
        __syncthreads();

        // phase 1: lane = key slot; 4 K floats live per step, Q via broadcast
        float sv[8];
#pragma unroll
        for (int q = 0; q < 8; ++q) sv[q] = 0.0f;
#pragma unroll 2
        for (int d4 = 0; d4 < 16; ++d4) {
            float k0 = Ks[lane][d4 * 4 + 0];
            float k1 = Ks[lane][d4 * 4 + 1];
            float k2 = Ks[lane][d4 * 4 + 2];
            float k3 = Ks[lane][d4 * 4 + 3];
#pragma unroll
            for (int q = 0; q < 8; ++q) {
                const float4 qv = *(const float4*)&Qs[w * 8 + q][d4 * 4];
                sv[q] = fmaf(qv.x, k0, fmaf(qv.y, k1, fmaf(qv.z, k2, fmaf(qv.w, k3, sv[q]))));
            }
        }
        int j = (r == 0) ? (i0 - 4 + lane) : (SL_ + (r - 1) * 64 + lane);
        int jok = (r == 0) ? (j >= 0 && j < SL_) : 1;
        int padj = jok ? pad[j] : 1;
#pragma unroll
        for (int q = 0; q < 8; ++q) {
            int qi = w * 8 + q;
            float s;
            if (r == 0) {
                int rel = lane - qi;
                if (rel >= 0 && rel <= 8 && jok)
                    s = padj ? NEG_ : sv[q] + relb[h * (2 * KCLIP_ + 1) + rel];
                else
                    s = MINF_;
            } else {
                s = padj ? NEG_ : sv[q];
            }
            float rmax = wave_max(s);
            float mnew = fmaxf(m[q], rmax);
            float fac = __expf(m[q] - mnew);
            float pv = __expf(s - mnew);
            float psum = wave_sum(pv);
            l[q] = l[q] * fac + psum;
            m[q] = mnew;
            acc[q] *= fac;
            Ps[w][q][lane] = pv;
        }

        // phase 2: lane = dim; 4 V floats live per step, P via broadcast
#pragma unroll 2
        for (int j4 = 0; j4 < 16; ++j4) {
            float v0 = Vs[j4 * 4 + 0][lane];
            float v1 = Vs[j4 * 4 + 1][lane];
            float v2 = Vs[j4 * 4 + 2][lane];
            float v3 = Vs[j4 * 4 + 3][lane];
#pragma unroll
            for (int q = 0; q < 8; ++q) {
                const float4 p4 = *(const float4*)&Ps[w][q][j4 * 4];
                acc[q] = fmaf(p4.x, v0, fmaf(p4.y, v1, fmaf(p4.z, v2, fmaf(p4.w, v3, acc[q]))));
            }
        }
    }
#pragma unroll
    for (int q = 0; q < 8; ++q) {
        int i = i0 + w * 8 + q;
        Ob[(size_t)(b * S_ + i) * D_ + h * HD_ + lane] = __float2bfloat16(acc[q] / l[q]);
    }
}

// ------------------------------------------- global queries, split-K
__global__ __launch_bounds__(256, 3) void attn_global_kernel(const float* __restrict__ QKV,
                                                             const int* __restrict__ pad_all,
                                                             float* __restrict__ pacc,
                                                             float* __restrict__ pm,
                                                             float* __restrict__ pl) {
    __shared__ float Ks[64][PADK_];
    __shared__ float Vs[64][PADK_];
    __shared__ __align__(16) float Qs[32][64];
    __shared__ __align__(16) float Ps[4][8][64];

    int bid = blockIdx.x;
    int c  = bid & 3;
    int qt = (bid >> 2) & 3;
    int h  = (bid >> 4) & 7;
    int b  = bid >> 7;
    int i0 = SL_ + qt * 32;
    int tid = threadIdx.x, w = tid >> 6, lane = tid & 63;
    const int* pad = pad_all + b * S_;

#pragma unroll
    for (int p = 0; p < 2; ++p) {
        int r = p * 16 + (tid >> 4);
        int f = tid & 15;
        float4 qv = *(const float4*)(QKV + (size_t)(b * S_ + i0 + r) * QKVLD_ + h * HD_ + f * 4);
        qv.x *= 0.125f; qv.y *= 0.125f; qv.z *= 0.125f; qv.w *= 0.125f;
        *(float4*)&Qs[r][f * 4] = qv;
    }

    float m[8], l[8], acc[8];
#pragma unroll
    for (int q = 0; q < 8; ++q) { m[q] = MINF_; l[q] = 0.0f; acc[q] = 0.0f; }

    int t0 = (c * 34) >> 2, t1 = ((c + 1) * 34) >> 2;
    for (int t = t0; t < t1; ++t) {
        int j0 = t * 64;
        __syncthreads();
        {
            int f = tid & 15;
#pragma unroll
            for (int p = 0; p < 4; ++p) {
                int row = p * 16 + (tid >> 4);
                size_t base = (size_t)(b * S_ + j0 + row) * QKVLD_ + h * HD_;
                float4 kv = *(const float4*)(QKV + base + 512 + f * 4);
                float4 vv = *(const float4*)(QKV + base + 1024 + f * 4);
                Ks[row][f * 4 + 0] = kv.x; Ks[row][f * 4 + 1] = kv.y;
                Ks[row][f * 4 + 2] = kv.z; Ks[row][f * 4 + 3] = kv.w;
                Vs[row][f * 4 + 0] = vv.x; Vs[row][f * 4 + 1] = vv.y;
                Vs[row][f * 4 + 2] = vv.z; Vs[row][f * 4 + 3] = vv.w;
            }
        }
        __syncthreads();

        float sv[8];
#pragma unroll
        for (int q = 0; q < 8; ++q) sv[q] = 0.0f;
#pragma unroll 2
        for (int d4 = 0; d4 < 16; ++d4) {
            float k0 = Ks[lane][d4 * 4 + 0];
            float k1 = Ks[lane][d4 * 4 + 1];
            float k2 = Ks[lane][d4 * 4 + 2];
            float k3 = Ks[lane][d4 * 4 + 3];
#pragma unroll
            for (int q = 0; q < 8; ++q) {
                const float4 qv = *(const float4*)&Qs[w * 8 + q][d4 * 4];
                sv[q] = fmaf(qv.x, k0, fmaf(qv.y, k1, fmaf(qv.z, k2, fmaf(qv.w, k3, sv[q]))));
            }
        }
        int padj = pad[j0 + lane];
#pragma unroll
        for (int q = 0; q < 8; ++q) {
            float s = padj ? NEG_ : sv[q];
            float rmax = wave_max(s);
            float mnew = fmaxf(m[q], rmax);
            float fac = __expf(m[q] - mnew);
            float pv = __expf(s - mnew);
            float psum = wave_sum(pv);
            l[q] = l[q] * fac + psum;
            m[q] = mnew;
            acc[q] *= fac;
            Ps[w][q][lane] = pv;
        }

#pragma unroll 2
        for (int j4 = 0; j4 < 16; ++j4) {
            float v0 = Vs[j4 * 4 + 0][lane];
            float v1 = Vs[j4 * 4 + 1][lane];
            float v2 = Vs[j4 * 4 + 2][lane];
            float v3 = Vs[j4 * 4 + 3][lane];
#pragma unroll
            for (int q = 0; q < 8; ++q) {
                const float4 p4 = *(const float4*)&Ps[w][q][j4 * 4];
                acc[q] = fmaf(p4.x, v0, fmaf(p4.y, v1, fmaf(p4.z, v2, fmaf(p4.w, v3, acc[q]))));
            }
        }
    }
#pragma unroll
    for (int q = 0; q < 8; ++q) {
        int gq = qt * 32 + w * 8 + q;
        int pidx = ((c * B_ + b) * H_ + h) * SG_ + gq;
        pacc[(size_t)pidx * HD_ + lane] = acc[q];
        if (lane == 0) { pm[pidx] = m[q]; pl[pidx] = l[q]; }
    }
}

__global__ __launch_bounds__(256) void attn_combine_kernel(const float* __restrict__ pacc,
                                                           const float* __restrict__ pm,
                                                           const float* __restrict__ pl,
                                                           __hip_bfloat16* __restrict__ Ob) {
    int wave = (int)((blockIdx.x * (size_t)blockDim.x + threadIdx.x) >> 6);
    int lane = threadIdx.x & 63;
    int gq = wave & (SG_ - 1);
    int h  = (wave >> 7) & 7;
    int b  = wave >> 10;

    float M = MINF_;
#pragma unroll
    for (int c = 0; c < KC_; ++c) {
        int pidx = ((c * B_ + b) * H_ + h) * SG_ + gq;
        M = fmaxf(M, pm[pidx]);
    }
    float L = 0.0f, Ov = 0.0f;
#pragma unroll
    for (int c = 0; c < KC_; ++c) {
        int pidx = ((c * B_ + b) * H_ + h) * SG_ + gq;
        float e = __expf(pm[pidx] - M);
        L += pl[pidx] * e;
        Ov += pacc[(size_t)pidx * HD_ + lane] * e;
    }
    Ob[(size_t)(b * S_ + SL_ + gq) * D_ + h * HD_ + lane] = __float2bfloat16(Ov / L);
}

// ---------------------------------------------------------------- residual + LN
__global__ __launch_bounds__(256) void ln_kernel(const float* __restrict__ A,
                                                 const float* __restrict__ Bres,
                                                 const float* __restrict__ g,
                                                 const float* __restrict__ be,
                                                 float* __restrict__ out,
                                                 __hip_bfloat16* __restrict__ outb,
                                                 int wb) {
    int row = blockIdx.x;
    int tid = threadIdx.x;
    size_t base = (size_t)row * D_;
    float x0 = A[base + tid]       + Bres[base + tid];
    float x1 = A[base + tid + 256] + Bres[base + tid + 256];
    float s1 = x0 + x1;
    float s2 = x0 * x0 + x1 * x1;
    for (int off = 1; off < 64; off <<= 1) {
        s1 += __shfl_xor(s1, off);
        s2 += __shfl_xor(s2, off);
    }
    __shared__ float ws1[4], ws2[4];
    int wid = tid >> 6;
    if ((tid & 63) == 0) { ws1[wid] = s1; ws2[wid] = s2; }
    __syncthreads();
    s1 = ws1[0] + ws1[1] + ws1[2] + ws1[3];
    s2 = ws2[0] + ws2[1] + ws2[2] + ws2[3];
    float mean = s1 * (1.0f / D_);
    float var  = s2 * (1.0f / D_) - mean * mean;
    float rstd = rsqrtf(var + 1e-5f);
    float o0 = (x0 - mean) * rstd * g[tid]       + be[tid];
    float o1 = (x1 - mean) * rstd * g[tid + 256] + be[tid + 256];
    out[base + tid]       = o0;
    out[base + tid + 256] = o1;
    if (wb) {
        outb[base + tid]       = __float2bfloat16(o0);
        outb[base + tid + 256] = __float2bfloat16(o1);
    }
}

// ---------------------------------------------------------------- pool + classifier
__global__ __launch_bounds__(256) void pool_cls_kernel(const float* __restrict__ x2,
                                                       const int* __restrict__ pad_all,
                                                       const float* __restrict__ w1,
                                                       const float* __restrict__ w2,
                                                       float* __restrict__ out) {
    int b = blockIdx.x;
    int tid = threadIdx.x;
    __shared__ float zg[D_];
    __shared__ int cnt_s;
    if (tid == 0) {
        int c = 0;
        for (int g = 0; g < SG_; ++g) c += pad_all[b * S_ + SL_ + g] ? 0 : 1;
        cnt_s = c;
    }
    float acc0 = 0.0f, acc1 = 0.0f;
    for (int g = 0; g < SG_; ++g) {
        if (!pad_all[b * S_ + SL_ + g]) {
            size_t base = (size_t)(b * S_ + SL_ + g) * D_;
            acc0 += x2[base + tid];
            acc1 += x2[base + tid + 256];
        }
    }
    __syncthreads();
    float inv = 1.0f / (float)cnt_s;
    zg[tid]       = acc0 * inv;
    zg[tid + 256] = acc1 * inv;
    __syncthreads();
    float hsum = 0.0f;
    for (int d = 0; d < D_; ++d)
        hsum = fmaf(zg[d], w1[(size_t)d * 256 + tid], hsum);
    hsum = fmaxf(hsum, 0.0f);
    float o0 = hsum * w2[(size_t)tid * NC_ + 0];
    float o1 = hsum * w2[(size_t)tid * NC_ + 1];
    for (int off = 1; off < 64; off <<= 1) {
        o0 += __shfl_xor(o0, off);
        o1 += __shfl_xor(o1, off);
    }
    __shared__ float r0[4], r1[4];
    if ((tid & 63) == 0) { r0[tid >> 6] = o0; r1[tid >> 6] = o1; }
    __syncthreads();
    if (tid == 0) {
        out[b * NC_ + 0] = r0[0] + r0[1] + r0[2] + r0[3];
        out[b * NC_ + 1] = r1[0] + r1[1] + r1[2] + r1[3];
    }
}

// ---------------------------------------------------------------- launch
extern "C" void kernel_launch(void* const* d_in, const int* in_sizes, int n_in,
                              void* d_out, int out_size, void* d_ws, size_t ws_size,
                              hipStream_t stream) {
    const int*   ids    = (const int*)d_in[0];
    const float* embed  = (const float*)d_in[1];
    const float* gtok   = (const float*)d_in[2];
    const float* relb   = (const float*)d_in[3];
    const float* q_w    = (const float*)d_in[4];
    const float* q_b    = (const float*)d_in[5];
    const float* k_w    = (const float*)d_in[6];
    const float* k_b    = (const float*)d_in[7];
    const float* v_w    = (const float*)d_in[8];
    const float* v_b    = (const float*)d_in[9];
    const float* o_w    = (const float*)d_in[10];
    const float* o_b    = (const float*)d_in[11];
    const float* ln1_g  = (const float*)d_in[12];
    const float* ln1_b  = (const float*)d_in[13];
    const float* ln2_g  = (const float*)d_in[14];
    const float* ln2_b  = (const float*)d_in[15];
    const float* ff1_w  = (const float*)d_in[16];
    const float* ff1_b  = (const float*)d_in[17];
    const float* ff2_w  = (const float*)d_in[18];
    const float* ff2_b  = (const float*)d_in[19];
    const float* cls_w1 = (const float*)d_in[20];
    const float* cls_w2 = (const float*)d_in[21];

    char* ws = (char*)d_ws;
    const size_t SLOT = (size_t)MROWS_ * D_ * sizeof(float);   // 8,912,896
    float*          x_f32 = (float*)(ws);
    __hip_bfloat16* x_b   = (__hip_bfloat16*)(ws + SLOT);
    float*          QKV   = (float*)(ws + SLOT + SLOT / 2);
    __hip_bfloat16* o_bf  = (__hip_bfloat16*)(ws + SLOT + SLOT / 2 + 3 * SLOT);
    char*           extra = ws + SLOT + SLOT / 2 + 3 * SLOT + SLOT / 2;

    __hip_bfloat16* WqkvT = (__hip_bfloat16*)extra;                      // 1,572,864 B
    __hip_bfloat16* WoT   = (__hip_bfloat16*)(extra + 1572864);          //   524,288
    __hip_bfloat16* Wff1T = (__hip_bfloat16*)(extra + 2097152);          // 1,048,576
    __hip_bfloat16* Wff2T = (__hip_bfloat16*)(extra + 3145728);          // 1,048,576
    float* qkvb   = (float*)(extra + 4194304);                           //     6,144
    int*   pad_all = (int*)(extra + 4202496);                            //    17,408
    float* pacc   = (float*)(extra + 4227072);                           // 2,097,152
    float* pm     = (float*)(extra + 6324224);                           //    32,768
    float* pl     = (float*)(extra + 6356992);                           //    32,768

    float*          tmp  = QKV;
    float*          x1   = QKV + (size_t)MROWS_ * D_;
    __hip_bfloat16* x1b  = o_bf;
    __hip_bfloat16* ffh  = (__hip_bfloat16*)(QKV + 2 * (size_t)MROWS_ * D_);
    float*          tmp2 = QKV;
    float*          x2   = x_f32;

    build_x_kernel<<<MROWS_, 128, 0, stream>>>(ids, embed, gtok, x_f32, x_b, pad_all);
    bias_concat_kernel<<<6, 256, 0, stream>>>(q_b, k_b, v_b, qkvb);
    wt_kernel<<<dim3(8, 8), 256, 0, stream>>>(q_w, WqkvT, 512, 512);
    wt_kernel<<<dim3(8, 8), 256, 0, stream>>>(k_w, WqkvT + (size_t)512 * 512, 512, 512);
    wt_kernel<<<dim3(8, 8), 256, 0, stream>>>(v_w, WqkvT + (size_t)1024 * 512, 512, 512);
    wt_kernel<<<dim3(8, 8), 256, 0, stream>>>(o_w, WoT, 512, 512);
    wt_kernel<<<dim3(16, 8), 256, 0, stream>>>(ff1_w, Wff1T, 512, 1024);
    wt_kernel<<<dim3(8, 16), 256, 0, stream>>>(ff2_w, Wff2T, 1024, 512);

    gemm_bt_kernel<<<dim3(12, 34), 256, 0, stream>>>(x_b, WqkvT, qkvb, QKV, QKVLD_, 512, 0);

    attn_long_kernel<<<B_ * H_ * 64, 256, 0, stream>>>(QKV, relb, pad_all, o_bf);
    attn_global_kernel<<<B_ * H_ * 4 * KC_, 256, 0, stream>>>(QKV, pad_all, pacc, pm, pl);
    attn_combine_kernel<<<(B_ * H_ * SG_) / 4, 256, 0, stream>>>(pacc, pm, pl, o_bf);

    gemm_bt_kernel<<<dim3(4, 34), 256, 0, stream>>>(o_bf, WoT, o_b, tmp, 512, 512, 0);
    ln_kernel<<<MROWS_, 256, 0, stream>>>(x_f32, tmp, ln1_g, ln1_b, x1, x1b, 1);

    gemm_bt_kernel<<<dim3(8, 34), 256, 0, stream>>>(x1b, Wff1T, ff1_b, ffh, 1024, 512, 3);
    gemm_bt_kernel<<<dim3(4, 34), 256, 0, stream>>>(ffh, Wff2T, ff2_b, tmp2, 512, 1024, 0);
    ln_kernel<<<MROWS_, 256, 0, stream>>>(x1, tmp2, ln2_g, ln2_b, x2, nullptr, 0);

    pool_cls_kernel<<<B_, 256, 0, stream>>>(x2, pad_all, cls_w1, cls_w2, (float*)d_out);
}

// Round 5
// 184.420 us; speedup vs baseline: 7.7196x; 1.6484x over previous
//
#include <hip/hip_runtime.h>
#include <hip/hip_bf16.h>
#include <cstddef>

#define B_ 2
#define SL_ 2048
#define RATIO_ 16
#define SG_ 128
#define S_ 2176
#define D_ 512
#define H_ 8
#define HD_ 64
#define FF_ 1024
#define KCLIP_ 4
#define NC_ 2
#define NEG_ (-1.0e9f)
#define MINF_ (-1.0e30f)
#define MROWS_ (B_ * S_)   // 4352
#define KC_ 4
#define QKVLD_ 1536        // fused QKV row stride (bf16)

typedef __attribute__((ext_vector_type(8))) short short8;
typedef __attribute__((ext_vector_type(4))) float f32x4;

__device__ __forceinline__ void gll16(const void* g, void* l) {
    __builtin_amdgcn_global_load_lds((const __attribute__((address_space(1))) void*)g,
                                     (__attribute__((address_space(3))) void*)l, 16, 0, 0);
}
__device__ __forceinline__ unsigned short f2bf(float x) {
    __hip_bfloat16 h = __float2bfloat16(x);
    return *reinterpret_cast<unsigned short*>(&h);
}
__device__ __forceinline__ float wave_sum(float v) {
#pragma unroll
    for (int off = 1; off < 64; off <<= 1) v += __shfl_xor(v, off);
    return v;
}

// ---------------------------------------------------------------- build x (f32 + bf16) + pad
__global__ void build_x_kernel(const int* __restrict__ ids,
                               const float* __restrict__ embed,
                               const float* __restrict__ gtok,
                               float* __restrict__ x,
                               __hip_bfloat16* __restrict__ xb,
                               int* __restrict__ pad_all) {
    int row = blockIdx.x;
    int b = row / S_, s = row % S_;
    const float* src;
    if (s < SL_) {
        int tok = ids[b * SL_ + s];
        src = embed + (size_t)tok * D_;
        if (threadIdx.x == 0) pad_all[row] = (tok == 0) ? 1 : 0;
    } else {
        src = gtok;
        if (threadIdx.x == 0) {
            int g = s - SL_;
            int allz = 1;
            for (int r = 0; r < RATIO_; ++r)
                allz &= (ids[b * SL_ + g * RATIO_ + r] == 0) ? 1 : 0;
            pad_all[row] = allz;
        }
    }
    float4 v = ((const float4*)src)[threadIdx.x];
    ((float4*)(x + (size_t)row * D_))[threadIdx.x] = v;
    __hip_bfloat16 hb[4] = {__float2bfloat16(v.x), __float2bfloat16(v.y),
                            __float2bfloat16(v.z), __float2bfloat16(v.w)};
    *(uint2*)(xb + (size_t)row * D_ + threadIdx.x * 4) = *(const uint2*)hb;
}

// ---------------------------------------------------------------- fused weight transpose+convert
// 512 blocks, each does one 64x64 tile of one of the 6 weights.
__global__ __launch_bounds__(256) void wt_all_kernel(const float* __restrict__ qw,
                                                     const float* __restrict__ kw,
                                                     const float* __restrict__ vw,
                                                     const float* __restrict__ ow,
                                                     const float* __restrict__ f1w,
                                                     const float* __restrict__ f2w,
                                                     __hip_bfloat16* __restrict__ WqkvT,
                                                     __hip_bfloat16* __restrict__ WoT,
                                                     __hip_bfloat16* __restrict__ W1T,
                                                     __hip_bfloat16* __restrict__ W2T) {
    __shared__ float tile[64][65];
    int bid = blockIdx.x;
    const float* W; __hip_bfloat16* Wt; int K, N, tx, ty;
    if (bid < 192) {
        int which = bid >> 6, id = bid & 63;
        W = (which == 0) ? qw : (which == 1) ? kw : vw;
        Wt = WqkvT + (size_t)which * 512 * 512;
        K = 512; N = 512; tx = id & 7; ty = id >> 3;
    } else if (bid < 256) {
        int id = bid - 192; W = ow; Wt = WoT; K = 512; N = 512; tx = id & 7; ty = id >> 3;
    } else if (bid < 384) {
        int id = bid - 256; W = f1w; Wt = W1T; K = 512; N = 1024; tx = id & 15; ty = id >> 4;
    } else {
        int id = bid - 384; W = f2w; Wt = W2T; K = 1024; N = 512; tx = id & 7; ty = id >> 3;
    }
    int n0 = tx * 64, k0 = ty * 64;
    int t = threadIdx.x, c = t & 63, r4 = t >> 6;
#pragma unroll
    for (int i = 0; i < 16; ++i) {
        int r = i * 4 + r4;
        tile[r][c] = W[(size_t)(k0 + r) * N + n0 + c];
    }
    __syncthreads();
#pragma unroll
    for (int i = 0; i < 16; ++i) {
        int n = i * 4 + r4;
        Wt[(size_t)(n0 + n) * K + k0 + c] = __float2bfloat16(tile[c][n]);
    }
}

__global__ void bias_concat_kernel(const float* __restrict__ qb,
                                   const float* __restrict__ kb,
                                   const float* __restrict__ vb,
                                   float* __restrict__ out) {
    int i = blockIdx.x * 256 + threadIdx.x;
    float v = (i < 512) ? qb[i] : (i < 1024 ? kb[i - 512] : vb[i - 1024]);
    out[i] = v;
}

// ---------------------------------------------------------------- bf16 MFMA GEMM (B^T form)
// flags: 1 = relu, 2 = bf16 output
__global__ __launch_bounds__(256) void gemm_bt_kernel(const __hip_bfloat16* __restrict__ A,
                                                      const __hip_bfloat16* __restrict__ Bt,
                                                      const float* __restrict__ bias,
                                                      void* __restrict__ Cout,
                                                      int N, int K, int flags) {
    __shared__ short As[128 * 32];
    __shared__ short Bs[128 * 32];
    int tid = threadIdx.x;
    int m0 = blockIdx.y * 128, n0 = blockIdx.x * 128;
    int w = tid >> 6, lane = tid & 63;
    int wr = w >> 1, wc = w & 1;

    f32x4 acc[4][4];
#pragma unroll
    for (int m = 0; m < 4; ++m)
#pragma unroll
        for (int n = 0; n < 4; ++n)
            acc[m][n] = (f32x4){0.f, 0.f, 0.f, 0.f};

    int p0 = tid * 16;
    int rs = p0 >> 6;
    int cs = p0 & 63;
    const char* Ab = (const char*)A;
    const char* Bb = (const char*)Bt;

    for (int k0 = 0; k0 < K; k0 += 32) {
        __syncthreads();
        gll16(Ab + ((size_t)(m0 + rs) * K + k0) * 2 + cs, (char*)As + p0);
        gll16(Ab + ((size_t)(m0 + rs + 64) * K + k0) * 2 + cs, (char*)As + p0 + 4096);
        gll16(Bb + ((size_t)(n0 + rs) * K + k0) * 2 + cs, (char*)Bs + p0);
        gll16(Bb + ((size_t)(n0 + rs + 64) * K + k0) * 2 + cs, (char*)Bs + p0 + 4096);
        __syncthreads();
        short8 af[4], bfr[4];
#pragma unroll
        for (int m = 0; m < 4; ++m)
            af[m] = *(const short8*)&As[(wr * 64 + m * 16 + (lane & 15)) * 32 + (lane >> 4) * 8];
#pragma unroll
        for (int n = 0; n < 4; ++n)
            bfr[n] = *(const short8*)&Bs[(wc * 64 + n * 16 + (lane & 15)) * 32 + (lane >> 4) * 8];
#pragma unroll
        for (int m = 0; m < 4; ++m)
#pragma unroll
            for (int n = 0; n < 4; ++n)
                acc[m][n] = __builtin_amdgcn_mfma_f32_16x16x32_bf16(af[m], bfr[n], acc[m][n], 0, 0, 0);
    }

    int rbase = m0 + wr * 64 + (lane >> 4) * 4;
    int cbase = n0 + wc * 64 + (lane & 15);
#pragma unroll
    for (int m = 0; m < 4; ++m)
#pragma unroll
        for (int n = 0; n < 4; ++n) {
            int col = cbase + n * 16;
            float bv = bias[col];
#pragma unroll
            for (int j = 0; j < 4; ++j) {
                int row = rbase + m * 16 + j;
                float v = acc[m][n][j] + bv;
                if (flags & 1) v = fmaxf(v, 0.0f);
                if (flags & 2)
                    ((__hip_bfloat16*)Cout)[(size_t)row * N + col] = __float2bfloat16(v);
                else
                    ((float*)Cout)[(size_t)row * N + col] = v;
            }
        }
}

// ================================================================ MFMA attention
// LDS layout (bytes): Qs[32][72]s @0 (4608) | Ks[64][72]s @4608 (9216) |
// Vt[64][72]s @13824 (9216) | Pl[2][16][72]s @23040 (4608) | padv[64]f @27648 |
// rb[9]f @27904 | msh[2][2][16]f @27968 | lsh @28224 | end 28480.
// Epilogue Osh[2][2][16][68]f (17408) aliases Qs/Ks/Vt.
#define ATT_LDS_ 28480

// Wave roles: w = qg*2 + kh; qg = query group (16 q), kh = key half (32 keys).
// S^T via mfma(K_frag, Q_frag): lane holds 8 S vals: query cq=lane&15 (+16*qg),
// keys k = kh*32 + mt*16 + (lane>>4)*4 + j. Online softmax per wave (chunk);
// cross-lane reduce = shfl_xor 16,32 (4 lanes share a query).
// PV via mfma(Vt_frag, P_frag) -> O^T: lane holds 16 d vals for query cq.

__global__ __launch_bounds__(256, 4) void attn_long_kernel(const __hip_bfloat16* __restrict__ QKVb,
                                                           const float* __restrict__ relb,
                                                           const int* __restrict__ pad_all,
                                                           __hip_bfloat16* __restrict__ Ob) {
    __shared__ __align__(16) char smem[ATT_LDS_];
    short* Qs = (short*)(smem + 0);
    short* Ks = (short*)(smem + 4608);
    short* Vt = (short*)(smem + 13824);
    short* Pl = (short*)(smem + 23040);
    float* padv = (float*)(smem + 27648);
    float* rb   = (float*)(smem + 27904);
    float* msh  = (float*)(smem + 27968);
    float* lsh  = (float*)(smem + 28224);
    float* Osh  = (float*)smem;

    int bid = blockIdx.x;
    int qt = bid & 63, h = (bid >> 6) & 7, b = bid >> 9;
    int i0 = qt * 32;
    int tid = threadIdx.x;
    int w = tid >> 6, lane = tid & 63;
    int qg = w >> 1, kh = w & 1;
    int cq = lane & 15, g4 = lane >> 4;
    int qq = qg * 16 + cq;
    const int* pad = pad_all + b * S_;
    const short* qkv = (const short*)QKVb;

    // stage Q (once) + rel bias row
    {
        int q = tid >> 3, g = tid & 7;
        short8 v = *(const short8*)(qkv + (size_t)(b * S_ + i0 + q) * QKVLD_ + h * HD_ + g * 8);
        *(short8*)(Qs + q * 72 + g * 8) = v;
        if (tid < 9) rb[tid] = relb[h * 9 + tid];
    }

    float mreg = MINF_, lreg = 0.0f;
    f32x4 ot0 = {0,0,0,0}, ot1 = {0,0,0,0}, ot2 = {0,0,0,0}, ot3 = {0,0,0,0};

    for (int r = 0; r < 3; ++r) {
        __syncthreads();
        // stage K (row-major) and V^T (transposed) + padv
        {
            int key = tid >> 2, g2 = tid & 3;
            int j = (r == 0) ? (i0 - 4 + key) : (SL_ + (r - 1) * 64 + key);
            int jc = j < 0 ? 0 : ((r == 0 && j > SL_ - 1) ? SL_ - 1 : j);
            size_t base = (size_t)(b * S_ + jc) * QKVLD_ + h * HD_;
#pragma unroll
            for (int gg = 0; gg < 2; ++gg) {
                int g = g2 + gg * 4;
                short8 kv = *(const short8*)(qkv + base + 512 + g * 8);
                *(short8*)(Ks + key * 72 + g * 8) = kv;
                short8 vv = *(const short8*)(qkv + base + 1024 + g * 8);
#pragma unroll
                for (int i = 0; i < 8; ++i)
                    Vt[(g * 8 + i) * 72 + key] = vv[i];
            }
            if (tid < 64) {
                int k2 = tid;
                int j2 = (r == 0) ? (i0 - 4 + k2) : (SL_ + (r - 1) * 64 + k2);
                int ok = (r == 0) ? (j2 >= 0 && j2 < SL_) : 1;
                float pv = NEG_;
                if (ok) pv = pad[j2] ? NEG_ : 0.0f;
                padv[k2] = pv;
            }
        }
        __syncthreads();

        // QK^T (S^T = K . Q^T)
        short8 qf0 = *(const short8*)(Qs + (qg * 16 + cq) * 72 + 0 + g4 * 8);
        short8 qf1 = *(const short8*)(Qs + (qg * 16 + cq) * 72 + 32 + g4 * 8);
        f32x4 st0 = {0,0,0,0}, st1 = {0,0,0,0};
        {
            short8 kf;
            kf = *(const short8*)(Ks + (kh * 32 + cq) * 72 + 0 + g4 * 8);
            st0 = __builtin_amdgcn_mfma_f32_16x16x32_bf16(kf, qf0, st0, 0, 0, 0);
            kf = *(const short8*)(Ks + (kh * 32 + cq) * 72 + 32 + g4 * 8);
            st0 = __builtin_amdgcn_mfma_f32_16x16x32_bf16(kf, qf1, st0, 0, 0, 0);
            kf = *(const short8*)(Ks + (kh * 32 + 16 + cq) * 72 + 0 + g4 * 8);
            st1 = __builtin_amdgcn_mfma_f32_16x16x32_bf16(kf, qf0, st1, 0, 0, 0);
            kf = *(const short8*)(Ks + (kh * 32 + 16 + cq) * 72 + 32 + g4 * 8);
            st1 = __builtin_amdgcn_mfma_f32_16x16x32_bf16(kf, qf1, st1, 0, 0, 0);
        }
        // mask + bias
        float sarr[8];
#pragma unroll
        for (int mt = 0; mt < 2; ++mt)
#pragma unroll
            for (int j = 0; j < 4; ++j) {
                int k = kh * 32 + mt * 16 + g4 * 4 + j;
                float sval = (mt ? st1[j] : st0[j]) * 0.125f + padv[k];
                if (r == 0) {
                    int rel = k - qq;
                    bool allowed = (rel >= 0 && rel <= 8);
                    int relc = min(max(rel, 0), 8);
                    sval = allowed ? (sval + rb[relc]) : MINF_;
                }
                sarr[mt * 4 + j] = sval;
            }
        // online softmax (per 32-key chunk)
        float cmax = sarr[0];
#pragma unroll
        for (int i = 1; i < 8; ++i) cmax = fmaxf(cmax, sarr[i]);
        cmax = fmaxf(cmax, __shfl_xor(cmax, 16));
        cmax = fmaxf(cmax, __shfl_xor(cmax, 32));
        float mnew = fmaxf(mreg, cmax);
        float fac = __expf(mreg - mnew);
        float parr[8], psum = 0.0f;
#pragma unroll
        for (int i = 0; i < 8; ++i) { parr[i] = __expf(sarr[i] - mnew); psum += parr[i]; }
        psum += __shfl_xor(psum, 16);
        psum += __shfl_xor(psum, 32);
        lreg = lreg * fac + psum;
        mreg = mnew;
        ot0 *= fac; ot1 *= fac; ot2 *= fac; ot3 *= fac;
        // pack P -> bf16 LDS [q][key]
#pragma unroll
        for (int mt = 0; mt < 2; ++mt) {
            unsigned int lo = (unsigned int)f2bf(parr[mt * 4 + 0]) | ((unsigned int)f2bf(parr[mt * 4 + 1]) << 16);
            unsigned int hi = (unsigned int)f2bf(parr[mt * 4 + 2]) | ((unsigned int)f2bf(parr[mt * 4 + 3]) << 16);
            unsigned int* dst = (unsigned int*)(Pl + (qg * 16 + cq) * 72 + kh * 32 + mt * 16 + g4 * 4);
            dst[0] = lo; dst[1] = hi;
        }
        // PV (O^T += V^T . P^T)
        short8 pf = *(const short8*)(Pl + (qg * 16 + cq) * 72 + kh * 32 + g4 * 8);
        {
            short8 vf;
            vf = *(const short8*)(Vt + (0 * 16 + cq) * 72 + kh * 32 + g4 * 8);
            ot0 = __builtin_amdgcn_mfma_f32_16x16x32_bf16(vf, pf, ot0, 0, 0, 0);
            vf = *(const short8*)(Vt + (1 * 16 + cq) * 72 + kh * 32 + g4 * 8);
            ot1 = __builtin_amdgcn_mfma_f32_16x16x32_bf16(vf, pf, ot1, 0, 0, 0);
            vf = *(const short8*)(Vt + (2 * 16 + cq) * 72 + kh * 32 + g4 * 8);
            ot2 = __builtin_amdgcn_mfma_f32_16x16x32_bf16(vf, pf, ot2, 0, 0, 0);
            vf = *(const short8*)(Vt + (3 * 16 + cq) * 72 + kh * 32 + g4 * 8);
            ot3 = __builtin_amdgcn_mfma_f32_16x16x32_bf16(vf, pf, ot3, 0, 0, 0);
        }
    }

    // cross-wave merge (kh pairs) + write
    __syncthreads();
    if (g4 == 0) {
        msh[(qg * 2 + kh) * 16 + cq] = mreg;
        lsh[(qg * 2 + kh) * 16 + cq] = lreg;
    }
    __syncthreads();
    {
        float m0 = msh[(qg * 2 + 0) * 16 + cq], m1 = msh[(qg * 2 + 1) * 16 + cq];
        float Mm = fmaxf(m0, m1);
        float e_self = __expf(mreg - Mm);
        f32x4 o;
        o = ot0 * e_self; *(f32x4*)(Osh + ((qg * 2 + kh) * 16 + cq) * 68 + 0  + g4 * 4) = o;
        o = ot1 * e_self; *(f32x4*)(Osh + ((qg * 2 + kh) * 16 + cq) * 68 + 16 + g4 * 4) = o;
        o = ot2 * e_self; *(f32x4*)(Osh + ((qg * 2 + kh) * 16 + cq) * 68 + 32 + g4 * 4) = o;
        o = ot3 * e_self; *(f32x4*)(Osh + ((qg * 2 + kh) * 16 + cq) * 68 + 48 + g4 * 4) = o;
    }
    __syncthreads();
    {
        int q_all = tid >> 3, d0 = (tid & 7) * 8;
        int qg2 = q_all >> 4, ql = q_all & 15;
        float mm0 = msh[(qg2 * 2 + 0) * 16 + ql], mm1 = msh[(qg2 * 2 + 1) * 16 + ql];
        float MM = fmaxf(mm0, mm1);
        float lt = lsh[(qg2 * 2 + 0) * 16 + ql] * __expf(mm0 - MM) +
                   lsh[(qg2 * 2 + 1) * 16 + ql] * __expf(mm1 - MM);
        float inv = 1.0f / lt;
        short8 o8;
#pragma unroll
        for (int i = 0; i < 8; ++i) {
            float a = Osh[((qg2 * 2 + 0) * 16 + ql) * 68 + d0 + i] +
                      Osh[((qg2 * 2 + 1) * 16 + ql) * 68 + d0 + i];
            o8[i] = (short)f2bf(a * inv);
        }
        *(short8*)((short*)Ob + (size_t)(b * S_ + i0 + q_all) * D_ + h * HD_ + d0) = o8;
    }
}

// ------------------------------------------- global queries, split-K, same core
__global__ __launch_bounds__(256, 4) void attn_global_kernel(const __hip_bfloat16* __restrict__ QKVb,
                                                             const int* __restrict__ pad_all,
                                                             float* __restrict__ pacc,
                                                             float* __restrict__ pm,
                                                             float* __restrict__ pl) {
    __shared__ __align__(16) char smem[ATT_LDS_];
    short* Qs = (short*)(smem + 0);
    short* Ks = (short*)(smem + 4608);
    short* Vt = (short*)(smem + 13824);
    short* Pl = (short*)(smem + 23040);
    float* padv = (float*)(smem + 27648);
    float* msh  = (float*)(smem + 27968);
    float* lsh  = (float*)(smem + 28224);
    float* Osh  = (float*)smem;

    const int TS[KC_ + 1] = {0, 8, 17, 25, 34};
    int bid = blockIdx.x;
    int c  = bid & 3;
    int qt = (bid >> 2) & 3;
    int h  = (bid >> 4) & 7;
    int b  = bid >> 7;
    int i0 = SL_ + qt * 32;
    int tid = threadIdx.x;
    int w = tid >> 6, lane = tid & 63;
    int qg = w >> 1, kh = w & 1;
    int cq = lane & 15, g4 = lane >> 4;
    const int* pad = pad_all + b * S_;
    const short* qkv = (const short*)QKVb;

    {
        int q = tid >> 3, g = tid & 7;
        short8 v = *(const short8*)(qkv + (size_t)(b * S_ + i0 + q) * QKVLD_ + h * HD_ + g * 8);
        *(short8*)(Qs + q * 72 + g * 8) = v;
    }

    float mreg = MINF_, lreg = 0.0f;
    f32x4 ot0 = {0,0,0,0}, ot1 = {0,0,0,0}, ot2 = {0,0,0,0}, ot3 = {0,0,0,0};

    for (int t = TS[c]; t < TS[c + 1]; ++t) {
        int j0 = t * 64;
        __syncthreads();
        {
            int key = tid >> 2, g2 = tid & 3;
            size_t base = (size_t)(b * S_ + j0 + key) * QKVLD_ + h * HD_;
#pragma unroll
            for (int gg = 0; gg < 2; ++gg) {
                int g = g2 + gg * 4;
                short8 kv = *(const short8*)(qkv + base + 512 + g * 8);
                *(short8*)(Ks + key * 72 + g * 8) = kv;
                short8 vv = *(const short8*)(qkv + base + 1024 + g * 8);
#pragma unroll
                for (int i = 0; i < 8; ++i)
                    Vt[(g * 8 + i) * 72 + key] = vv[i];
            }
            if (tid < 64) padv[tid] = pad[j0 + tid] ? NEG_ : 0.0f;
        }
        __syncthreads();

        short8 qf0 = *(const short8*)(Qs + (qg * 16 + cq) * 72 + 0 + g4 * 8);
        short8 qf1 = *(const short8*)(Qs + (qg * 16 + cq) * 72 + 32 + g4 * 8);
        f32x4 st0 = {0,0,0,0}, st1 = {0,0,0,0};
        {
            short8 kf;
            kf = *(const short8*)(Ks + (kh * 32 + cq) * 72 + 0 + g4 * 8);
            st0 = __builtin_amdgcn_mfma_f32_16x16x32_bf16(kf, qf0, st0, 0, 0, 0);
            kf = *(const short8*)(Ks + (kh * 32 + cq) * 72 + 32 + g4 * 8);
            st0 = __builtin_amdgcn_mfma_f32_16x16x32_bf16(kf, qf1, st0, 0, 0, 0);
            kf = *(const short8*)(Ks + (kh * 32 + 16 + cq) * 72 + 0 + g4 * 8);
            st1 = __builtin_amdgcn_mfma_f32_16x16x32_bf16(kf, qf0, st1, 0, 0, 0);
            kf = *(const short8*)(Ks + (kh * 32 + 16 + cq) * 72 + 32 + g4 * 8);
            st1 = __builtin_amdgcn_mfma_f32_16x16x32_bf16(kf, qf1, st1, 0, 0, 0);
        }
        float sarr[8];
#pragma unroll
        for (int mt = 0; mt < 2; ++mt)
#pragma unroll
            for (int j = 0; j < 4; ++j) {
                int k = kh * 32 + mt * 16 + g4 * 4 + j;
                sarr[mt * 4 + j] = (mt ? st1[j] : st0[j]) * 0.125f + padv[k];
            }
        float cmax = sarr[0];
#pragma unroll
        for (int i = 1; i < 8; ++i) cmax = fmaxf(cmax, sarr[i]);
        cmax = fmaxf(cmax, __shfl_xor(cmax, 16));
        cmax = fmaxf(cmax, __shfl_xor(cmax, 32));
        float mnew = fmaxf(mreg, cmax);
        float fac = __expf(mreg - mnew);
        float parr[8], psum = 0.0f;
#pragma unroll
        for (int i = 0; i < 8; ++i) { parr[i] = __expf(sarr[i] - mnew); psum += parr[i]; }
        psum += __shfl_xor(psum, 16);
        psum += __shfl_xor(psum, 32);
        lreg = lreg * fac + psum;
        mreg = mnew;
        ot0 *= fac; ot1 *= fac; ot2 *= fac; ot3 *= fac;
#pragma unroll
        for (int mt = 0; mt < 2; ++mt) {
            unsigned int lo = (unsigned int)f2bf(parr[mt * 4 + 0]) | ((unsigned int)f2bf(parr[mt * 4 + 1]) << 16);
            unsigned int hi = (unsigned int)f2bf(parr[mt * 4 + 2]) | ((unsigned int)f2bf(parr[mt * 4 + 3]) << 16);
            unsigned int* dst = (unsigned int*)(Pl + (qg * 16 + cq) * 72 + kh * 32 + mt * 16 + g4 * 4);
            dst[0] = lo; dst[1] = hi;
        }
        short8 pf = *(const short8*)(Pl + (qg * 16 + cq) * 72 + kh * 32 + g4 * 8);
        {
            short8 vf;
            vf = *(const short8*)(Vt + (0 * 16 + cq) * 72 + kh * 32 + g4 * 8);
            ot0 = __builtin_amdgcn_mfma_f32_16x16x32_bf16(vf, pf, ot0, 0, 0, 0);
            vf = *(const short8*)(Vt + (1 * 16 + cq) * 72 + kh * 32 + g4 * 8);
            ot1 = __builtin_amdgcn_mfma_f32_16x16x32_bf16(vf, pf, ot1, 0, 0, 0);
            vf = *(const short8*)(Vt + (2 * 16 + cq) * 72 + kh * 32 + g4 * 8);
            ot2 = __builtin_amdgcn_mfma_f32_16x16x32_bf16(vf, pf, ot2, 0, 0, 0);
            vf = *(const short8*)(Vt + (3 * 16 + cq) * 72 + kh * 32 + g4 * 8);
            ot3 = __builtin_amdgcn_mfma_f32_16x16x32_bf16(vf, pf, ot3, 0, 0, 0);
        }
    }

    __syncthreads();
    if (g4 == 0) {
        msh[(qg * 2 + kh) * 16 + cq] = mreg;
        lsh[(qg * 2 + kh) * 16 + cq] = lreg;
    }
    __syncthreads();
    {
        float m0 = msh[(qg * 2 + 0) * 16 + cq], m1 = msh[(qg * 2 + 1) * 16 + cq];
        float Mm = fmaxf(m0, m1);
        float e_self = __expf(mreg - Mm);
        f32x4 o;
        o = ot0 * e_self; *(f32x4*)(Osh + ((qg * 2 + kh) * 16 + cq) * 68 + 0  + g4 * 4) = o;
        o = ot1 * e_self; *(f32x4*)(Osh + ((qg * 2 + kh) * 16 + cq) * 68 + 16 + g4 * 4) = o;
        o = ot2 * e_self; *(f32x4*)(Osh + ((qg * 2 + kh) * 16 + cq) * 68 + 32 + g4 * 4) = o;
        o = ot3 * e_self; *(f32x4*)(Osh + ((qg * 2 + kh) * 16 + cq) * 68 + 48 + g4 * 4) = o;
    }
    __syncthreads();
    {
        int q_all = tid >> 3, d0 = (tid & 7) * 8;
        int qg2 = q_all >> 4, ql = q_all & 15;
        float mm0 = msh[(qg2 * 2 + 0) * 16 + ql], mm1 = msh[(qg2 * 2 + 1) * 16 + ql];
        float MM = fmaxf(mm0, mm1);
        float lt = lsh[(qg2 * 2 + 0) * 16 + ql] * __expf(mm0 - MM) +
                   lsh[(qg2 * 2 + 1) * 16 + ql] * __expf(mm1 - MM);
        int prow = ((c * B_ + b) * H_ + h) * SG_ + qt * 32 + q_all;
#pragma unroll
        for (int i = 0; i < 8; ++i) {
            float a = Osh[((qg2 * 2 + 0) * 16 + ql) * 68 + d0 + i] +
                      Osh[((qg2 * 2 + 1) * 16 + ql) * 68 + d0 + i];
            pacc[(size_t)prow * HD_ + d0 + i] = a;
        }
        if ((tid & 7) == 0) { pm[prow] = MM; pl[prow] = lt; }
    }
}

__global__ __launch_bounds__(256) void attn_combine_kernel(const float* __restrict__ pacc,
                                                           const float* __restrict__ pm,
                                                           const float* __restrict__ pl,
                                                           __hip_bfloat16* __restrict__ Ob) {
    int wave = (int)((blockIdx.x * (size_t)blockDim.x + threadIdx.x) >> 6);
    int lane = threadIdx.x & 63;
    int gq = wave & (SG_ - 1);
    int h  = (wave >> 7) & 7;
    int b  = wave >> 10;

    float M = MINF_;
#pragma unroll
    for (int c = 0; c < KC_; ++c) {
        int pidx = ((c * B_ + b) * H_ + h) * SG_ + gq;
        M = fmaxf(M, pm[pidx]);
    }
    float L = 0.0f, Ov = 0.0f;
#pragma unroll
    for (int c = 0; c < KC_; ++c) {
        int pidx = ((c * B_ + b) * H_ + h) * SG_ + gq;
        float e = __expf(pm[pidx] - M);
        L += pl[pidx] * e;
        Ov += pacc[(size_t)pidx * HD_ + lane] * e;
    }
    Ob[(size_t)(b * S_ + SL_ + gq) * D_ + h * HD_ + lane] = __float2bfloat16(Ov / L);
}

// ---------------------------------------------------------------- residual + LN
__global__ __launch_bounds__(256) void ln_kernel(const float* __restrict__ A,
                                                 const float* __restrict__ Bres,
                                                 const float* __restrict__ g,
                                                 const float* __restrict__ be,
                                                 float* __restrict__ out,
                                                 __hip_bfloat16* __restrict__ outb,
                                                 int wb) {
    int row = blockIdx.x;
    int tid = threadIdx.x;
    size_t base = (size_t)row * D_;
    float x0 = A[base + tid]       + Bres[base + tid];
    float x1 = A[base + tid + 256] + Bres[base + tid + 256];
    float s1 = x0 + x1;
    float s2 = x0 * x0 + x1 * x1;
    for (int off = 1; off < 64; off <<= 1) {
        s1 += __shfl_xor(s1, off);
        s2 += __shfl_xor(s2, off);
    }
    __shared__ float ws1[4], ws2[4];
    int wid = tid >> 6;
    if ((tid & 63) == 0) { ws1[wid] = s1; ws2[wid] = s2; }
    __syncthreads();
    s1 = ws1[0] + ws1[1] + ws1[2] + ws1[3];
    s2 = ws2[0] + ws2[1] + ws2[2] + ws2[3];
    float mean = s1 * (1.0f / D_);
    float var  = s2 * (1.0f / D_) - mean * mean;
    float rstd = rsqrtf(var + 1e-5f);
    float o0 = (x0 - mean) * rstd * g[tid]       + be[tid];
    float o1 = (x1 - mean) * rstd * g[tid + 256] + be[tid + 256];
    out[base + tid]       = o0;
    out[base + tid + 256] = o1;
    if (wb) {
        outb[base + tid]       = __float2bfloat16(o0);
        outb[base + tid + 256] = __float2bfloat16(o1);
    }
}

// ---------------------------------------------------------------- pool + classifier (3-stage)
__global__ __launch_bounds__(256) void pool_zg_kernel(const float* __restrict__ x2,
                                                      const int* __restrict__ pad_all,
                                                      float* __restrict__ zg) {
    int b = blockIdx.x, tid = threadIdx.x;
    float a0 = 0.f, a1 = 0.f, c = 0.f;
    for (int g = 0; g < SG_; ++g) {
        int p = pad_all[b * S_ + SL_ + g];
        if (!p) {
            size_t base = (size_t)(b * S_ + SL_ + g) * D_;
            a0 += x2[base + tid];
            a1 += x2[base + tid + 256];
            c += 1.0f;
        }
    }
    float inv = 1.0f / c;
    zg[b * D_ + tid]       = a0 * inv;
    zg[b * D_ + tid + 256] = a1 * inv;
}

__global__ __launch_bounds__(256) void cls_part_kernel(const float* __restrict__ zg,
                                                       const float* __restrict__ w1,
                                                       float* __restrict__ part) {
    int kc = blockIdx.x, b = blockIdx.y, n = threadIdx.x;
    float s = 0.0f;
#pragma unroll 4
    for (int dd = 0; dd < 64; ++dd)
        s = fmaf(zg[b * D_ + kc * 64 + dd], w1[(size_t)(kc * 64 + dd) * 256 + n], s);
    part[(b * 8 + kc) * 256 + n] = s;
}

__global__ __launch_bounds__(256) void cls_fin_kernel(const float* __restrict__ part,
                                                      const float* __restrict__ w2,
                                                      float* __restrict__ out) {
    int b = blockIdx.x, n = threadIdx.x;
    float hsum = 0.0f;
#pragma unroll
    for (int kc = 0; kc < 8; ++kc) hsum += part[(b * 8 + kc) * 256 + n];
    hsum = fmaxf(hsum, 0.0f);
    float o0 = hsum * w2[(size_t)n * NC_ + 0];
    float o1 = hsum * w2[(size_t)n * NC_ + 1];
    o0 = wave_sum(o0);
    o1 = wave_sum(o1);
    __shared__ float r0[4], r1[4];
    if ((n & 63) == 0) { r0[n >> 6] = o0; r1[n >> 6] = o1; }
    __syncthreads();
    if (n == 0) {
        out[b * NC_ + 0] = r0[0] + r0[1] + r0[2] + r0[3];
        out[b * NC_ + 1] = r1[0] + r1[1] + r1[2] + r1[3];
    }
}

// ---------------------------------------------------------------- launch
extern "C" void kernel_launch(void* const* d_in, const int* in_sizes, int n_in,
                              void* d_out, int out_size, void* d_ws, size_t ws_size,
                              hipStream_t stream) {
    const int*   ids    = (const int*)d_in[0];
    const float* embed  = (const float*)d_in[1];
    const float* gtok   = (const float*)d_in[2];
    const float* relb   = (const float*)d_in[3];
    const float* q_w    = (const float*)d_in[4];
    const float* q_b    = (const float*)d_in[5];
    const float* k_w    = (const float*)d_in[6];
    const float* k_b    = (const float*)d_in[7];
    const float* v_w    = (const float*)d_in[8];
    const float* v_b    = (const float*)d_in[9];
    const float* o_w    = (const float*)d_in[10];
    const float* o_b    = (const float*)d_in[11];
    const float* ln1_g  = (const float*)d_in[12];
    const float* ln1_b  = (const float*)d_in[13];
    const float* ln2_g  = (const float*)d_in[14];
    const float* ln2_b  = (const float*)d_in[15];
    const float* ff1_w  = (const float*)d_in[16];
    const float* ff1_b  = (const float*)d_in[17];
    const float* ff2_w  = (const float*)d_in[18];
    const float* ff2_b  = (const float*)d_in[19];
    const float* cls_w1 = (const float*)d_in[20];
    const float* cls_w2 = (const float*)d_in[21];

    char* ws = (char*)d_ws;
    // layout (bytes):
    // 0         x_f32   8,912,896   (x2 aliases after LN1)
    // 8912896   x_b     4,456,448   (x1 f32 aliases [8912896, 17825792) after attention)
    // 13369344  qkv_bf  13,369,344  (tail of x1; ffh bf16 at [17825792, 26738688))
    // 26738688  o_bf    4,456,448   (x1b aliases after O-proj)
    // 31195136  tmp f32 8,912,896   (pacc/pm/pl alias its head during attention; tmp2 alias)
    // 40108032  weights + misc
    float*          x_f32  = (float*)(ws);
    __hip_bfloat16* x_b    = (__hip_bfloat16*)(ws + 8912896);
    __hip_bfloat16* qkv_bf = (__hip_bfloat16*)(ws + 13369344);
    __hip_bfloat16* o_bf   = (__hip_bfloat16*)(ws + 26738688);
    float*          tmp    = (float*)(ws + 31195136);
    char*           extra  = ws + 40108032;

    __hip_bfloat16* WqkvT = (__hip_bfloat16*)extra;                      // 1,572,864
    __hip_bfloat16* WoT   = (__hip_bfloat16*)(extra + 1572864);          //   524,288
    __hip_bfloat16* Wff1T = (__hip_bfloat16*)(extra + 2097152);          // 1,048,576
    __hip_bfloat16* Wff2T = (__hip_bfloat16*)(extra + 3145728);          // 1,048,576
    float* qkvb    = (float*)(extra + 4194304);                          //     6,144
    int*   pad_all = (int*)(extra + 4202496);                            //    17,408
    float* zg      = (float*)(extra + 4227072);                          //     4,096
    float* clspart = (float*)(extra + 4231168);                          //    16,384

    float* pacc = tmp;                                    // 2,097,152 (dead before tmp written)
    float* pm   = (float*)((char*)tmp + 2097152);         //    32,768
    float* pl   = (float*)((char*)tmp + 2129920);         //    32,768

    float*          x1   = (float*)(ws + 8912896);        // alias x_b + qkv_bf head
    __hip_bfloat16* x1b  = o_bf;
    __hip_bfloat16* ffh  = (__hip_bfloat16*)(ws + 17825792);  // qkv_bf tail
    float*          tmp2 = tmp;
    float*          x2   = x_f32;

    build_x_kernel<<<MROWS_, 128, 0, stream>>>(ids, embed, gtok, x_f32, x_b, pad_all);
    bias_concat_kernel<<<6, 256, 0, stream>>>(q_b, k_b, v_b, qkvb);
    wt_all_kernel<<<512, 256, 0, stream>>>(q_w, k_w, v_w, o_w, ff1_w, ff2_w,
                                           WqkvT, WoT, Wff1T, Wff2T);

    gemm_bt_kernel<<<dim3(12, 34), 256, 0, stream>>>(x_b, WqkvT, qkvb, qkv_bf, QKVLD_, 512, 2);

    attn_long_kernel<<<B_ * H_ * 64, 256, 0, stream>>>(qkv_bf, relb, pad_all, o_bf);
    attn_global_kernel<<<B_ * H_ * 4 * KC_, 256, 0, stream>>>(qkv_bf, pad_all, pacc, pm, pl);
    attn_combine_kernel<<<(B_ * H_ * SG_) / 4, 256, 0, stream>>>(pacc, pm, pl, o_bf);

    gemm_bt_kernel<<<dim3(4, 34), 256, 0, stream>>>(o_bf, WoT, o_b, tmp, 512, 512, 0);
    ln_kernel<<<MROWS_, 256, 0, stream>>>(x_f32, tmp, ln1_g, ln1_b, x1, x1b, 1);

    gemm_bt_kernel<<<dim3(8, 34), 256, 0, stream>>>(x1b, Wff1T, ff1_b, ffh, 1024, 512, 3);
    gemm_bt_kernel<<<dim3(4, 34), 256, 0, stream>>>(ffh, Wff2T, ff2_b, tmp2, 512, 1024, 0);
    ln_kernel<<<MROWS_, 256, 0, stream>>>(x1, tmp2, ln2_g, ln2_b, x2, nullptr, 0);

    pool_zg_kernel<<<B_, 256, 0, stream>>>(x2, pad_all, zg);
    cls_part_kernel<<<dim3(8, B_), 256, 0, stream>>>(zg, cls_w1, clspart);
    cls_fin_kernel<<<B_, 256, 0, stream>>>(clspart, cls_w2, (float*)d_out);
}

// Round 7
// 136.223 us; speedup vs baseline: 10.4509x; 1.3538x over previous
//
#include <hip/hip_runtime.h>
#include <hip/hip_bf16.h>
#include <cstddef>

#define B_ 2
#define SL_ 2048
#define RATIO_ 16
#define SG_ 128
#define S_ 2176
#define D_ 512
#define H_ 8
#define HD_ 64
#define FF_ 1024
#define NC_ 2
#define NEG_ (-1.0e9f)
#define MINF_ (-1.0e30f)
#define MROWS_ (B_ * S_)   // 4352
#define GR_ (B_ * SG_)     // 256 global rows (the only live rows post-attention)
#define KC_ 8              // split-K chunks for global-query attention

typedef __attribute__((ext_vector_type(8))) short short8;
typedef __attribute__((ext_vector_type(4))) float f32x4;

__device__ __forceinline__ void gll16(const void* g, void* l) {
    __builtin_amdgcn_global_load_lds((const __attribute__((address_space(1))) void*)g,
                                     (__attribute__((address_space(3))) void*)l, 16, 0, 0);
}
__device__ __forceinline__ unsigned short f2bf(float x) {
    __hip_bfloat16 h = __float2bfloat16(x);
    return *reinterpret_cast<unsigned short*>(&h);
}
__device__ __forceinline__ float wave_sum(float v) {
#pragma unroll
    for (int off = 1; off < 64; off <<= 1) v += __shfl_xor(v, off);
    return v;
}
// raw barrier (no compiler-inserted vmcnt(0) drain) + compiler memory fence
#define BARRIER() do { asm volatile("" ::: "memory"); __builtin_amdgcn_s_barrier(); asm volatile("" ::: "memory"); } while (0)

// ---------------------------------------------------------------- build x_b (full bf16) + xg (global f32) + pad
__global__ void build_x_kernel(const int* __restrict__ ids,
                               const float* __restrict__ embed,
                               const float* __restrict__ gtok,
                               __hip_bfloat16* __restrict__ xb,
                               float* __restrict__ xg,
                               int* __restrict__ pad_all) {
    int row = blockIdx.x;
    int b = row / S_, s = row % S_;
    const float* src;
    if (s < SL_) {
        int tok = ids[b * SL_ + s];
        src = embed + (size_t)tok * D_;
        if (threadIdx.x == 0) pad_all[row] = (tok == 0) ? 1 : 0;
    } else {
        src = gtok;
        if (threadIdx.x == 0) {
            int g = s - SL_;
            int allz = 1;
            for (int r = 0; r < RATIO_; ++r)
                allz &= (ids[b * SL_ + g * RATIO_ + r] == 0) ? 1 : 0;
            pad_all[row] = allz;
        }
    }
    float4 v = ((const float4*)src)[threadIdx.x];
    __hip_bfloat16 hb[4] = {__float2bfloat16(v.x), __float2bfloat16(v.y),
                            __float2bfloat16(v.z), __float2bfloat16(v.w)};
    *(uint2*)(xb + (size_t)row * D_ + threadIdx.x * 4) = *(const uint2*)hb;
    if (s >= SL_)
        ((float4*)(xg + (size_t)(b * SG_ + s - SL_) * D_))[threadIdx.x] = v;
}

// ---------------------------------------------------------------- fused weight transpose+convert (+kv bias concat)
__global__ __launch_bounds__(256) void wt_all_kernel(const float* __restrict__ qw,
                                                     const float* __restrict__ kw,
                                                     const float* __restrict__ vw,
                                                     const float* __restrict__ ow,
                                                     const float* __restrict__ f1w,
                                                     const float* __restrict__ f2w,
                                                     __hip_bfloat16* __restrict__ WqT,
                                                     __hip_bfloat16* __restrict__ WkvT,
                                                     __hip_bfloat16* __restrict__ WoT,
                                                     __hip_bfloat16* __restrict__ W1T,
                                                     __hip_bfloat16* __restrict__ W2T,
                                                     const float* __restrict__ k_b,
                                                     const float* __restrict__ v_b,
                                                     float* __restrict__ kvb) {
    __shared__ float tile[64][65];
    int bid = blockIdx.x;
    int tid = threadIdx.x;
    if (bid == 0) {
#pragma unroll
        for (int i = tid; i < 1024; i += 256)
            kvb[i] = (i < 512) ? k_b[i] : v_b[i - 512];
    }
    const float* W; __hip_bfloat16* Wt; int K, N, tx, ty;
    if (bid < 192) {
        int which = bid >> 6, id = bid & 63;
        W = (which == 0) ? qw : (which == 1) ? kw : vw;
        Wt = (which == 0) ? WqT : (which == 1) ? WkvT : (WkvT + (size_t)512 * 512);
        K = 512; N = 512; tx = id & 7; ty = id >> 3;
    } else if (bid < 256) {
        int id = bid - 192; W = ow; Wt = WoT; K = 512; N = 512; tx = id & 7; ty = id >> 3;
    } else if (bid < 384) {
        int id = bid - 256; W = f1w; Wt = W1T; K = 512; N = 1024; tx = id & 15; ty = id >> 4;
    } else {
        int id = bid - 384; W = f2w; Wt = W2T; K = 1024; N = 512; tx = id & 7; ty = id >> 3;
    }
    int n0 = tx * 64, k0 = ty * 64;
    int c = tid & 63, r4 = tid >> 6;
#pragma unroll
    for (int i = 0; i < 16; ++i) {
        int r = i * 4 + r4;
        tile[r][c] = W[(size_t)(k0 + r) * N + n0 + c];
    }
    __syncthreads();
#pragma unroll
    for (int i = 0; i < 16; ++i) {
        int n = i * 4 + r4;
        Wt[(size_t)(n0 + n) * K + k0 + c] = __float2bfloat16(tile[c][n]);
    }
}

// ---------------------------------------------------------------- 128x128 bf16 MFMA GEMM, 2-phase dbuf prefetch
// flags: 1 = relu, 2 = bf16 output
__global__ __launch_bounds__(256) void gemm_bt_kernel(const __hip_bfloat16* __restrict__ A,
                                                      const __hip_bfloat16* __restrict__ Bt,
                                                      const float* __restrict__ bias,
                                                      void* __restrict__ Cout,
                                                      int N, int K, int flags) {
    __shared__ short As[2][128 * 32];
    __shared__ short Bs[2][128 * 32];
    int tid = threadIdx.x;
    int m0 = blockIdx.y * 128, n0 = blockIdx.x * 128;
    int w = tid >> 6, lane = tid & 63;
    int wr = w >> 1, wc = w & 1;

    f32x4 acc[4][4];
#pragma unroll
    for (int m = 0; m < 4; ++m)
#pragma unroll
        for (int n = 0; n < 4; ++n)
            acc[m][n] = (f32x4){0.f, 0.f, 0.f, 0.f};

    int p0 = tid * 16, rs = p0 >> 6, cs = p0 & 63;
    const char* Ab = (const char*)A;
    const char* Bb = (const char*)Bt;

    auto STAGE = [&](int buf, int k0) {
        gll16(Ab + ((size_t)(m0 + rs) * K + k0) * 2 + cs, (char*)As[buf] + p0);
        gll16(Ab + ((size_t)(m0 + rs + 64) * K + k0) * 2 + cs, (char*)As[buf] + p0 + 4096);
        gll16(Bb + ((size_t)(n0 + rs) * K + k0) * 2 + cs, (char*)Bs[buf] + p0);
        gll16(Bb + ((size_t)(n0 + rs + 64) * K + k0) * 2 + cs, (char*)Bs[buf] + p0 + 4096);
    };
    STAGE(0, 0);
    int nk = K >> 5;
    for (int t = 0; t < nk; ++t) {
        int cur = t & 1;
        if (t + 1 < nk) {
            STAGE(cur ^ 1, (t + 1) << 5);
            asm volatile("s_waitcnt vmcnt(4)" ::: "memory");   // cur's 4 loads done; next 4 in flight
        } else {
            asm volatile("s_waitcnt vmcnt(0)" ::: "memory");
        }
        BARRIER();
        short8 af[4], bfr[4];
#pragma unroll
        for (int m = 0; m < 4; ++m)
            af[m] = *(const short8*)&As[cur][(wr * 64 + m * 16 + (lane & 15)) * 32 + (lane >> 4) * 8];
#pragma unroll
        for (int n = 0; n < 4; ++n)
            bfr[n] = *(const short8*)&Bs[cur][(wc * 64 + n * 16 + (lane & 15)) * 32 + (lane >> 4) * 8];
#pragma unroll
        for (int m = 0; m < 4; ++m)
#pragma unroll
            for (int n = 0; n < 4; ++n)
                acc[m][n] = __builtin_amdgcn_mfma_f32_16x16x32_bf16(af[m], bfr[n], acc[m][n], 0, 0, 0);
        BARRIER();   // protect cur from next iteration's prefetch overwrite
    }

    int rbase = m0 + wr * 64 + (lane >> 4) * 4;
    int cbase = n0 + wc * 64 + (lane & 15);
#pragma unroll
    for (int m = 0; m < 4; ++m)
#pragma unroll
        for (int n = 0; n < 4; ++n) {
            int col = cbase + n * 16;
            float bv = bias[col];
#pragma unroll
            for (int j = 0; j < 4; ++j) {
                int row = rbase + m * 16 + j;
                float v = acc[m][n][j] + bv;
                if (flags & 1) v = fmaxf(v, 0.0f);
                if (flags & 2)
                    ((__hip_bfloat16*)Cout)[(size_t)row * N + col] = __float2bfloat16(v);
                else
                    ((float*)Cout)[(size_t)row * N + col] = v;
            }
        }
}

// ---------------------------------------------------------------- 64x64 bf16 MFMA GEMM (small-M tail), dbuf
// flags: 1 = relu, 2 = bf16 output, 4 = add residual Res[row*N+col], 8 = A-row remap (global rows of full x_b)
__global__ __launch_bounds__(256) void gemm64_kernel(const __hip_bfloat16* __restrict__ A,
                                                     const __hip_bfloat16* __restrict__ Bt,
                                                     const float* __restrict__ bias,
                                                     const float* __restrict__ Res,
                                                     void* __restrict__ Cout,
                                                     int N, int K, int flags) {
    __shared__ short As[2][64 * 32];
    __shared__ short Bs[2][64 * 32];
    int tid = threadIdx.x;
    int m0 = blockIdx.y * 64, n0 = blockIdx.x * 64;
    int w = tid >> 6, lane = tid & 63;
    int wr = w >> 1, wc = w & 1;

    f32x4 acc[2][2];
#pragma unroll
    for (int m = 0; m < 2; ++m)
#pragma unroll
        for (int n = 0; n < 2; ++n)
            acc[m][n] = (f32x4){0.f, 0.f, 0.f, 0.f};

    int p0 = tid * 16, rs = p0 >> 6, cs = p0 & 63;
    int rl = m0 + rs;
    size_t arow = (flags & 8) ? (size_t)((rl >> 7) * S_ + SL_ + (rl & 127)) : (size_t)rl;
    const char* Ab = (const char*)A;
    const char* Bb = (const char*)Bt;

    auto STAGE = [&](int buf, int k0) {
        gll16(Ab + (arow * K + k0) * 2 + cs, (char*)As[buf] + p0);
        gll16(Bb + ((size_t)(n0 + rs) * K + k0) * 2 + cs, (char*)Bs[buf] + p0);
    };
    STAGE(0, 0);
    int nk = K >> 5;
    for (int t = 0; t < nk; ++t) {
        int cur = t & 1;
        if (t + 1 < nk) {
            STAGE(cur ^ 1, (t + 1) << 5);
            asm volatile("s_waitcnt vmcnt(2)" ::: "memory");
        } else {
            asm volatile("s_waitcnt vmcnt(0)" ::: "memory");
        }
        BARRIER();
        short8 af[2], bfr[2];
#pragma unroll
        for (int m = 0; m < 2; ++m)
            af[m] = *(const short8*)&As[cur][(wr * 32 + m * 16 + (lane & 15)) * 32 + (lane >> 4) * 8];
#pragma unroll
        for (int n = 0; n < 2; ++n)
            bfr[n] = *(const short8*)&Bs[cur][(wc * 32 + n * 16 + (lane & 15)) * 32 + (lane >> 4) * 8];
#pragma unroll
        for (int m = 0; m < 2; ++m)
#pragma unroll
            for (int n = 0; n < 2; ++n)
                acc[m][n] = __builtin_amdgcn_mfma_f32_16x16x32_bf16(af[m], bfr[n], acc[m][n], 0, 0, 0);
        BARRIER();
    }

    int rbase = m0 + wr * 32 + (lane >> 4) * 4;
    int cbase = n0 + wc * 32 + (lane & 15);
#pragma unroll
    for (int m = 0; m < 2; ++m)
#pragma unroll
        for (int n = 0; n < 2; ++n) {
            int col = cbase + n * 16;
            float bv = bias[col];
#pragma unroll
            for (int j = 0; j < 4; ++j) {
                int row = rbase + m * 16 + j;
                float v = acc[m][n][j] + bv;
                if (flags & 4) v += Res[(size_t)row * N + col];
                if (flags & 1) v = fmaxf(v, 0.0f);
                if (flags & 2)
                    ((__hip_bfloat16*)Cout)[(size_t)row * N + col] = __float2bfloat16(v);
                else
                    ((float*)Cout)[(size_t)row * N + col] = v;
            }
        }
}

// ================================================================ MFMA attention (global queries only), split-K
// LDS layout (bytes): Qs[32][72]s @0 | Ks[64][72]s @4608 | Vt[64][72]s @13824 |
// Pl[2][16][72]s @23040 | padv[64]f @27648 | msh @27968 | lsh @28224. Osh aliases head.
#define ATT_LDS_ 28480

__global__ __launch_bounds__(256, 4) void attn_global_kernel(const __hip_bfloat16* __restrict__ Qg,
                                                             const __hip_bfloat16* __restrict__ KV,
                                                             const int* __restrict__ pad_all,
                                                             float* __restrict__ pacc,
                                                             float* __restrict__ pm,
                                                             float* __restrict__ pl) {
    __shared__ __align__(16) char smem[ATT_LDS_];
    short* Qs = (short*)(smem + 0);
    short* Ks = (short*)(smem + 4608);
    short* Vt = (short*)(smem + 13824);
    short* Pl = (short*)(smem + 23040);
    float* padv = (float*)(smem + 27648);
    float* msh  = (float*)(smem + 27968);
    float* lsh  = (float*)(smem + 28224);
    float* Osh  = (float*)smem;

    const int TS[KC_ + 1] = {0, 4, 8, 12, 17, 21, 25, 29, 34};
    int bid = blockIdx.x;
    int c  = bid & 7;
    int qt = (bid >> 3) & 3;
    int h  = (bid >> 5) & 7;
    int b  = bid >> 8;
    int i0c = qt * 32;
    int tid = threadIdx.x;
    int w = tid >> 6, lane = tid & 63;
    int qg = w >> 1, kh = w & 1;
    int cq = lane & 15, g4 = lane >> 4;
    const int* pad = pad_all + b * S_;
    const short* qgp = (const short*)Qg;
    const short* kv  = (const short*)KV;

    {
        int q = tid >> 3, g = tid & 7;
        // NOTE: h * HD_ head offset (round-6 bug: was missing -> all heads used head 0)
        short8 v = *(const short8*)(qgp + (size_t)(b * SG_ + i0c + q) * D_ + h * HD_ + g * 8);
        *(short8*)(Qs + q * 72 + g * 8) = v;
    }

    float mreg = MINF_, lreg = 0.0f;
    f32x4 ot0 = {0,0,0,0}, ot1 = {0,0,0,0}, ot2 = {0,0,0,0}, ot3 = {0,0,0,0};

    for (int t = TS[c]; t < TS[c + 1]; ++t) {
        int j0 = t * 64;
        __syncthreads();
        {
            int key = tid >> 2, g2 = tid & 3;
            // NOTE: h * HD_ head offset here too
            size_t base = (size_t)(b * S_ + j0 + key) * 1024 + h * HD_;
#pragma unroll
            for (int gg = 0; gg < 2; ++gg) {
                int g = g2 + gg * 4;
                short8 kvv = *(const short8*)(kv + base + g * 8);
                *(short8*)(Ks + key * 72 + g * 8) = kvv;
                short8 vv = *(const short8*)(kv + base + 512 + g * 8);
#pragma unroll
                for (int i = 0; i < 8; ++i)
                    Vt[(g * 8 + i) * 72 + key] = vv[i];
            }
            if (tid < 64) padv[tid] = pad[j0 + tid] ? NEG_ : 0.0f;
        }
        __syncthreads();

        short8 qf0 = *(const short8*)(Qs + (qg * 16 + cq) * 72 + 0 + g4 * 8);
        short8 qf1 = *(const short8*)(Qs + (qg * 16 + cq) * 72 + 32 + g4 * 8);
        f32x4 st0 = {0,0,0,0}, st1 = {0,0,0,0};
        {
            short8 kf;
            kf = *(const short8*)(Ks + (kh * 32 + cq) * 72 + 0 + g4 * 8);
            st0 = __builtin_amdgcn_mfma_f32_16x16x32_bf16(kf, qf0, st0, 0, 0, 0);
            kf = *(const short8*)(Ks + (kh * 32 + cq) * 72 + 32 + g4 * 8);
            st0 = __builtin_amdgcn_mfma_f32_16x16x32_bf16(kf, qf1, st0, 0, 0, 0);
            kf = *(const short8*)(Ks + (kh * 32 + 16 + cq) * 72 + 0 + g4 * 8);
            st1 = __builtin_amdgcn_mfma_f32_16x16x32_bf16(kf, qf0, st1, 0, 0, 0);
            kf = *(const short8*)(Ks + (kh * 32 + 16 + cq) * 72 + 32 + g4 * 8);
            st1 = __builtin_amdgcn_mfma_f32_16x16x32_bf16(kf, qf1, st1, 0, 0, 0);
        }
        float sarr[8];
#pragma unroll
        for (int mt = 0; mt < 2; ++mt)
#pragma unroll
            for (int j = 0; j < 4; ++j) {
                int k = kh * 32 + mt * 16 + g4 * 4 + j;
                sarr[mt * 4 + j] = (mt ? st1[j] : st0[j]) * 0.125f + padv[k];
            }
        float cmax = sarr[0];
#pragma unroll
        for (int i = 1; i < 8; ++i) cmax = fmaxf(cmax, sarr[i]);
        cmax = fmaxf(cmax, __shfl_xor(cmax, 16));
        cmax = fmaxf(cmax, __shfl_xor(cmax, 32));
        float mnew = fmaxf(mreg, cmax);
        float fac = __expf(mreg - mnew);
        float parr[8], psum = 0.0f;
#pragma unroll
        for (int i = 0; i < 8; ++i) { parr[i] = __expf(sarr[i] - mnew); psum += parr[i]; }
        psum += __shfl_xor(psum, 16);
        psum += __shfl_xor(psum, 32);
        lreg = lreg * fac + psum;
        mreg = mnew;
        ot0 *= fac; ot1 *= fac; ot2 *= fac; ot3 *= fac;
#pragma unroll
        for (int mt = 0; mt < 2; ++mt) {
            unsigned int lo = (unsigned int)f2bf(parr[mt * 4 + 0]) | ((unsigned int)f2bf(parr[mt * 4 + 1]) << 16);
            unsigned int hi = (unsigned int)f2bf(parr[mt * 4 + 2]) | ((unsigned int)f2bf(parr[mt * 4 + 3]) << 16);
            unsigned int* dst = (unsigned int*)(Pl + (qg * 16 + cq) * 72 + kh * 32 + mt * 16 + g4 * 4);
            dst[0] = lo; dst[1] = hi;
        }
        short8 pf = *(const short8*)(Pl + (qg * 16 + cq) * 72 + kh * 32 + g4 * 8);
        {
            short8 vf;
            vf = *(const short8*)(Vt + (0 * 16 + cq) * 72 + kh * 32 + g4 * 8);
            ot0 = __builtin_amdgcn_mfma_f32_16x16x32_bf16(vf, pf, ot0, 0, 0, 0);
            vf = *(const short8*)(Vt + (1 * 16 + cq) * 72 + kh * 32 + g4 * 8);
            ot1 = __builtin_amdgcn_mfma_f32_16x16x32_bf16(vf, pf, ot1, 0, 0, 0);
            vf = *(const short8*)(Vt + (2 * 16 + cq) * 72 + kh * 32 + g4 * 8);
            ot2 = __builtin_amdgcn_mfma_f32_16x16x32_bf16(vf, pf, ot2, 0, 0, 0);
            vf = *(const short8*)(Vt + (3 * 16 + cq) * 72 + kh * 32 + g4 * 8);
            ot3 = __builtin_amdgcn_mfma_f32_16x16x32_bf16(vf, pf, ot3, 0, 0, 0);
        }
    }

    __syncthreads();
    if (g4 == 0) {
        msh[(qg * 2 + kh) * 16 + cq] = mreg;
        lsh[(qg * 2 + kh) * 16 + cq] = lreg;
    }
    __syncthreads();
    {
        float m0 = msh[(qg * 2 + 0) * 16 + cq], m1 = msh[(qg * 2 + 1) * 16 + cq];
        float Mm = fmaxf(m0, m1);
        float e_self = __expf(mreg - Mm);
        f32x4 o;
        o = ot0 * e_self; *(f32x4*)(Osh + ((qg * 2 + kh) * 16 + cq) * 68 + 0  + g4 * 4) = o;
        o = ot1 * e_self; *(f32x4*)(Osh + ((qg * 2 + kh) * 16 + cq) * 68 + 16 + g4 * 4) = o;
        o = ot2 * e_self; *(f32x4*)(Osh + ((qg * 2 + kh) * 16 + cq) * 68 + 32 + g4 * 4) = o;
        o = ot3 * e_self; *(f32x4*)(Osh + ((qg * 2 + kh) * 16 + cq) * 68 + 48 + g4 * 4) = o;
    }
    __syncthreads();
    {
        int q_all = tid >> 3, d0 = (tid & 7) * 8;
        int qg2 = q_all >> 4, ql = q_all & 15;
        float mm0 = msh[(qg2 * 2 + 0) * 16 + ql], mm1 = msh[(qg2 * 2 + 1) * 16 + ql];
        float MM = fmaxf(mm0, mm1);
        float lt = lsh[(qg2 * 2 + 0) * 16 + ql] * __expf(mm0 - MM) +
                   lsh[(qg2 * 2 + 1) * 16 + ql] * __expf(mm1 - MM);
        int prow = ((c * B_ + b) * H_ + h) * SG_ + qt * 32 + q_all;
#pragma unroll
        for (int i = 0; i < 8; ++i) {
            float a = Osh[((qg2 * 2 + 0) * 16 + ql) * 68 + d0 + i] +
                      Osh[((qg2 * 2 + 1) * 16 + ql) * 68 + d0 + i];
            pacc[(size_t)prow * HD_ + d0 + i] = a;
        }
        if ((tid & 7) == 0) { pm[prow] = MM; pl[prow] = lt; }
    }
}

__global__ __launch_bounds__(256) void attn_combine_kernel(const float* __restrict__ pacc,
                                                           const float* __restrict__ pm,
                                                           const float* __restrict__ pl,
                                                           __hip_bfloat16* __restrict__ Og) {
    int wave = (int)((blockIdx.x * (size_t)blockDim.x + threadIdx.x) >> 6);
    int lane = threadIdx.x & 63;
    int gq = wave & (SG_ - 1);
    int h  = (wave >> 7) & 7;
    int b  = wave >> 10;

    float M = MINF_;
#pragma unroll
    for (int c = 0; c < KC_; ++c) {
        int pidx = ((c * B_ + b) * H_ + h) * SG_ + gq;
        M = fmaxf(M, pm[pidx]);
    }
    float L = 0.0f, Ov = 0.0f;
#pragma unroll
    for (int c = 0; c < KC_; ++c) {
        int pidx = ((c * B_ + b) * H_ + h) * SG_ + gq;
        float e = __expf(pm[pidx] - M);
        L += pl[pidx] * e;
        Ov += pacc[(size_t)pidx * HD_ + lane] * e;
    }
    Og[(size_t)(b * SG_ + gq) * D_ + h * HD_ + lane] = __float2bfloat16(Ov / L);
}

// ---------------------------------------------------------------- LN (input already has residual added)
__global__ __launch_bounds__(256) void ln_kernel(const float* __restrict__ A,
                                                 const float* __restrict__ g,
                                                 const float* __restrict__ be,
                                                 float* __restrict__ out,
                                                 __hip_bfloat16* __restrict__ outb,
                                                 int wb) {
    int row = blockIdx.x;
    int tid = threadIdx.x;
    size_t base = (size_t)row * D_;
    float x0 = A[base + tid];
    float x1 = A[base + tid + 256];
    float s1 = x0 + x1;
    float s2 = x0 * x0 + x1 * x1;
    for (int off = 1; off < 64; off <<= 1) {
        s1 += __shfl_xor(s1, off);
        s2 += __shfl_xor(s2, off);
    }
    __shared__ float ws1[4], ws2[4];
    int wid = tid >> 6;
    if ((tid & 63) == 0) { ws1[wid] = s1; ws2[wid] = s2; }
    __syncthreads();
    s1 = ws1[0] + ws1[1] + ws1[2] + ws1[3];
    s2 = ws2[0] + ws2[1] + ws2[2] + ws2[3];
    float mean = s1 * (1.0f / D_);
    float var  = s2 * (1.0f / D_) - mean * mean;
    float rstd = rsqrtf(var + 1e-5f);
    float o0 = (x0 - mean) * rstd * g[tid]       + be[tid];
    float o1 = (x1 - mean) * rstd * g[tid + 256] + be[tid + 256];
    out[base + tid]       = o0;
    out[base + tid + 256] = o1;
    if (wb) {
        outb[base + tid]       = __float2bfloat16(o0);
        outb[base + tid + 256] = __float2bfloat16(o1);
    }
}

// ---------------------------------------------------------------- pool (fused) + classifier
__global__ __launch_bounds__(256) void cls_pool_kernel(const float* __restrict__ x2g,
                                                       const int* __restrict__ pad_all,
                                                       const float* __restrict__ w1,
                                                       float* __restrict__ part) {
    int kc = blockIdx.x, b = blockIdx.y, n = threadIdx.x;
    __shared__ float zgs[64];
    __shared__ float cnt_s;
    if (n < 64) {
        float a = 0.f, c = 0.f;
        for (int g = 0; g < SG_; ++g) {
            if (!pad_all[b * S_ + SL_ + g]) {
                a += x2g[(size_t)(b * SG_ + g) * D_ + kc * 64 + n];
                c += 1.0f;
            }
        }
        zgs[n] = a;
        if (n == 0) cnt_s = c;
    }
    __syncthreads();
    float inv = 1.0f / cnt_s;
    float s = 0.0f;
#pragma unroll 4
    for (int dd = 0; dd < 64; ++dd)
        s = fmaf(zgs[dd] * inv, w1[(size_t)(kc * 64 + dd) * 256 + n], s);
    part[(b * 8 + kc) * 256 + n] = s;
}

__global__ __launch_bounds__(256) void cls_fin_kernel(const float* __restrict__ part,
                                                      const float* __restrict__ w2,
                                                      float* __restrict__ out) {
    int b = blockIdx.x, n = threadIdx.x;
    float hsum = 0.0f;
#pragma unroll
    for (int kc = 0; kc < 8; ++kc) hsum += part[(b * 8 + kc) * 256 + n];
    hsum = fmaxf(hsum, 0.0f);
    float o0 = hsum * w2[(size_t)n * NC_ + 0];
    float o1 = hsum * w2[(size_t)n * NC_ + 1];
    o0 = wave_sum(o0);
    o1 = wave_sum(o1);
    __shared__ float r0[4], r1[4];
    if ((n & 63) == 0) { r0[n >> 6] = o0; r1[n >> 6] = o1; }
    __syncthreads();
    if (n == 0) {
        out[b * NC_ + 0] = r0[0] + r0[1] + r0[2] + r0[3];
        out[b * NC_ + 1] = r1[0] + r1[1] + r1[2] + r1[3];
    }
}

// ---------------------------------------------------------------- launch
extern "C" void kernel_launch(void* const* d_in, const int* in_sizes, int n_in,
                              void* d_out, int out_size, void* d_ws, size_t ws_size,
                              hipStream_t stream) {
    const int*   ids    = (const int*)d_in[0];
    const float* embed  = (const float*)d_in[1];
    const float* gtok   = (const float*)d_in[2];
    const float* q_w    = (const float*)d_in[4];
    const float* q_b    = (const float*)d_in[5];
    const float* k_w    = (const float*)d_in[6];
    const float* k_b    = (const float*)d_in[7];
    const float* v_w    = (const float*)d_in[8];
    const float* v_b    = (const float*)d_in[9];
    const float* o_w    = (const float*)d_in[10];
    const float* o_b    = (const float*)d_in[11];
    const float* ln1_g  = (const float*)d_in[12];
    const float* ln1_b  = (const float*)d_in[13];
    const float* ln2_g  = (const float*)d_in[14];
    const float* ln2_b  = (const float*)d_in[15];
    const float* ff1_w  = (const float*)d_in[16];
    const float* ff1_b  = (const float*)d_in[17];
    const float* ff2_w  = (const float*)d_in[18];
    const float* ff2_b  = (const float*)d_in[19];
    const float* cls_w1 = (const float*)d_in[20];
    const float* cls_w2 = (const float*)d_in[21];

    char* ws = (char*)d_ws;
    __hip_bfloat16* x_b     = (__hip_bfloat16*)(ws + 0);          //  4,456,448 full rows bf16
    __hip_bfloat16* kv_bf   = (__hip_bfloat16*)(ws + 4456448);    //  8,912,896 K|V all rows
    __hip_bfloat16* qg_bf   = (__hip_bfloat16*)(ws + 13369344);   //    262,144 Q global rows
    __hip_bfloat16* og_bf   = (__hip_bfloat16*)(ws + 13631488);   //    262,144 attn out global
    float*          xg_f32  = (float*)(ws + 13893632);            //    524,288 x global rows f32
    float*          tmpA    = (float*)(ws + 14417920);            //    524,288 O-proj(+res)
    float*          x1g     = (float*)(ws + 14942208);            //    524,288
    __hip_bfloat16* x1g_b   = (__hip_bfloat16*)(ws + 15466496);   //    262,144
    __hip_bfloat16* ffh_b   = (__hip_bfloat16*)(ws + 15728640);   //    524,288
    float*          tmpB    = (float*)(ws + 16252928);            //    524,288 FF2(+res)
    float*          x2g     = (float*)(ws + 16777216);            //    524,288
    __hip_bfloat16* WqT     = (__hip_bfloat16*)(ws + 17301504);   //    524,288
    __hip_bfloat16* WkvT    = (__hip_bfloat16*)(ws + 17825792);   //  1,048,576
    __hip_bfloat16* WoT     = (__hip_bfloat16*)(ws + 18874368);   //    524,288
    __hip_bfloat16* W1T     = (__hip_bfloat16*)(ws + 19398656);   //  1,048,576
    __hip_bfloat16* W2T     = (__hip_bfloat16*)(ws + 20447232);   //  1,048,576
    float*          kvb     = (float*)(ws + 21495808);            //      4,096
    int*            pad_all = (int*)(ws + 21499904);              //     17,408 (+pad)
    float*          pacc    = (float*)(ws + 21520384);            //  4,194,304
    float*          pm      = (float*)(ws + 25714688);            //     65,536
    float*          pl      = (float*)(ws + 25780224);            //     65,536
    float*          clspart = (float*)(ws + 25845760);            //     16,384

    build_x_kernel<<<MROWS_, 128, 0, stream>>>(ids, embed, gtok, x_b, xg_f32, pad_all);
    wt_all_kernel<<<512, 256, 0, stream>>>(q_w, k_w, v_w, o_w, ff1_w, ff2_w,
                                           WqT, WkvT, WoT, W1T, W2T, k_b, v_b, kvb);

    // K,V for all rows (the only full-width GEMM left)
    gemm_bt_kernel<<<dim3(8, 34), 256, 0, stream>>>(x_b, WkvT, kvb, kv_bf, 1024, 512, 2);
    // Q for global rows only (A-row remap from full x_b)
    gemm64_kernel<<<dim3(8, 4), 256, 0, stream>>>(x_b, WqT, q_b, nullptr, qg_bf, 512, 512, 2 | 8);

    attn_global_kernel<<<512, 256, 0, stream>>>(qg_bf, kv_bf, pad_all, pacc, pm, pl);
    attn_combine_kernel<<<512, 256, 0, stream>>>(pacc, pm, pl, og_bf);

    // tail: 256 rows only
    gemm64_kernel<<<dim3(8, 4), 256, 0, stream>>>(og_bf, WoT, o_b, xg_f32, tmpA, 512, 512, 4);
    ln_kernel<<<GR_, 256, 0, stream>>>(tmpA, ln1_g, ln1_b, x1g, x1g_b, 1);
    gemm64_kernel<<<dim3(16, 4), 256, 0, stream>>>(x1g_b, W1T, ff1_b, nullptr, ffh_b, 1024, 512, 1 | 2);
    gemm64_kernel<<<dim3(8, 4), 256, 0, stream>>>(ffh_b, W2T, ff2_b, x1g, tmpB, 512, 1024, 4);
    ln_kernel<<<GR_, 256, 0, stream>>>(tmpB, ln2_g, ln2_b, x2g, nullptr, 0);

    cls_pool_kernel<<<dim3(8, B_), 256, 0, stream>>>(x2g, pad_all, cls_w1, clspart);
    cls_fin_kernel<<<B_, 256, 0, stream>>>(clspart, cls_w2, (float*)d_out);
}

// Round 8
// 120.300 us; speedup vs baseline: 11.8342x; 1.1324x over previous
//
#include <hip/hip_runtime.h>
#include <hip/hip_bf16.h>
#include <cstddef>

#define B_ 2
#define SL_ 2048
#define RATIO_ 16
#define SG_ 128
#define S_ 2176
#define D_ 512
#define H_ 8
#define HD_ 64
#define FF_ 1024
#define NC_ 2
#define NEG_ (-1.0e9f)
#define MINF_ (-1.0e30f)
#define MROWS_ (B_ * S_)   // 4352
#define GR_ (B_ * SG_)     // 256 global rows (the only live rows post-attention)
#define KC_ 8              // split-K chunks for global-query attention

typedef __attribute__((ext_vector_type(8))) short short8;
typedef __attribute__((ext_vector_type(4))) float f32x4;

__device__ __forceinline__ void gll16(const void* g, void* l) {
    __builtin_amdgcn_global_load_lds((const __attribute__((address_space(1))) void*)g,
                                     (__attribute__((address_space(3))) void*)l, 16, 0, 0);
}
__device__ __forceinline__ unsigned short f2bf(float x) {
    __hip_bfloat16 h = __float2bfloat16(x);
    return *reinterpret_cast<unsigned short*>(&h);
}
__device__ __forceinline__ float wave_sum(float v) {
#pragma unroll
    for (int off = 1; off < 64; off <<= 1) v += __shfl_xor(v, off);
    return v;
}
// raw barrier (no compiler-inserted vmcnt(0) drain) + compiler memory fence
#define BARRIER() do { asm volatile("" ::: "memory"); __builtin_amdgcn_s_barrier(); asm volatile("" ::: "memory"); } while (0)

// ---------------------------------------------------------------- build x_b (full bf16) + xg (global f32) + pad
__global__ void build_x_kernel(const int* __restrict__ ids,
                               const float* __restrict__ embed,
                               const float* __restrict__ gtok,
                               __hip_bfloat16* __restrict__ xb,
                               float* __restrict__ xg,
                               int* __restrict__ pad_all) {
    int row = blockIdx.x;
    int b = row / S_, s = row % S_;
    const float* src;
    if (s < SL_) {
        int tok = ids[b * SL_ + s];
        src = embed + (size_t)tok * D_;
        if (threadIdx.x == 0) pad_all[row] = (tok == 0) ? 1 : 0;
    } else {
        src = gtok;
        if (threadIdx.x == 0) {
            int g = s - SL_;
            int allz = 1;
            for (int r = 0; r < RATIO_; ++r)
                allz &= (ids[b * SL_ + g * RATIO_ + r] == 0) ? 1 : 0;
            pad_all[row] = allz;
        }
    }
    float4 v = ((const float4*)src)[threadIdx.x];
    __hip_bfloat16 hb[4] = {__float2bfloat16(v.x), __float2bfloat16(v.y),
                            __float2bfloat16(v.z), __float2bfloat16(v.w)};
    *(uint2*)(xb + (size_t)row * D_ + threadIdx.x * 4) = *(const uint2*)hb;
    if (s >= SL_)
        ((float4*)(xg + (size_t)(b * SG_ + s - SL_) * D_))[threadIdx.x] = v;
}

// ---------------------------------------------------------------- fused weight transpose+convert (+kv bias concat)
__global__ __launch_bounds__(256) void wt_all_kernel(const float* __restrict__ qw,
                                                     const float* __restrict__ kw,
                                                     const float* __restrict__ vw,
                                                     const float* __restrict__ ow,
                                                     const float* __restrict__ f1w,
                                                     const float* __restrict__ f2w,
                                                     __hip_bfloat16* __restrict__ WqT,
                                                     __hip_bfloat16* __restrict__ WkvT,
                                                     __hip_bfloat16* __restrict__ WoT,
                                                     __hip_bfloat16* __restrict__ W1T,
                                                     __hip_bfloat16* __restrict__ W2T,
                                                     const float* __restrict__ k_b,
                                                     const float* __restrict__ v_b,
                                                     float* __restrict__ kvb) {
    __shared__ float tile[64][65];
    int bid = blockIdx.x;
    int tid = threadIdx.x;
    if (bid == 0) {
#pragma unroll
        for (int i = tid; i < 1024; i += 256)
            kvb[i] = (i < 512) ? k_b[i] : v_b[i - 512];
    }
    const float* W; __hip_bfloat16* Wt; int K, N, tx, ty;
    if (bid < 192) {
        int which = bid >> 6, id = bid & 63;
        W = (which == 0) ? qw : (which == 1) ? kw : vw;
        Wt = (which == 0) ? WqT : (which == 1) ? WkvT : (WkvT + (size_t)512 * 512);
        K = 512; N = 512; tx = id & 7; ty = id >> 3;
    } else if (bid < 256) {
        int id = bid - 192; W = ow; Wt = WoT; K = 512; N = 512; tx = id & 7; ty = id >> 3;
    } else if (bid < 384) {
        int id = bid - 256; W = f1w; Wt = W1T; K = 512; N = 1024; tx = id & 15; ty = id >> 4;
    } else {
        int id = bid - 384; W = f2w; Wt = W2T; K = 1024; N = 512; tx = id & 7; ty = id >> 3;
    }
    int n0 = tx * 64, k0 = ty * 64;
    int c = tid & 63, r4 = tid >> 6;
#pragma unroll
    for (int i = 0; i < 16; ++i) {
        int r = i * 4 + r4;
        tile[r][c] = W[(size_t)(k0 + r) * N + n0 + c];
    }
    __syncthreads();
#pragma unroll
    for (int i = 0; i < 16; ++i) {
        int n = i * 4 + r4;
        Wt[(size_t)(n0 + n) * K + k0 + c] = __float2bfloat16(tile[c][n]);
    }
}

// ---------------------------------------------------------------- 128x128 bf16 MFMA GEMM, 2-phase dbuf prefetch
// flags: 1 = relu, 2 = bf16 output
__global__ __launch_bounds__(256) void gemm_bt_kernel(const __hip_bfloat16* __restrict__ A,
                                                      const __hip_bfloat16* __restrict__ Bt,
                                                      const float* __restrict__ bias,
                                                      void* __restrict__ Cout,
                                                      int N, int K, int flags) {
    __shared__ short As[2][128 * 32];
    __shared__ short Bs[2][128 * 32];
    int tid = threadIdx.x;
    int m0 = blockIdx.y * 128, n0 = blockIdx.x * 128;
    int w = tid >> 6, lane = tid & 63;
    int wr = w >> 1, wc = w & 1;

    f32x4 acc[4][4];
#pragma unroll
    for (int m = 0; m < 4; ++m)
#pragma unroll
        for (int n = 0; n < 4; ++n)
            acc[m][n] = (f32x4){0.f, 0.f, 0.f, 0.f};

    int p0 = tid * 16, rs = p0 >> 6, cs = p0 & 63;
    const char* Ab = (const char*)A;
    const char* Bb = (const char*)Bt;

    auto STAGE = [&](int buf, int k0) {
        gll16(Ab + ((size_t)(m0 + rs) * K + k0) * 2 + cs, (char*)As[buf] + p0);
        gll16(Ab + ((size_t)(m0 + rs + 64) * K + k0) * 2 + cs, (char*)As[buf] + p0 + 4096);
        gll16(Bb + ((size_t)(n0 + rs) * K + k0) * 2 + cs, (char*)Bs[buf] + p0);
        gll16(Bb + ((size_t)(n0 + rs + 64) * K + k0) * 2 + cs, (char*)Bs[buf] + p0 + 4096);
    };
    STAGE(0, 0);
    int nk = K >> 5;
    for (int t = 0; t < nk; ++t) {
        int cur = t & 1;
        if (t + 1 < nk) {
            STAGE(cur ^ 1, (t + 1) << 5);
            asm volatile("s_waitcnt vmcnt(4)" ::: "memory");   // cur's 4 loads done; next 4 in flight
        } else {
            asm volatile("s_waitcnt vmcnt(0)" ::: "memory");
        }
        BARRIER();
        short8 af[4], bfr[4];
#pragma unroll
        for (int m = 0; m < 4; ++m)
            af[m] = *(const short8*)&As[cur][(wr * 64 + m * 16 + (lane & 15)) * 32 + (lane >> 4) * 8];
#pragma unroll
        for (int n = 0; n < 4; ++n)
            bfr[n] = *(const short8*)&Bs[cur][(wc * 64 + n * 16 + (lane & 15)) * 32 + (lane >> 4) * 8];
#pragma unroll
        for (int m = 0; m < 4; ++m)
#pragma unroll
            for (int n = 0; n < 4; ++n)
                acc[m][n] = __builtin_amdgcn_mfma_f32_16x16x32_bf16(af[m], bfr[n], acc[m][n], 0, 0, 0);
        BARRIER();   // protect cur from next iteration's prefetch overwrite
    }

    int rbase = m0 + wr * 64 + (lane >> 4) * 4;
    int cbase = n0 + wc * 64 + (lane & 15);
#pragma unroll
    for (int m = 0; m < 4; ++m)
#pragma unroll
        for (int n = 0; n < 4; ++n) {
            int col = cbase + n * 16;
            float bv = bias[col];
#pragma unroll
            for (int j = 0; j < 4; ++j) {
                int row = rbase + m * 16 + j;
                float v = acc[m][n][j] + bv;
                if (flags & 1) v = fmaxf(v, 0.0f);
                if (flags & 2)
                    ((__hip_bfloat16*)Cout)[(size_t)row * N + col] = __float2bfloat16(v);
                else
                    ((float*)Cout)[(size_t)row * N + col] = v;
            }
        }
}

// ---------------------------------------------------------------- 64x64 bf16 MFMA GEMM (small-M tail), dbuf
// flags: 1 = relu, 2 = bf16 output, 4 = add residual Res[row*N+col], 8 = A-row remap (global rows of full x_b)
__global__ __launch_bounds__(256) void gemm64_kernel(const __hip_bfloat16* __restrict__ A,
                                                     const __hip_bfloat16* __restrict__ Bt,
                                                     const float* __restrict__ bias,
                                                     const float* __restrict__ Res,
                                                     void* __restrict__ Cout,
                                                     int N, int K, int flags) {
    __shared__ short As[2][64 * 32];
    __shared__ short Bs[2][64 * 32];
    int tid = threadIdx.x;
    int m0 = blockIdx.y * 64, n0 = blockIdx.x * 64;
    int w = tid >> 6, lane = tid & 63;
    int wr = w >> 1, wc = w & 1;

    f32x4 acc[2][2];
#pragma unroll
    for (int m = 0; m < 2; ++m)
#pragma unroll
        for (int n = 0; n < 2; ++n)
            acc[m][n] = (f32x4){0.f, 0.f, 0.f, 0.f};

    int p0 = tid * 16, rs = p0 >> 6, cs = p0 & 63;
    int rl = m0 + rs;
    size_t arow = (flags & 8) ? (size_t)((rl >> 7) * S_ + SL_ + (rl & 127)) : (size_t)rl;
    const char* Ab = (const char*)A;
    const char* Bb = (const char*)Bt;

    auto STAGE = [&](int buf, int k0) {
        gll16(Ab + (arow * K + k0) * 2 + cs, (char*)As[buf] + p0);
        gll16(Bb + ((size_t)(n0 + rs) * K + k0) * 2 + cs, (char*)Bs[buf] + p0);
    };
    STAGE(0, 0);
    int nk = K >> 5;
    for (int t = 0; t < nk; ++t) {
        int cur = t & 1;
        if (t + 1 < nk) {
            STAGE(cur ^ 1, (t + 1) << 5);
            asm volatile("s_waitcnt vmcnt(2)" ::: "memory");
        } else {
            asm volatile("s_waitcnt vmcnt(0)" ::: "memory");
        }
        BARRIER();
        short8 af[2], bfr[2];
#pragma unroll
        for (int m = 0; m < 2; ++m)
            af[m] = *(const short8*)&As[cur][(wr * 32 + m * 16 + (lane & 15)) * 32 + (lane >> 4) * 8];
#pragma unroll
        for (int n = 0; n < 2; ++n)
            bfr[n] = *(const short8*)&Bs[cur][(wc * 32 + n * 16 + (lane & 15)) * 32 + (lane >> 4) * 8];
#pragma unroll
        for (int m = 0; m < 2; ++m)
#pragma unroll
            for (int n = 0; n < 2; ++n)
                acc[m][n] = __builtin_amdgcn_mfma_f32_16x16x32_bf16(af[m], bfr[n], acc[m][n], 0, 0, 0);
        BARRIER();
    }

    int rbase = m0 + wr * 32 + (lane >> 4) * 4;
    int cbase = n0 + wc * 32 + (lane & 15);
#pragma unroll
    for (int m = 0; m < 2; ++m)
#pragma unroll
        for (int n = 0; n < 2; ++n) {
            int col = cbase + n * 16;
            float bv = bias[col];
#pragma unroll
            for (int j = 0; j < 4; ++j) {
                int row = rbase + m * 16 + j;
                float v = acc[m][n][j] + bv;
                if (flags & 4) v += Res[(size_t)row * N + col];
                if (flags & 1) v = fmaxf(v, 0.0f);
                if (flags & 2)
                    ((__hip_bfloat16*)Cout)[(size_t)row * N + col] = __float2bfloat16(v);
                else
                    ((float*)Cout)[(size_t)row * N + col] = v;
            }
        }
}

// ================================================================ MFMA attention (global queries only), split-K
// LDS layout (bytes): Qs[32][72]s @0 | Ks[64][72]s @4608 | Vt[64][72]s @13824 |
// Pl[2][16][72]s @23040 | padv[64]f @27648 | msh @27968 | lsh @28224. Osh aliases head.
#define ATT_LDS_ 28480

__global__ __launch_bounds__(256, 4) void attn_global_kernel(const __hip_bfloat16* __restrict__ Qg,
                                                             const __hip_bfloat16* __restrict__ KV,
                                                             const int* __restrict__ pad_all,
                                                             float* __restrict__ pacc,
                                                             float* __restrict__ pm,
                                                             float* __restrict__ pl) {
    __shared__ __align__(16) char smem[ATT_LDS_];
    short* Qs = (short*)(smem + 0);
    short* Ks = (short*)(smem + 4608);
    short* Vt = (short*)(smem + 13824);
    short* Pl = (short*)(smem + 23040);
    float* padv = (float*)(smem + 27648);
    float* msh  = (float*)(smem + 27968);
    float* lsh  = (float*)(smem + 28224);
    float* Osh  = (float*)smem;

    const int TS[KC_ + 1] = {0, 4, 8, 12, 17, 21, 25, 29, 34};
    int bid = blockIdx.x;
    int c  = bid & 7;
    int qt = (bid >> 3) & 3;
    int h  = (bid >> 5) & 7;
    int b  = bid >> 8;
    int i0c = qt * 32;
    int tid = threadIdx.x;
    int w = tid >> 6, lane = tid & 63;
    int qg = w >> 1, kh = w & 1;
    int cq = lane & 15, g4 = lane >> 4;
    const int* pad = pad_all + b * S_;
    const short* qgp = (const short*)Qg;
    const short* kv  = (const short*)KV;

    {
        int q = tid >> 3, g = tid & 7;
        short8 v = *(const short8*)(qgp + (size_t)(b * SG_ + i0c + q) * D_ + h * HD_ + g * 8);
        *(short8*)(Qs + q * 72 + g * 8) = v;
    }

    float mreg = MINF_, lreg = 0.0f;
    f32x4 ot0 = {0,0,0,0}, ot1 = {0,0,0,0}, ot2 = {0,0,0,0}, ot3 = {0,0,0,0};

    for (int t = TS[c]; t < TS[c + 1]; ++t) {
        int j0 = t * 64;
        __syncthreads();
        {
            int key = tid >> 2, g2 = tid & 3;
            size_t base = (size_t)(b * S_ + j0 + key) * 1024 + h * HD_;
#pragma unroll
            for (int gg = 0; gg < 2; ++gg) {
                int g = g2 + gg * 4;
                short8 kvv = *(const short8*)(kv + base + g * 8);
                *(short8*)(Ks + key * 72 + g * 8) = kvv;
                short8 vv = *(const short8*)(kv + base + 512 + g * 8);
#pragma unroll
                for (int i = 0; i < 8; ++i)
                    Vt[(g * 8 + i) * 72 + key] = vv[i];
            }
            if (tid < 64) padv[tid] = pad[j0 + tid] ? NEG_ : 0.0f;
        }
        __syncthreads();

        short8 qf0 = *(const short8*)(Qs + (qg * 16 + cq) * 72 + 0 + g4 * 8);
        short8 qf1 = *(const short8*)(Qs + (qg * 16 + cq) * 72 + 32 + g4 * 8);
        f32x4 st0 = {0,0,0,0}, st1 = {0,0,0,0};
        {
            short8 kf;
            kf = *(const short8*)(Ks + (kh * 32 + cq) * 72 + 0 + g4 * 8);
            st0 = __builtin_amdgcn_mfma_f32_16x16x32_bf16(kf, qf0, st0, 0, 0, 0);
            kf = *(const short8*)(Ks + (kh * 32 + cq) * 72 + 32 + g4 * 8);
            st0 = __builtin_amdgcn_mfma_f32_16x16x32_bf16(kf, qf1, st0, 0, 0, 0);
            kf = *(const short8*)(Ks + (kh * 32 + 16 + cq) * 72 + 0 + g4 * 8);
            st1 = __builtin_amdgcn_mfma_f32_16x16x32_bf16(kf, qf0, st1, 0, 0, 0);
            kf = *(const short8*)(Ks + (kh * 32 + 16 + cq) * 72 + 32 + g4 * 8);
            st1 = __builtin_amdgcn_mfma_f32_16x16x32_bf16(kf, qf1, st1, 0, 0, 0);
        }
        float sarr[8];
#pragma unroll
        for (int mt = 0; mt < 2; ++mt)
#pragma unroll
            for (int j = 0; j < 4; ++j) {
                int k = kh * 32 + mt * 16 + g4 * 4 + j;
                sarr[mt * 4 + j] = (mt ? st1[j] : st0[j]) * 0.125f + padv[k];
            }
        float cmax = sarr[0];
#pragma unroll
        for (int i = 1; i < 8; ++i) cmax = fmaxf(cmax, sarr[i]);
        cmax = fmaxf(cmax, __shfl_xor(cmax, 16));
        cmax = fmaxf(cmax, __shfl_xor(cmax, 32));
        float mnew = fmaxf(mreg, cmax);
        float fac = __expf(mreg - mnew);
        float parr[8], psum = 0.0f;
#pragma unroll
        for (int i = 0; i < 8; ++i) { parr[i] = __expf(sarr[i] - mnew); psum += parr[i]; }
        psum += __shfl_xor(psum, 16);
        psum += __shfl_xor(psum, 32);
        lreg = lreg * fac + psum;
        mreg = mnew;
        ot0 *= fac; ot1 *= fac; ot2 *= fac; ot3 *= fac;
#pragma unroll
        for (int mt = 0; mt < 2; ++mt) {
            unsigned int lo = (unsigned int)f2bf(parr[mt * 4 + 0]) | ((unsigned int)f2bf(parr[mt * 4 + 1]) << 16);
            unsigned int hi = (unsigned int)f2bf(parr[mt * 4 + 2]) | ((unsigned int)f2bf(parr[mt * 4 + 3]) << 16);
            unsigned int* dst = (unsigned int*)(Pl + (qg * 16 + cq) * 72 + kh * 32 + mt * 16 + g4 * 4);
            dst[0] = lo; dst[1] = hi;
        }
        short8 pf = *(const short8*)(Pl + (qg * 16 + cq) * 72 + kh * 32 + g4 * 8);
        {
            short8 vf;
            vf = *(const short8*)(Vt + (0 * 16 + cq) * 72 + kh * 32 + g4 * 8);
            ot0 = __builtin_amdgcn_mfma_f32_16x16x32_bf16(vf, pf, ot0, 0, 0, 0);
            vf = *(const short8*)(Vt + (1 * 16 + cq) * 72 + kh * 32 + g4 * 8);
            ot1 = __builtin_amdgcn_mfma_f32_16x16x32_bf16(vf, pf, ot1, 0, 0, 0);
            vf = *(const short8*)(Vt + (2 * 16 + cq) * 72 + kh * 32 + g4 * 8);
            ot2 = __builtin_amdgcn_mfma_f32_16x16x32_bf16(vf, pf, ot2, 0, 0, 0);
            vf = *(const short8*)(Vt + (3 * 16 + cq) * 72 + kh * 32 + g4 * 8);
            ot3 = __builtin_amdgcn_mfma_f32_16x16x32_bf16(vf, pf, ot3, 0, 0, 0);
        }
    }

    __syncthreads();
    if (g4 == 0) {
        msh[(qg * 2 + kh) * 16 + cq] = mreg;
        lsh[(qg * 2 + kh) * 16 + cq] = lreg;
    }
    __syncthreads();
    {
        float m0 = msh[(qg * 2 + 0) * 16 + cq], m1 = msh[(qg * 2 + 1) * 16 + cq];
        float Mm = fmaxf(m0, m1);
        float e_self = __expf(mreg - Mm);
        f32x4 o;
        o = ot0 * e_self; *(f32x4*)(Osh + ((qg * 2 + kh) * 16 + cq) * 68 + 0  + g4 * 4) = o;
        o = ot1 * e_self; *(f32x4*)(Osh + ((qg * 2 + kh) * 16 + cq) * 68 + 16 + g4 * 4) = o;
        o = ot2 * e_self; *(f32x4*)(Osh + ((qg * 2 + kh) * 16 + cq) * 68 + 32 + g4 * 4) = o;
        o = ot3 * e_self; *(f32x4*)(Osh + ((qg * 2 + kh) * 16 + cq) * 68 + 48 + g4 * 4) = o;
    }
    __syncthreads();
    {
        int q_all = tid >> 3, d0 = (tid & 7) * 8;
        int qg2 = q_all >> 4, ql = q_all & 15;
        float mm0 = msh[(qg2 * 2 + 0) * 16 + ql], mm1 = msh[(qg2 * 2 + 1) * 16 + ql];
        float MM = fmaxf(mm0, mm1);
        float lt = lsh[(qg2 * 2 + 0) * 16 + ql] * __expf(mm0 - MM) +
                   lsh[(qg2 * 2 + 1) * 16 + ql] * __expf(mm1 - MM);
        int prow = ((c * B_ + b) * H_ + h) * SG_ + qt * 32 + q_all;
#pragma unroll
        for (int i = 0; i < 8; ++i) {
            float a = Osh[((qg2 * 2 + 0) * 16 + ql) * 68 + d0 + i] +
                      Osh[((qg2 * 2 + 1) * 16 + ql) * 68 + d0 + i];
            pacc[(size_t)prow * HD_ + d0 + i] = a;
        }
        if ((tid & 7) == 0) { pm[prow] = MM; pl[prow] = lt; }
    }
}

__global__ __launch_bounds__(256) void attn_combine_kernel(const float* __restrict__ pacc,
                                                           const float* __restrict__ pm,
                                                           const float* __restrict__ pl,
                                                           __hip_bfloat16* __restrict__ Og) {
    int wave = (int)((blockIdx.x * (size_t)blockDim.x + threadIdx.x) >> 6);
    int lane = threadIdx.x & 63;
    int gq = wave & (SG_ - 1);
    int h  = (wave >> 7) & 7;
    int b  = wave >> 10;

    float M = MINF_;
#pragma unroll
    for (int c = 0; c < KC_; ++c) {
        int pidx = ((c * B_ + b) * H_ + h) * SG_ + gq;
        M = fmaxf(M, pm[pidx]);
    }
    float L = 0.0f, Ov = 0.0f;
#pragma unroll
    for (int c = 0; c < KC_; ++c) {
        int pidx = ((c * B_ + b) * H_ + h) * SG_ + gq;
        float e = __expf(pm[pidx] - M);
        L += pl[pidx] * e;
        Ov += pacc[(size_t)pidx * HD_ + lane] * e;
    }
    Og[(size_t)(b * SG_ + gq) * D_ + h * HD_ + lane] = __float2bfloat16(Ov / L);
}

// ---------------------------------------------------------------- LN (input already has residual added)
__global__ __launch_bounds__(256) void ln_kernel(const float* __restrict__ A,
                                                 const float* __restrict__ g,
                                                 const float* __restrict__ be,
                                                 float* __restrict__ out,
                                                 __hip_bfloat16* __restrict__ outb,
                                                 int wb) {
    int row = blockIdx.x;
    int tid = threadIdx.x;
    size_t base = (size_t)row * D_;
    float x0 = A[base + tid];
    float x1 = A[base + tid + 256];
    float s1 = x0 + x1;
    float s2 = x0 * x0 + x1 * x1;
    for (int off = 1; off < 64; off <<= 1) {
        s1 += __shfl_xor(s1, off);
        s2 += __shfl_xor(s2, off);
    }
    __shared__ float ws1[4], ws2[4];
    int wid = tid >> 6;
    if ((tid & 63) == 0) { ws1[wid] = s1; ws2[wid] = s2; }
    __syncthreads();
    s1 = ws1[0] + ws1[1] + ws1[2] + ws1[3];
    s2 = ws2[0] + ws2[1] + ws2[2] + ws2[3];
    float mean = s1 * (1.0f / D_);
    float var  = s2 * (1.0f / D_) - mean * mean;
    float rstd = rsqrtf(var + 1e-5f);
    float o0 = (x0 - mean) * rstd * g[tid]       + be[tid];
    float o1 = (x1 - mean) * rstd * g[tid + 256] + be[tid + 256];
    out[base + tid]       = o0;
    out[base + tid + 256] = o1;
    if (wb) {
        outb[base + tid]       = __float2bfloat16(o0);
        outb[base + tid + 256] = __float2bfloat16(o1);
    }
}

// ---------------------------------------------------------------- fused pool + 2-layer classifier
// 2 blocks (one per batch), 256 threads. Branch-free pool (pad weights staged in
// LDS first -> loads pipeline; r7's pad-branch serialized 128 iters = 42us).
__global__ __launch_bounds__(256) void cls_kernel(const float* __restrict__ x2g,
                                                  const int* __restrict__ pad_all,
                                                  const float* __restrict__ w1,
                                                  const float* __restrict__ w2,
                                                  float* __restrict__ out) {
    int b = blockIdx.x, tid = threadIdx.x;
    __shared__ float wrow[SG_];
    __shared__ float zg[D_];
    __shared__ float r0[4], r1[4];
    if (tid < SG_) wrow[tid] = pad_all[b * S_ + SL_ + tid] ? 0.0f : 1.0f;
    __syncthreads();
    float cnt = 0.0f;
#pragma unroll 16
    for (int g = 0; g < SG_; ++g) cnt += wrow[g];   // LDS broadcast, cheap
    float inv = 1.0f / cnt;

    const float* xb = x2g + (size_t)b * SG_ * D_;
    float a0 = 0.0f, a1 = 0.0f;
#pragma unroll 8
    for (int g = 0; g < SG_; ++g) {
        float wv = wrow[g];
        a0 = fmaf(wv, xb[(size_t)g * D_ + tid], a0);
        a1 = fmaf(wv, xb[(size_t)g * D_ + tid + 256], a1);
    }
    zg[tid]       = a0 * inv;
    zg[tid + 256] = a1 * inv;
    __syncthreads();

    // hidden[tid] = relu(zg . w1[:,tid]); zg reads broadcast, w1 coalesced
    float h = 0.0f;
#pragma unroll 8
    for (int d = 0; d < D_; ++d)
        h = fmaf(zg[d], w1[(size_t)d * 256 + tid], h);
    h = fmaxf(h, 0.0f);

    float o0 = h * w2[(size_t)tid * NC_ + 0];
    float o1 = h * w2[(size_t)tid * NC_ + 1];
    o0 = wave_sum(o0);
    o1 = wave_sum(o1);
    if ((tid & 63) == 0) { r0[tid >> 6] = o0; r1[tid >> 6] = o1; }
    __syncthreads();
    if (tid == 0) {
        out[b * NC_ + 0] = r0[0] + r0[1] + r0[2] + r0[3];
        out[b * NC_ + 1] = r1[0] + r1[1] + r1[2] + r1[3];
    }
}

// ---------------------------------------------------------------- launch
extern "C" void kernel_launch(void* const* d_in, const int* in_sizes, int n_in,
                              void* d_out, int out_size, void* d_ws, size_t ws_size,
                              hipStream_t stream) {
    const int*   ids    = (const int*)d_in[0];
    const float* embed  = (const float*)d_in[1];
    const float* gtok   = (const float*)d_in[2];
    const float* q_w    = (const float*)d_in[4];
    const float* q_b    = (const float*)d_in[5];
    const float* k_w    = (const float*)d_in[6];
    const float* k_b    = (const float*)d_in[7];
    const float* v_w    = (const float*)d_in[8];
    const float* v_b    = (const float*)d_in[9];
    const float* o_w    = (const float*)d_in[10];
    const float* o_b    = (const float*)d_in[11];
    const float* ln1_g  = (const float*)d_in[12];
    const float* ln1_b  = (const float*)d_in[13];
    const float* ln2_g  = (const float*)d_in[14];
    const float* ln2_b  = (const float*)d_in[15];
    const float* ff1_w  = (const float*)d_in[16];
    const float* ff1_b  = (const float*)d_in[17];
    const float* ff2_w  = (const float*)d_in[18];
    const float* ff2_b  = (const float*)d_in[19];
    const float* cls_w1 = (const float*)d_in[20];
    const float* cls_w2 = (const float*)d_in[21];

    char* ws = (char*)d_ws;
    __hip_bfloat16* x_b     = (__hip_bfloat16*)(ws + 0);          //  4,456,448 full rows bf16
    __hip_bfloat16* kv_bf   = (__hip_bfloat16*)(ws + 4456448);    //  8,912,896 K|V all rows
    __hip_bfloat16* qg_bf   = (__hip_bfloat16*)(ws + 13369344);   //    262,144 Q global rows
    __hip_bfloat16* og_bf   = (__hip_bfloat16*)(ws + 13631488);   //    262,144 attn out global
    float*          xg_f32  = (float*)(ws + 13893632);            //    524,288 x global rows f32
    float*          tmpA    = (float*)(ws + 14417920);            //    524,288 O-proj(+res)
    float*          x1g     = (float*)(ws + 14942208);            //    524,288
    __hip_bfloat16* x1g_b   = (__hip_bfloat16*)(ws + 15466496);   //    262,144
    __hip_bfloat16* ffh_b   = (__hip_bfloat16*)(ws + 15728640);   //    524,288
    float*          tmpB    = (float*)(ws + 16252928);            //    524,288 FF2(+res)
    float*          x2g     = (float*)(ws + 16777216);            //    524,288
    __hip_bfloat16* WqT     = (__hip_bfloat16*)(ws + 17301504);   //    524,288
    __hip_bfloat16* WkvT    = (__hip_bfloat16*)(ws + 17825792);   //  1,048,576
    __hip_bfloat16* WoT     = (__hip_bfloat16*)(ws + 18874368);   //    524,288
    __hip_bfloat16* W1T     = (__hip_bfloat16*)(ws + 19398656);   //  1,048,576
    __hip_bfloat16* W2T     = (__hip_bfloat16*)(ws + 20447232);   //  1,048,576
    float*          kvb     = (float*)(ws + 21495808);            //      4,096
    int*            pad_all = (int*)(ws + 21499904);              //     17,408 (+pad)
    float*          pacc    = (float*)(ws + 21520384);            //  4,194,304
    float*          pm      = (float*)(ws + 25714688);            //     65,536
    float*          pl      = (float*)(ws + 25780224);            //     65,536

    build_x_kernel<<<MROWS_, 128, 0, stream>>>(ids, embed, gtok, x_b, xg_f32, pad_all);
    wt_all_kernel<<<512, 256, 0, stream>>>(q_w, k_w, v_w, o_w, ff1_w, ff2_w,
                                           WqT, WkvT, WoT, W1T, W2T, k_b, v_b, kvb);

    // K,V for all rows (the only full-width GEMM left)
    gemm_bt_kernel<<<dim3(8, 34), 256, 0, stream>>>(x_b, WkvT, kvb, kv_bf, 1024, 512, 2);
    // Q for global rows only (A-row remap from full x_b)
    gemm64_kernel<<<dim3(8, 4), 256, 0, stream>>>(x_b, WqT, q_b, nullptr, qg_bf, 512, 512, 2 | 8);

    attn_global_kernel<<<512, 256, 0, stream>>>(qg_bf, kv_bf, pad_all, pacc, pm, pl);
    attn_combine_kernel<<<512, 256, 0, stream>>>(pacc, pm, pl, og_bf);

    // tail: 256 rows only
    gemm64_kernel<<<dim3(8, 4), 256, 0, stream>>>(og_bf, WoT, o_b, xg_f32, tmpA, 512, 512, 4);
    ln_kernel<<<GR_, 256, 0, stream>>>(tmpA, ln1_g, ln1_b, x1g, x1g_b, 1);
    gemm64_kernel<<<dim3(16, 4), 256, 0, stream>>>(x1g_b, W1T, ff1_b, nullptr, ffh_b, 1024, 512, 1 | 2);
    gemm64_kernel<<<dim3(8, 4), 256, 0, stream>>>(ffh_b, W2T, ff2_b, x1g, tmpB, 512, 1024, 4);
    ln_kernel<<<GR_, 256, 0, stream>>>(tmpB, ln2_g, ln2_b, x2g, nullptr, 0);

    cls_kernel<<<B_, 256, 0, stream>>>(x2g, pad_all, cls_w1, cls_w2, (float*)d_out);
}

// Round 9
// 102.121 us; speedup vs baseline: 13.9408x; 1.1780x over previous
//
#include <hip/hip_runtime.h>
#include <hip/hip_bf16.h>
#include <cstddef>

#define B_ 2
#define SL_ 2048
#define RATIO_ 16
#define SG_ 128
#define S_ 2176
#define D_ 512
#define H_ 8
#define HD_ 64
#define FF_ 1024
#define NC_ 2
#define NEG_ (-1.0e9f)
#define MINF_ (-1.0e30f)
#define MROWS_ (B_ * S_)   // 4352
#define GR_ (B_ * SG_)     // 256 global rows (the only live rows post-attention)
#define KC_ 8              // split-K chunks for global-query attention

typedef __attribute__((ext_vector_type(8))) short short8;
typedef __attribute__((ext_vector_type(4))) float f32x4;

__device__ __forceinline__ void gll16(const void* g, void* l) {
    __builtin_amdgcn_global_load_lds((const __attribute__((address_space(1))) void*)g,
                                     (__attribute__((address_space(3))) void*)l, 16, 0, 0);
}
__device__ __forceinline__ unsigned short f2bf(float x) {
    __hip_bfloat16 h = __float2bfloat16(x);
    return *reinterpret_cast<unsigned short*>(&h);
}
__device__ __forceinline__ float wave_sum(float v) {
#pragma unroll
    for (int off = 1; off < 64; off <<= 1) v += __shfl_xor(v, off);
    return v;
}
// raw barrier (no compiler-inserted vmcnt(0) drain) + compiler memory fence
#define BARRIER() do { asm volatile("" ::: "memory"); __builtin_amdgcn_s_barrier(); asm volatile("" ::: "memory"); } while (0)

// ---------------------------------------------------------------- build x_b (full bf16) + xg (global f32) + pad
__global__ void build_x_kernel(const int* __restrict__ ids,
                               const float* __restrict__ embed,
                               const float* __restrict__ gtok,
                               __hip_bfloat16* __restrict__ xb,
                               float* __restrict__ xg,
                               int* __restrict__ pad_all) {
    int row = blockIdx.x;
    int b = row / S_, s = row % S_;
    const float* src;
    if (s < SL_) {
        int tok = ids[b * SL_ + s];
        src = embed + (size_t)tok * D_;
        if (threadIdx.x == 0) pad_all[row] = (tok == 0) ? 1 : 0;
    } else {
        src = gtok;
        if (threadIdx.x == 0) {
            int g = s - SL_;
            int allz = 1;
            for (int r = 0; r < RATIO_; ++r)
                allz &= (ids[b * SL_ + g * RATIO_ + r] == 0) ? 1 : 0;
            pad_all[row] = allz;
        }
    }
    float4 v = ((const float4*)src)[threadIdx.x];
    __hip_bfloat16 hb[4] = {__float2bfloat16(v.x), __float2bfloat16(v.y),
                            __float2bfloat16(v.z), __float2bfloat16(v.w)};
    *(uint2*)(xb + (size_t)row * D_ + threadIdx.x * 4) = *(const uint2*)hb;
    if (s >= SL_)
        ((float4*)(xg + (size_t)(b * SG_ + s - SL_) * D_))[threadIdx.x] = v;
}

// ---------------------------------------------------------------- fused weight transpose+convert (+kv bias concat)
__global__ __launch_bounds__(256) void wt_all_kernel(const float* __restrict__ qw,
                                                     const float* __restrict__ kw,
                                                     const float* __restrict__ vw,
                                                     const float* __restrict__ ow,
                                                     const float* __restrict__ f1w,
                                                     const float* __restrict__ f2w,
                                                     __hip_bfloat16* __restrict__ WqT,
                                                     __hip_bfloat16* __restrict__ WkvT,
                                                     __hip_bfloat16* __restrict__ WoT,
                                                     __hip_bfloat16* __restrict__ W1T,
                                                     __hip_bfloat16* __restrict__ W2T,
                                                     const float* __restrict__ k_b,
                                                     const float* __restrict__ v_b,
                                                     float* __restrict__ kvb) {
    __shared__ float tile[64][65];
    int bid = blockIdx.x;
    int tid = threadIdx.x;
    if (bid == 0) {
#pragma unroll
        for (int i = tid; i < 1024; i += 256)
            kvb[i] = (i < 512) ? k_b[i] : v_b[i - 512];
    }
    const float* W; __hip_bfloat16* Wt; int K, N, tx, ty;
    if (bid < 192) {
        int which = bid >> 6, id = bid & 63;
        W = (which == 0) ? qw : (which == 1) ? kw : vw;
        Wt = (which == 0) ? WqT : (which == 1) ? WkvT : (WkvT + (size_t)512 * 512);
        K = 512; N = 512; tx = id & 7; ty = id >> 3;
    } else if (bid < 256) {
        int id = bid - 192; W = ow; Wt = WoT; K = 512; N = 512; tx = id & 7; ty = id >> 3;
    } else if (bid < 384) {
        int id = bid - 256; W = f1w; Wt = W1T; K = 512; N = 1024; tx = id & 15; ty = id >> 4;
    } else {
        int id = bid - 384; W = f2w; Wt = W2T; K = 1024; N = 512; tx = id & 7; ty = id >> 3;
    }
    int n0 = tx * 64, k0 = ty * 64;
    int c = tid & 63, r4 = tid >> 6;
#pragma unroll
    for (int i = 0; i < 16; ++i) {
        int r = i * 4 + r4;
        tile[r][c] = W[(size_t)(k0 + r) * N + n0 + c];
    }
    __syncthreads();
#pragma unroll
    for (int i = 0; i < 16; ++i) {
        int n = i * 4 + r4;
        Wt[(size_t)(n0 + n) * K + k0 + c] = __float2bfloat16(tile[c][n]);
    }
}

// ---------------------------------------------------------------- 128x128 bf16 MFMA GEMM, 2-phase dbuf prefetch
// flags: 1 = relu, 2 = bf16 output
__global__ __launch_bounds__(256) void gemm_bt_kernel(const __hip_bfloat16* __restrict__ A,
                                                      const __hip_bfloat16* __restrict__ Bt,
                                                      const float* __restrict__ bias,
                                                      void* __restrict__ Cout,
                                                      int N, int K, int flags) {
    __shared__ short As[2][128 * 32];
    __shared__ short Bs[2][128 * 32];
    int tid = threadIdx.x;
    int m0 = blockIdx.y * 128, n0 = blockIdx.x * 128;
    int w = tid >> 6, lane = tid & 63;
    int wr = w >> 1, wc = w & 1;

    f32x4 acc[4][4];
#pragma unroll
    for (int m = 0; m < 4; ++m)
#pragma unroll
        for (int n = 0; n < 4; ++n)
            acc[m][n] = (f32x4){0.f, 0.f, 0.f, 0.f};

    int p0 = tid * 16, rs = p0 >> 6, cs = p0 & 63;
    const char* Ab = (const char*)A;
    const char* Bb = (const char*)Bt;

    auto STAGE = [&](int buf, int k0) {
        gll16(Ab + ((size_t)(m0 + rs) * K + k0) * 2 + cs, (char*)As[buf] + p0);
        gll16(Ab + ((size_t)(m0 + rs + 64) * K + k0) * 2 + cs, (char*)As[buf] + p0 + 4096);
        gll16(Bb + ((size_t)(n0 + rs) * K + k0) * 2 + cs, (char*)Bs[buf] + p0);
        gll16(Bb + ((size_t)(n0 + rs + 64) * K + k0) * 2 + cs, (char*)Bs[buf] + p0 + 4096);
    };
    STAGE(0, 0);
    int nk = K >> 5;
    for (int t = 0; t < nk; ++t) {
        int cur = t & 1;
        if (t + 1 < nk) {
            STAGE(cur ^ 1, (t + 1) << 5);
            asm volatile("s_waitcnt vmcnt(4)" ::: "memory");   // cur's 4 loads done; next 4 in flight
        } else {
            asm volatile("s_waitcnt vmcnt(0)" ::: "memory");
        }
        BARRIER();
        short8 af[4], bfr[4];
#pragma unroll
        for (int m = 0; m < 4; ++m)
            af[m] = *(const short8*)&As[cur][(wr * 64 + m * 16 + (lane & 15)) * 32 + (lane >> 4) * 8];
#pragma unroll
        for (int n = 0; n < 4; ++n)
            bfr[n] = *(const short8*)&Bs[cur][(wc * 64 + n * 16 + (lane & 15)) * 32 + (lane >> 4) * 8];
#pragma unroll
        for (int m = 0; m < 4; ++m)
#pragma unroll
            for (int n = 0; n < 4; ++n)
                acc[m][n] = __builtin_amdgcn_mfma_f32_16x16x32_bf16(af[m], bfr[n], acc[m][n], 0, 0, 0);
        BARRIER();   // protect cur from next iteration's prefetch overwrite
    }

    int rbase = m0 + wr * 64 + (lane >> 4) * 4;
    int cbase = n0 + wc * 64 + (lane & 15);
#pragma unroll
    for (int m = 0; m < 4; ++m)
#pragma unroll
        for (int n = 0; n < 4; ++n) {
            int col = cbase + n * 16;
            float bv = bias[col];
#pragma unroll
            for (int j = 0; j < 4; ++j) {
                int row = rbase + m * 16 + j;
                float v = acc[m][n][j] + bv;
                if (flags & 1) v = fmaxf(v, 0.0f);
                if (flags & 2)
                    ((__hip_bfloat16*)Cout)[(size_t)row * N + col] = __float2bfloat16(v);
                else
                    ((float*)Cout)[(size_t)row * N + col] = v;
            }
        }
}

// ---------------------------------------------------------------- 64x64 bf16 MFMA GEMM (small-M tail), dbuf
// flags: 1 = relu, 2 = bf16 output, 4 = add residual Res[row*N+col], 8 = A-row remap (global rows of full x_b)
__global__ __launch_bounds__(256) void gemm64_kernel(const __hip_bfloat16* __restrict__ A,
                                                     const __hip_bfloat16* __restrict__ Bt,
                                                     const float* __restrict__ bias,
                                                     const float* __restrict__ Res,
                                                     void* __restrict__ Cout,
                                                     int N, int K, int flags) {
    __shared__ short As[2][64 * 32];
    __shared__ short Bs[2][64 * 32];
    int tid = threadIdx.x;
    int m0 = blockIdx.y * 64, n0 = blockIdx.x * 64;
    int w = tid >> 6, lane = tid & 63;
    int wr = w >> 1, wc = w & 1;

    f32x4 acc[2][2];
#pragma unroll
    for (int m = 0; m < 2; ++m)
#pragma unroll
        for (int n = 0; n < 2; ++n)
            acc[m][n] = (f32x4){0.f, 0.f, 0.f, 0.f};

    int p0 = tid * 16, rs = p0 >> 6, cs = p0 & 63;
    int rl = m0 + rs;
    size_t arow = (flags & 8) ? (size_t)((rl >> 7) * S_ + SL_ + (rl & 127)) : (size_t)rl;
    const char* Ab = (const char*)A;
    const char* Bb = (const char*)Bt;

    auto STAGE = [&](int buf, int k0) {
        gll16(Ab + (arow * K + k0) * 2 + cs, (char*)As[buf] + p0);
        gll16(Bb + ((size_t)(n0 + rs) * K + k0) * 2 + cs, (char*)Bs[buf] + p0);
    };
    STAGE(0, 0);
    int nk = K >> 5;
    for (int t = 0; t < nk; ++t) {
        int cur = t & 1;
        if (t + 1 < nk) {
            STAGE(cur ^ 1, (t + 1) << 5);
            asm volatile("s_waitcnt vmcnt(2)" ::: "memory");
        } else {
            asm volatile("s_waitcnt vmcnt(0)" ::: "memory");
        }
        BARRIER();
        short8 af[2], bfr[2];
#pragma unroll
        for (int m = 0; m < 2; ++m)
            af[m] = *(const short8*)&As[cur][(wr * 32 + m * 16 + (lane & 15)) * 32 + (lane >> 4) * 8];
#pragma unroll
        for (int n = 0; n < 2; ++n)
            bfr[n] = *(const short8*)&Bs[cur][(wc * 32 + n * 16 + (lane & 15)) * 32 + (lane >> 4) * 8];
#pragma unroll
        for (int m = 0; m < 2; ++m)
#pragma unroll
            for (int n = 0; n < 2; ++n)
                acc[m][n] = __builtin_amdgcn_mfma_f32_16x16x32_bf16(af[m], bfr[n], acc[m][n], 0, 0, 0);
        BARRIER();
    }

    int rbase = m0 + wr * 32 + (lane >> 4) * 4;
    int cbase = n0 + wc * 32 + (lane & 15);
#pragma unroll
    for (int m = 0; m < 2; ++m)
#pragma unroll
        for (int n = 0; n < 2; ++n) {
            int col = cbase + n * 16;
            float bv = bias[col];
#pragma unroll
            for (int j = 0; j < 4; ++j) {
                int row = rbase + m * 16 + j;
                float v = acc[m][n][j] + bv;
                if (flags & 4) v += Res[(size_t)row * N + col];
                if (flags & 1) v = fmaxf(v, 0.0f);
                if (flags & 2)
                    ((__hip_bfloat16*)Cout)[(size_t)row * N + col] = __float2bfloat16(v);
                else
                    ((float*)Cout)[(size_t)row * N + col] = v;
            }
        }
}

// ================================================================ MFMA attention (global queries only), split-K
// LDS layout (bytes): Qs[32][72]s @0 | Ks[64][72]s @4608 | Vt[64][72]s @13824 |
// Pl[2][16][72]s @23040 | padv[64]f @27648 | msh @27968 | lsh @28224. Osh aliases head.
#define ATT_LDS_ 28480

__global__ __launch_bounds__(256, 4) void attn_global_kernel(const __hip_bfloat16* __restrict__ Qg,
                                                             const __hip_bfloat16* __restrict__ KV,
                                                             const int* __restrict__ pad_all,
                                                             float* __restrict__ pacc,
                                                             float* __restrict__ pm,
                                                             float* __restrict__ pl) {
    __shared__ __align__(16) char smem[ATT_LDS_];
    short* Qs = (short*)(smem + 0);
    short* Ks = (short*)(smem + 4608);
    short* Vt = (short*)(smem + 13824);
    short* Pl = (short*)(smem + 23040);
    float* padv = (float*)(smem + 27648);
    float* msh  = (float*)(smem + 27968);
    float* lsh  = (float*)(smem + 28224);
    float* Osh  = (float*)smem;

    const int TS[KC_ + 1] = {0, 4, 8, 12, 17, 21, 25, 29, 34};
    int bid = blockIdx.x;
    int c  = bid & 7;
    int qt = (bid >> 3) & 3;
    int h  = (bid >> 5) & 7;
    int b  = bid >> 8;
    int i0c = qt * 32;
    int tid = threadIdx.x;
    int w = tid >> 6, lane = tid & 63;
    int qg = w >> 1, kh = w & 1;
    int cq = lane & 15, g4 = lane >> 4;
    const int* pad = pad_all + b * S_;
    const short* qgp = (const short*)Qg;
    const short* kv  = (const short*)KV;

    {
        int q = tid >> 3, g = tid & 7;
        short8 v = *(const short8*)(qgp + (size_t)(b * SG_ + i0c + q) * D_ + h * HD_ + g * 8);
        *(short8*)(Qs + q * 72 + g * 8) = v;
    }

    float mreg = MINF_, lreg = 0.0f;
    f32x4 ot0 = {0,0,0,0}, ot1 = {0,0,0,0}, ot2 = {0,0,0,0}, ot3 = {0,0,0,0};

    for (int t = TS[c]; t < TS[c + 1]; ++t) {
        int j0 = t * 64;
        __syncthreads();
        {
            int key = tid >> 2, g2 = tid & 3;
            size_t base = (size_t)(b * S_ + j0 + key) * 1024 + h * HD_;
#pragma unroll
            for (int gg = 0; gg < 2; ++gg) {
                int g = g2 + gg * 4;
                short8 kvv = *(const short8*)(kv + base + g * 8);
                *(short8*)(Ks + key * 72 + g * 8) = kvv;
                short8 vv = *(const short8*)(kv + base + 512 + g * 8);
#pragma unroll
                for (int i = 0; i < 8; ++i)
                    Vt[(g * 8 + i) * 72 + key] = vv[i];
            }
            if (tid < 64) padv[tid] = pad[j0 + tid] ? NEG_ : 0.0f;
        }
        __syncthreads();

        short8 qf0 = *(const short8*)(Qs + (qg * 16 + cq) * 72 + 0 + g4 * 8);
        short8 qf1 = *(const short8*)(Qs + (qg * 16 + cq) * 72 + 32 + g4 * 8);
        f32x4 st0 = {0,0,0,0}, st1 = {0,0,0,0};
        {
            short8 kf;
            kf = *(const short8*)(Ks + (kh * 32 + cq) * 72 + 0 + g4 * 8);
            st0 = __builtin_amdgcn_mfma_f32_16x16x32_bf16(kf, qf0, st0, 0, 0, 0);
            kf = *(const short8*)(Ks + (kh * 32 + cq) * 72 + 32 + g4 * 8);
            st0 = __builtin_amdgcn_mfma_f32_16x16x32_bf16(kf, qf1, st0, 0, 0, 0);
            kf = *(const short8*)(Ks + (kh * 32 + 16 + cq) * 72 + 0 + g4 * 8);
            st1 = __builtin_amdgcn_mfma_f32_16x16x32_bf16(kf, qf0, st1, 0, 0, 0);
            kf = *(const short8*)(Ks + (kh * 32 + 16 + cq) * 72 + 32 + g4 * 8);
            st1 = __builtin_amdgcn_mfma_f32_16x16x32_bf16(kf, qf1, st1, 0, 0, 0);
        }
        float sarr[8];
#pragma unroll
        for (int mt = 0; mt < 2; ++mt)
#pragma unroll
            for (int j = 0; j < 4; ++j) {
                int k = kh * 32 + mt * 16 + g4 * 4 + j;
                sarr[mt * 4 + j] = (mt ? st1[j] : st0[j]) * 0.125f + padv[k];
            }
        float cmax = sarr[0];
#pragma unroll
        for (int i = 1; i < 8; ++i) cmax = fmaxf(cmax, sarr[i]);
        cmax = fmaxf(cmax, __shfl_xor(cmax, 16));
        cmax = fmaxf(cmax, __shfl_xor(cmax, 32));
        float mnew = fmaxf(mreg, cmax);
        float fac = __expf(mreg - mnew);
        float parr[8], psum = 0.0f;
#pragma unroll
        for (int i = 0; i < 8; ++i) { parr[i] = __expf(sarr[i] - mnew); psum += parr[i]; }
        psum += __shfl_xor(psum, 16);
        psum += __shfl_xor(psum, 32);
        lreg = lreg * fac + psum;
        mreg = mnew;
        ot0 *= fac; ot1 *= fac; ot2 *= fac; ot3 *= fac;
#pragma unroll
        for (int mt = 0; mt < 2; ++mt) {
            unsigned int lo = (unsigned int)f2bf(parr[mt * 4 + 0]) | ((unsigned int)f2bf(parr[mt * 4 + 1]) << 16);
            unsigned int hi = (unsigned int)f2bf(parr[mt * 4 + 2]) | ((unsigned int)f2bf(parr[mt * 4 + 3]) << 16);
            unsigned int* dst = (unsigned int*)(Pl + (qg * 16 + cq) * 72 + kh * 32 + mt * 16 + g4 * 4);
            dst[0] = lo; dst[1] = hi;
        }
        short8 pf = *(const short8*)(Pl + (qg * 16 + cq) * 72 + kh * 32 + g4 * 8);
        {
            short8 vf;
            vf = *(const short8*)(Vt + (0 * 16 + cq) * 72 + kh * 32 + g4 * 8);
            ot0 = __builtin_amdgcn_mfma_f32_16x16x32_bf16(vf, pf, ot0, 0, 0, 0);
            vf = *(const short8*)(Vt + (1 * 16 + cq) * 72 + kh * 32 + g4 * 8);
            ot1 = __builtin_amdgcn_mfma_f32_16x16x32_bf16(vf, pf, ot1, 0, 0, 0);
            vf = *(const short8*)(Vt + (2 * 16 + cq) * 72 + kh * 32 + g4 * 8);
            ot2 = __builtin_amdgcn_mfma_f32_16x16x32_bf16(vf, pf, ot2, 0, 0, 0);
            vf = *(const short8*)(Vt + (3 * 16 + cq) * 72 + kh * 32 + g4 * 8);
            ot3 = __builtin_amdgcn_mfma_f32_16x16x32_bf16(vf, pf, ot3, 0, 0, 0);
        }
    }

    __syncthreads();
    if (g4 == 0) {
        msh[(qg * 2 + kh) * 16 + cq] = mreg;
        lsh[(qg * 2 + kh) * 16 + cq] = lreg;
    }
    __syncthreads();
    {
        float m0 = msh[(qg * 2 + 0) * 16 + cq], m1 = msh[(qg * 2 + 1) * 16 + cq];
        float Mm = fmaxf(m0, m1);
        float e_self = __expf(mreg - Mm);
        f32x4 o;
        o = ot0 * e_self; *(f32x4*)(Osh + ((qg * 2 + kh) * 16 + cq) * 68 + 0  + g4 * 4) = o;
        o = ot1 * e_self; *(f32x4*)(Osh + ((qg * 2 + kh) * 16 + cq) * 68 + 16 + g4 * 4) = o;
        o = ot2 * e_self; *(f32x4*)(Osh + ((qg * 2 + kh) * 16 + cq) * 68 + 32 + g4 * 4) = o;
        o = ot3 * e_self; *(f32x4*)(Osh + ((qg * 2 + kh) * 16 + cq) * 68 + 48 + g4 * 4) = o;
    }
    __syncthreads();
    {
        int q_all = tid >> 3, d0 = (tid & 7) * 8;
        int qg2 = q_all >> 4, ql = q_all & 15;
        float mm0 = msh[(qg2 * 2 + 0) * 16 + ql], mm1 = msh[(qg2 * 2 + 1) * 16 + ql];
        float MM = fmaxf(mm0, mm1);
        float lt = lsh[(qg2 * 2 + 0) * 16 + ql] * __expf(mm0 - MM) +
                   lsh[(qg2 * 2 + 1) * 16 + ql] * __expf(mm1 - MM);
        int prow = ((c * B_ + b) * H_ + h) * SG_ + qt * 32 + q_all;
#pragma unroll
        for (int i = 0; i < 8; ++i) {
            float a = Osh[((qg2 * 2 + 0) * 16 + ql) * 68 + d0 + i] +
                      Osh[((qg2 * 2 + 1) * 16 + ql) * 68 + d0 + i];
            pacc[(size_t)prow * HD_ + d0 + i] = a;
        }
        if ((tid & 7) == 0) { pm[prow] = MM; pl[prow] = lt; }
    }
}

__global__ __launch_bounds__(256) void attn_combine_kernel(const float* __restrict__ pacc,
                                                           const float* __restrict__ pm,
                                                           const float* __restrict__ pl,
                                                           __hip_bfloat16* __restrict__ Og) {
    int wave = (int)((blockIdx.x * (size_t)blockDim.x + threadIdx.x) >> 6);
    int lane = threadIdx.x & 63;
    int gq = wave & (SG_ - 1);
    int h  = (wave >> 7) & 7;
    int b  = wave >> 10;

    float M = MINF_;
#pragma unroll
    for (int c = 0; c < KC_; ++c) {
        int pidx = ((c * B_ + b) * H_ + h) * SG_ + gq;
        M = fmaxf(M, pm[pidx]);
    }
    float L = 0.0f, Ov = 0.0f;
#pragma unroll
    for (int c = 0; c < KC_; ++c) {
        int pidx = ((c * B_ + b) * H_ + h) * SG_ + gq;
        float e = __expf(pm[pidx] - M);
        L += pl[pidx] * e;
        Ov += pacc[(size_t)pidx * HD_ + lane] * e;
    }
    Og[(size_t)(b * SG_ + gq) * D_ + h * HD_ + lane] = __float2bfloat16(Ov / L);
}

// ---------------------------------------------------------------- LN (input already has residual added)
__global__ __launch_bounds__(256) void ln_kernel(const float* __restrict__ A,
                                                 const float* __restrict__ g,
                                                 const float* __restrict__ be,
                                                 float* __restrict__ out,
                                                 __hip_bfloat16* __restrict__ outb,
                                                 int wb) {
    int row = blockIdx.x;
    int tid = threadIdx.x;
    size_t base = (size_t)row * D_;
    float x0 = A[base + tid];
    float x1 = A[base + tid + 256];
    float s1 = x0 + x1;
    float s2 = x0 * x0 + x1 * x1;
    for (int off = 1; off < 64; off <<= 1) {
        s1 += __shfl_xor(s1, off);
        s2 += __shfl_xor(s2, off);
    }
    __shared__ float ws1[4], ws2[4];
    int wid = tid >> 6;
    if ((tid & 63) == 0) { ws1[wid] = s1; ws2[wid] = s2; }
    __syncthreads();
    s1 = ws1[0] + ws1[1] + ws1[2] + ws1[3];
    s2 = ws2[0] + ws2[1] + ws2[2] + ws2[3];
    float mean = s1 * (1.0f / D_);
    float var  = s2 * (1.0f / D_) - mean * mean;
    float rstd = rsqrtf(var + 1e-5f);
    float o0 = (x0 - mean) * rstd * g[tid]       + be[tid];
    float o1 = (x1 - mean) * rstd * g[tid + 256] + be[tid + 256];
    out[base + tid]       = o0;
    out[base + tid + 256] = o1;
    if (wb) {
        outb[base + tid]       = __float2bfloat16(o0);
        outb[base + tid + 256] = __float2bfloat16(o1);
    }
}

// ---------------------------------------------------------------- classifier stage 1: per-slice pool + w1 GEMV
// grid (8 kc, 2 b). 16 blocks -> the cold 512KB w1 is fetched by 16 CUs in
// parallel (r8's fused 2-block version was MLP-bound on this read: 39us).
__global__ __launch_bounds__(256) void cls_part_kernel(const float* __restrict__ x2g,
                                                       const int* __restrict__ pad_all,
                                                       const float* __restrict__ w1,
                                                       float* __restrict__ part) {
    int kc = blockIdx.x, b = blockIdx.y, tid = threadIdx.x;
    __shared__ float wrow[SG_];
    __shared__ float zpart[4][64];
    __shared__ float zgs[64];
    if (tid < SG_) wrow[tid] = pad_all[b * S_ + SL_ + tid] ? 0.0f : 1.0f;
    __syncthreads();

    // pool this block's 64-column slice: wave w handles g = w, w+4, ...
    int j = tid & 63, grp = tid >> 6;
    float a = 0.0f;
#pragma unroll 8
    for (int g = grp; g < SG_; g += 4)
        a = fmaf(wrow[g], x2g[(size_t)(b * SG_ + g) * D_ + kc * 64 + j], a);
    zpart[grp][j] = a;
    __syncthreads();
    if (tid < 64) {
        float cnt = 0.0f;
#pragma unroll 16
        for (int g = 0; g < SG_; ++g) cnt += wrow[g];
        zgs[tid] = (zpart[0][tid] + zpart[1][tid] + zpart[2][tid] + zpart[3][tid]) / cnt;
    }
    __syncthreads();

    // partial hidden: sum over this block's 64 d-values; w1 reads coalesced (1KB/iter)
    float s = 0.0f;
#pragma unroll 8
    for (int d = 0; d < 64; ++d)
        s = fmaf(zgs[d], w1[(size_t)(kc * 64 + d) * 256 + tid], s);
    part[(b * 8 + kc) * 256 + tid] = s;
}

__global__ __launch_bounds__(256) void cls_fin_kernel(const float* __restrict__ part,
                                                      const float* __restrict__ w2,
                                                      float* __restrict__ out) {
    int b = blockIdx.x, n = threadIdx.x;
    float hsum = 0.0f;
#pragma unroll
    for (int kc = 0; kc < 8; ++kc) hsum += part[(b * 8 + kc) * 256 + n];
    hsum = fmaxf(hsum, 0.0f);
    float o0 = hsum * w2[(size_t)n * NC_ + 0];
    float o1 = hsum * w2[(size_t)n * NC_ + 1];
    o0 = wave_sum(o0);
    o1 = wave_sum(o1);
    __shared__ float r0[4], r1[4];
    if ((n & 63) == 0) { r0[n >> 6] = o0; r1[n >> 6] = o1; }
    __syncthreads();
    if (n == 0) {
        out[b * NC_ + 0] = r0[0] + r0[1] + r0[2] + r0[3];
        out[b * NC_ + 1] = r1[0] + r1[1] + r1[2] + r1[3];
    }
}

// ---------------------------------------------------------------- launch
extern "C" void kernel_launch(void* const* d_in, const int* in_sizes, int n_in,
                              void* d_out, int out_size, void* d_ws, size_t ws_size,
                              hipStream_t stream) {
    const int*   ids    = (const int*)d_in[0];
    const float* embed  = (const float*)d_in[1];
    const float* gtok   = (const float*)d_in[2];
    const float* q_w    = (const float*)d_in[4];
    const float* q_b    = (const float*)d_in[5];
    const float* k_w    = (const float*)d_in[6];
    const float* k_b    = (const float*)d_in[7];
    const float* v_w    = (const float*)d_in[8];
    const float* v_b    = (const float*)d_in[9];
    const float* o_w    = (const float*)d_in[10];
    const float* o_b    = (const float*)d_in[11];
    const float* ln1_g  = (const float*)d_in[12];
    const float* ln1_b  = (const float*)d_in[13];
    const float* ln2_g  = (const float*)d_in[14];
    const float* ln2_b  = (const float*)d_in[15];
    const float* ff1_w  = (const float*)d_in[16];
    const float* ff1_b  = (const float*)d_in[17];
    const float* ff2_w  = (const float*)d_in[18];
    const float* ff2_b  = (const float*)d_in[19];
    const float* cls_w1 = (const float*)d_in[20];
    const float* cls_w2 = (const float*)d_in[21];

    char* ws = (char*)d_ws;
    __hip_bfloat16* x_b     = (__hip_bfloat16*)(ws + 0);          //  4,456,448 full rows bf16
    __hip_bfloat16* kv_bf   = (__hip_bfloat16*)(ws + 4456448);    //  8,912,896 K|V all rows
    __hip_bfloat16* qg_bf   = (__hip_bfloat16*)(ws + 13369344);   //    262,144 Q global rows
    __hip_bfloat16* og_bf   = (__hip_bfloat16*)(ws + 13631488);   //    262,144 attn out global
    float*          xg_f32  = (float*)(ws + 13893632);            //    524,288 x global rows f32
    float*          tmpA    = (float*)(ws + 14417920);            //    524,288 O-proj(+res)
    float*          x1g     = (float*)(ws + 14942208);            //    524,288
    __hip_bfloat16* x1g_b   = (__hip_bfloat16*)(ws + 15466496);   //    262,144
    __hip_bfloat16* ffh_b   = (__hip_bfloat16*)(ws + 15728640);   //    524,288
    float*          tmpB    = (float*)(ws + 16252928);            //    524,288 FF2(+res)
    float*          x2g     = (float*)(ws + 16777216);            //    524,288
    __hip_bfloat16* WqT     = (__hip_bfloat16*)(ws + 17301504);   //    524,288
    __hip_bfloat16* WkvT    = (__hip_bfloat16*)(ws + 17825792);   //  1,048,576
    __hip_bfloat16* WoT     = (__hip_bfloat16*)(ws + 18874368);   //    524,288
    __hip_bfloat16* W1T     = (__hip_bfloat16*)(ws + 19398656);   //  1,048,576
    __hip_bfloat16* W2T     = (__hip_bfloat16*)(ws + 20447232);   //  1,048,576
    float*          kvb     = (float*)(ws + 21495808);            //      4,096
    int*            pad_all = (int*)(ws + 21499904);              //     17,408 (+pad)
    float*          pacc    = (float*)(ws + 21520384);            //  4,194,304
    float*          pm      = (float*)(ws + 25714688);            //     65,536
    float*          pl      = (float*)(ws + 25780224);            //     65,536
    float*          clspart = (float*)(ws + 25845760);            //     16,384

    build_x_kernel<<<MROWS_, 128, 0, stream>>>(ids, embed, gtok, x_b, xg_f32, pad_all);
    wt_all_kernel<<<512, 256, 0, stream>>>(q_w, k_w, v_w, o_w, ff1_w, ff2_w,
                                           WqT, WkvT, WoT, W1T, W2T, k_b, v_b, kvb);

    // K,V for all rows (the only full-width GEMM left)
    gemm_bt_kernel<<<dim3(8, 34), 256, 0, stream>>>(x_b, WkvT, kvb, kv_bf, 1024, 512, 2);
    // Q for global rows only (A-row remap from full x_b)
    gemm64_kernel<<<dim3(8, 4), 256, 0, stream>>>(x_b, WqT, q_b, nullptr, qg_bf, 512, 512, 2 | 8);

    attn_global_kernel<<<512, 256, 0, stream>>>(qg_bf, kv_bf, pad_all, pacc, pm, pl);
    attn_combine_kernel<<<512, 256, 0, stream>>>(pacc, pm, pl, og_bf);

    // tail: 256 rows only
    gemm64_kernel<<<dim3(8, 4), 256, 0, stream>>>(og_bf, WoT, o_b, xg_f32, tmpA, 512, 512, 4);
    ln_kernel<<<GR_, 256, 0, stream>>>(tmpA, ln1_g, ln1_b, x1g, x1g_b, 1);
    gemm64_kernel<<<dim3(16, 4), 256, 0, stream>>>(x1g_b, W1T, ff1_b, nullptr, ffh_b, 1024, 512, 1 | 2);
    gemm64_kernel<<<dim3(8, 4), 256, 0, stream>>>(ffh_b, W2T, ff2_b, x1g, tmpB, 512, 1024, 4);
    ln_kernel<<<GR_, 256, 0, stream>>>(tmpB, ln2_g, ln2_b, x2g, nullptr, 0);

    cls_part_kernel<<<dim3(8, B_), 256, 0, stream>>>(x2g, pad_all, cls_w1, clspart);
    cls_fin_kernel<<<B_, 256, 0, stream>>>(clspart, cls_w2, (float*)d_out);
}